// Round 4
// baseline (765.059 us; speedup 1.0000x reference)
//
#include <hip/hip_runtime.h>

#define NN 10000
#define NE 160000
static constexpr int TPB = 256;

typedef unsigned int uint32;
typedef unsigned short ushort16;

static __device__ __forceinline__ ushort f2bf(float f) {
  uint32 u = __float_as_uint(f);
  u += 0x7fff + ((u >> 16) & 1);   // round-to-nearest-even
  return (ushort)(u >> 16);
}
static __device__ __forceinline__ float bf2f(ushort s) {
  return __uint_as_float(((uint32)s) << 16);
}

// ---------------- sort / CSR build ----------------

__global__ void k_count(const int* __restrict__ ei, int* __restrict__ cnt_row,
                        int* __restrict__ cnt_col) {
  int e = blockIdx.x * TPB + threadIdx.x;
  if (e >= NE) return;
  atomicAdd(&cnt_row[ei[e]], 1);
  atomicAdd(&cnt_col[ei[NE + e]], 1);
}

__global__ void k_scan2(const int* __restrict__ cnt_r, int* __restrict__ off_r, int* __restrict__ cur_r,
                        const int* __restrict__ cnt_c, int* __restrict__ off_c, int* __restrict__ cur_c) {
  const int* cnt = (blockIdx.x == 0) ? cnt_r : cnt_c;
  int* off = (blockIdx.x == 0) ? off_r : off_c;
  int* cur = (blockIdx.x == 0) ? cur_r : cur_c;
  int lane = threadIdx.x;  // 64 threads (one wave)
  int carry = 0;
  for (int base = 0; base < NN; base += 64) {
    int i = base + lane;
    int v = (i < NN) ? cnt[i] : 0;
    int s = v;
    #pragma unroll
    for (int dd = 1; dd < 64; dd <<= 1) {
      int t = __shfl_up(s, dd, 64);
      if (lane >= dd) s += t;
    }
    int excl = carry + s - v;
    if (i < NN) { off[i] = excl; cur[i] = excl; }
    carry += __shfl(s, 63, 64);
  }
  if (lane == 0) off[NN] = carry;
}

__global__ void k_fill_row(const int* __restrict__ ei, int* __restrict__ cur_row,
                           int* __restrict__ eid_row) {
  int e = blockIdx.x * TPB + threadIdx.x;
  if (e >= NE) return;
  int r = ei[e];
  int p = atomicAdd(&cur_row[r], 1);
  eid_row[p] = e;
}

__global__ void k_fill_col(const int* __restrict__ ei, const int* __restrict__ eid_row,
                           int* __restrict__ cur_col, int* __restrict__ slot_col) {
  int s = blockIdx.x * TPB + threadIdx.x;
  if (s >= NE) return;
  int e = eid_row[s];
  int c = ei[NE + e];
  int p = atomicAdd(&cur_col[c], 1);
  slot_col[p] = s;
}

// ---------------- per-layer kernels ----------------

// xp = x@pw^T + pb ; root = xp@rw^T + cb ; B[n,o] = sum_i xp[i]*eb2[i*D+o]
template<int DIN, int D>
__global__ void __launch_bounds__(TPB)
k_nodeprep(const float* __restrict__ x, const float* __restrict__ pw, const float* __restrict__ pb,
           const float* __restrict__ rw, const float* __restrict__ cb, const float* __restrict__ eb2,
           float* __restrict__ xp, float* __restrict__ root, float* __restrict__ Bb) {
  __shared__ float s_pw[D * DIN], s_rw[D * D], s_eb2[D * D], s_pb[D], s_cb[D];
  for (int t = threadIdx.x; t < D * DIN; t += TPB) s_pw[t] = pw[t];
  for (int t = threadIdx.x; t < D * D; t += TPB) { s_rw[t] = rw[t]; s_eb2[t] = eb2[t]; }
  for (int t = threadIdx.x; t < D; t += TPB) { s_pb[t] = pb[t]; s_cb[t] = cb[t]; }
  __syncthreads();
  int n = blockIdx.x * TPB + threadIdx.x;
  if (n >= NN) return;
  float xv[DIN];
  const float4* x4 = (const float4*)(x + (size_t)n * DIN);
  #pragma unroll
  for (int i = 0; i < DIN / 4; i++) {
    float4 v = x4[i];
    xv[4*i+0] = v.x; xv[4*i+1] = v.y; xv[4*i+2] = v.z; xv[4*i+3] = v.w;
  }
  float xpv[D];
  #pragma unroll
  for (int o = 0; o < D; o++) {
    float a = s_pb[o];
    #pragma unroll
    for (int i = 0; i < DIN; i++) a = fmaf(s_pw[o*DIN + i], xv[i], a);
    xpv[o] = a;
    xp[(size_t)n*D + o] = a;
  }
  #pragma unroll
  for (int o = 0; o < D; o++) {
    float a = s_cb[o];
    #pragma unroll
    for (int i = 0; i < D; i++) a = fmaf(s_rw[o*D + i], xpv[i], a);
    root[(size_t)n*D + o] = a;
  }
  #pragma unroll
  for (int o = 0; o < D; o++) {
    float a = 0.f;
    #pragma unroll
    for (int i = 0; i < D; i++) a = fmaf(xpv[i], s_eb2[i*D + o], a);
    Bb[(size_t)n*D + o] = a;
  }
}

// V[i][k*D+o] = ew2[(i*D+o)*128 + k]   (one-time per layer, 512 KB max)
__global__ void k_trans(const float* __restrict__ ew2, float* __restrict__ V, int D) {
  int t = blockIdx.x * TPB + threadIdx.x;
  int COLS = D * 128;
  if (t >= D * COLS) return;
  int i = t / COLS, c = t - i * COLS;
  int k = c / D, o = c - k * D;
  V[t] = ew2[((size_t)(i * D + o)) * 128 + k];
}

// U[nloc, c] = sum_i xp[n0+nloc, i] * V[i*COLS + c], c = k*D+o.  bf16 output.
// Register-blocked: each thread computes 4 consecutive c (float4 V load) x 16 nodes.
template<int D>
__global__ void __launch_bounds__(TPB)
k_ugemm3(const float* __restrict__ xp, const float* __restrict__ V,
         ushort* __restrict__ U, int n0, int nch) {
  constexpr int COLS = D * 128;
  constexpr int CQ = COLS / 4;
  int c4 = blockIdx.x * TPB + threadIdx.x;
  int nb = blockIdx.y * 16;
  __shared__ float s_xp[16][D];
  int nload = nch - nb; if (nload > 16) nload = 16;
  for (int t = threadIdx.x; t < 16 * D; t += TPB) {
    int g = t / D, i = t % D;
    s_xp[g][i] = (g < nload) ? xp[(size_t)(n0 + nb + g) * D + i] : 0.f;
  }
  __syncthreads();
  float4 acc[16];
  #pragma unroll
  for (int g = 0; g < 16; g++) acc[g] = {0.f, 0.f, 0.f, 0.f};
  const float4* V4 = (const float4*)V;
  #pragma unroll 4
  for (int i = 0; i < D; i++) {
    float4 v = V4[(size_t)i * CQ + c4];
    #pragma unroll
    for (int g = 0; g < 16; g++) {
      float xg = s_xp[g][i];
      acc[g].x = fmaf(xg, v.x, acc[g].x);
      acc[g].y = fmaf(xg, v.y, acc[g].y);
      acc[g].z = fmaf(xg, v.z, acc[g].z);
      acc[g].w = fmaf(xg, v.w, acc[g].w);
    }
  }
  for (int g = 0; g < nload; g++) {
    ushort4 o;
    o.x = f2bf(acc[g].x); o.y = f2bf(acc[g].y);
    o.z = f2bf(acc[g].z); o.w = f2bf(acc[g].w);
    ((ushort4*)(U + (size_t)(nb + g) * COLS))[c4] = o;
  }
}

// One block per source node: stage the node's U row (bf16 -> f32) in LDS once,
// then run all of its (row-sorted) edges against it.  D/4 threads per edge.
template<int D>
__global__ void __launch_bounds__(TPB)
k_edgemsg3(const int* __restrict__ eid_row, const int* __restrict__ row_off,
           const float* __restrict__ ea, const float* __restrict__ ew1,
           const float* __restrict__ eb1, const ushort* __restrict__ U,
           const float* __restrict__ Bb, float* __restrict__ msg, int n0) {
  constexpr int OQ = D / 4;       // threads per edge
  constexpr int EB = TPB / OQ;    // edges per inner iteration
  constexpr int COLS = D * 128;
  int n = n0 + blockIdx.x;
  int p0 = row_off[n], p1 = row_off[n + 1];
  if (p0 >= p1) return;
  __shared__ float s_w1t[8 * 128];    // [i][k]
  __shared__ float s_b1[128];
  __shared__ float s_U[COLS];         // this node's U row: [k][o]
  __shared__ float s_h[EB * 129];     // padded stride kills bank conflicts
  __shared__ float s_ea[EB * 8];
  int tid = threadIdx.x;
  for (int t = tid; t < 1024; t += TPB) {
    int k = t >> 3, i = t & 7;
    s_w1t[i * 128 + k] = ew1[t];
  }
  for (int t = tid; t < 128; t += TPB) s_b1[t] = eb1[t];
  {
    const ushort4* Ug = (const ushort4*)(U + (size_t)(n - n0) * COLS);
    float4* Us = (float4*)s_U;
    for (int t = tid; t < COLS / 4; t += TPB) {
      ushort4 q = Ug[t];
      float4 f = {bf2f(q.x), bf2f(q.y), bf2f(q.z), bf2f(q.w)};
      Us[t] = f;
    }
  }
  int el = tid / OQ, oq = tid % OQ;
  float4 b = ((const float4*)(Bb + (size_t)n * D))[oq];
  for (int pc = p0; pc < p1; pc += EB) {
    int cnt = p1 - pc; if (cnt > EB) cnt = EB;
    __syncthreads();   // first iter: staging done; later: protect s_ea/s_h reuse
    for (int t = tid; t < cnt * 8; t += TPB) {
      int e2 = t >> 3, i = t & 7;
      s_ea[t] = ea[(size_t)eid_row[pc + e2] * 8 + i];
    }
    __syncthreads();
    for (int t = tid; t < cnt * 128; t += TPB) {
      int e2 = t >> 7, k = t & 127;
      float a = s_b1[k];
      #pragma unroll
      for (int i = 0; i < 8; i++) a = fmaf(s_ea[e2 * 8 + i], s_w1t[i * 128 + k], a);
      s_h[e2 * 129 + k] = fmaxf(a, 0.f);
    }
    __syncthreads();
    if (el < cnt) {
      const float* hp = s_h + el * 129;
      const float4* U4 = (const float4*)s_U;
      float4 acc = {0.f, 0.f, 0.f, 0.f};
      #pragma unroll 8
      for (int k = 0; k < 128; k++) {
        float hk = hp[k];
        float4 u = U4[k * OQ + oq];
        acc.x = fmaf(hk, u.x, acc.x);
        acc.y = fmaf(hk, u.y, acc.y);
        acc.z = fmaf(hk, u.z, acc.z);
        acc.w = fmaf(hk, u.w, acc.w);
      }
      acc.x += b.x; acc.y += b.y; acc.z += b.z; acc.w += b.w;
      ((float4*)(msg + (size_t)(pc + el) * D))[oq] = acc;
    }
  }
}

// gather aggregation by col-CSR (deterministic), then x = relu(agg/deg + root) + xp
template<int D>
__global__ void __launch_bounds__(TPB)
k_agg(const int* __restrict__ col_off, const int* __restrict__ slot_col,
      const float* __restrict__ msg, const float* __restrict__ root,
      const float* __restrict__ xp, float* __restrict__ xout) {
  constexpr int GP = TPB / D;
  int g = threadIdx.x / D, o = threadIdx.x % D;
  int n = blockIdx.x * GP + g;
  if (n >= NN) return;
  int p0 = col_off[n], p1 = col_off[n + 1];
  float acc = 0.f;
  for (int p = p0; p < p1; p++) {
    int sc = slot_col[p];
    acc += msg[(size_t)sc * D + o];
  }
  float deg = (p1 > p0) ? (float)(p1 - p0) : 1.f;
  float conv = acc / deg + root[(size_t)n * D + o];
  float rl = conv > 0.f ? conv : 0.f;
  xout[(size_t)n * D + o] = rl + xp[(size_t)n * D + o];
}

// final edge MLP: out = relu((x[row]+x[col]) @ mw0^T + mb0) @ mw1^T + mb1
__global__ void __launch_bounds__(TPB)
k_final(const int* __restrict__ ei, const float* __restrict__ x,
        const float* __restrict__ mw0, const float* __restrict__ mb0,
        const float* __restrict__ mw1, const float* __restrict__ mb1,
        float* __restrict__ out) {
  __shared__ float s_w0[256], s_b0[16], s_w1[16], s_b1;
  for (int t = threadIdx.x; t < 256; t += TPB) s_w0[t] = mw0[t];
  if (threadIdx.x < 16) { s_b0[threadIdx.x] = mb0[threadIdx.x]; s_w1[threadIdx.x] = mw1[threadIdx.x]; }
  if (threadIdx.x == 0) s_b1 = mb1[0];
  __syncthreads();
  int e = blockIdx.x * TPB + threadIdx.x;
  if (e >= NE) return;
  int r = ei[e], c = ei[NE + e];
  const float4* xr4 = (const float4*)(x + (size_t)r * 16);
  const float4* xc4 = (const float4*)(x + (size_t)c * 16);
  float er[16];
  #pragma unroll
  for (int q = 0; q < 4; q++) {
    float4 vr = xr4[q], vc = xc4[q];
    er[4*q+0] = vr.x + vc.x; er[4*q+1] = vr.y + vc.y;
    er[4*q+2] = vr.z + vc.z; er[4*q+3] = vr.w + vc.w;
  }
  float o = s_b1;
  #pragma unroll
  for (int j = 0; j < 16; j++) {
    float t = s_b0[j];
    #pragma unroll
    for (int k = 0; k < 16; k++) t = fmaf(er[k], s_w0[j * 16 + k], t);
    t = fmaxf(t, 0.f);
    o = fmaf(t, s_w1[j], o);
  }
  out[e] = o;
}

// ---------------- host side ----------------

struct LayerPtrs {
  const float *pw, *pb, *ew1, *eb1, *ew2, *eb2, *rw, *cb;
};

template<int DIN, int D>
static void run_layer(const float* xin, float* xout, const LayerPtrs& L,
                      const int* ei, const float* ea,
                      const int* row_off, const int* col_off,
                      const int* eid_row, const int* slot_col,
                      float* xp, float* root, float* Bb, float* msg, float* Vb,
                      ushort* U, size_t uavail, hipStream_t stream) {
  k_nodeprep<DIN, D><<<(NN + TPB - 1) / TPB, TPB, 0, stream>>>(
      xin, L.pw, L.pb, L.rw, L.cb, L.eb2, xp, root, Bb);
  constexpr int COLS = D * 128;
  k_trans<<<(D * COLS + TPB - 1) / TPB, TPB, 0, stream>>>(L.ew2, Vb, D);
  size_t per_node = sizeof(ushort) * COLS;
  size_t ch = uavail / per_node;
  int CH = (ch > (size_t)NN) ? NN : (int)ch;
  if (CH < 1) CH = 1;
  for (int n0 = 0; n0 < NN; n0 += CH) {
    int n1 = n0 + CH; if (n1 > NN) n1 = NN;
    int nch = n1 - n0;
    dim3 gb((COLS / 4) / TPB, (nch + 15) / 16);
    k_ugemm3<D><<<gb, TPB, 0, stream>>>(xp, Vb, U, n0, nch);
    k_edgemsg3<D><<<nch, TPB, 0, stream>>>(
        eid_row, row_off, ea, L.ew1, L.eb1, U, Bb, msg, n0);
  }
  k_agg<D><<<(NN * D + TPB - 1) / TPB, TPB, 0, stream>>>(
      col_off, slot_col, msg, root, xp, xout);
}

extern "C" void kernel_launch(void* const* d_in, const int* in_sizes, int n_in,
                              void* d_out, int out_size, void* d_ws, size_t ws_size,
                              hipStream_t stream) {
  (void)in_sizes; (void)n_in; (void)out_size;
  const float* x0 = (const float*)d_in[0];
  const float* ea = (const float*)d_in[1];
  const int* ei = (const int*)d_in[2];
  LayerPtrs L[4];
  for (int l = 0; l < 4; l++) {
    L[l].pw  = (const float*)d_in[3 + 8 * l];
    L[l].pb  = (const float*)d_in[4 + 8 * l];
    L[l].ew1 = (const float*)d_in[5 + 8 * l];
    L[l].eb1 = (const float*)d_in[6 + 8 * l];
    L[l].ew2 = (const float*)d_in[7 + 8 * l];
    L[l].eb2 = (const float*)d_in[8 + 8 * l];
    L[l].rw  = (const float*)d_in[9 + 8 * l];
    L[l].cb  = (const float*)d_in[10 + 8 * l];
  }
  const float* mw0 = (const float*)d_in[35];
  const float* mb0 = (const float*)d_in[36];
  const float* mw1 = (const float*)d_in[37];
  const float* mb1 = (const float*)d_in[38];
  float* out = (float*)d_out;

  char* w = (char*)d_ws;
  size_t off = 0;
  auto alloc = [&](size_t b) -> void* {
    void* p = w + off;
    off = (off + b + 255) & ~(size_t)255;
    return p;
  };
  int* cnt_row  = (int*)alloc(sizeof(int) * NN);
  int* cnt_col  = (int*)alloc(sizeof(int) * NN);
  int* row_off  = (int*)alloc(sizeof(int) * (NN + 1));
  int* col_off  = (int*)alloc(sizeof(int) * (NN + 1));
  int* cur_row  = (int*)alloc(sizeof(int) * NN);
  int* cur_col  = (int*)alloc(sizeof(int) * NN);
  int* eid_row  = (int*)alloc(sizeof(int) * NE);
  int* slot_col = (int*)alloc(sizeof(int) * NE);
  float* xb0  = (float*)alloc(sizeof(float) * NN * 32);
  float* xb1  = (float*)alloc(sizeof(float) * NN * 32);
  float* xp   = (float*)alloc(sizeof(float) * NN * 32);
  float* root = (float*)alloc(sizeof(float) * NN * 32);
  float* Bb   = (float*)alloc(sizeof(float) * NN * 32);
  float* msg  = (float*)alloc(sizeof(float) * NE * 32);
  float* Vb   = (float*)alloc(sizeof(float) * 128 * 32 * 32);  // 512 KB max
  ushort* U = (ushort*)(w + off);
  size_t uavail = (ws_size > off) ? (ws_size - off) : 0;

  hipMemsetAsync(cnt_row, 0, sizeof(int) * NN, stream);
  hipMemsetAsync(cnt_col, 0, sizeof(int) * NN, stream);
  k_count<<<(NE + TPB - 1) / TPB, TPB, 0, stream>>>(ei, cnt_row, cnt_col);
  k_scan2<<<2, 64, 0, stream>>>(cnt_row, row_off, cur_row, cnt_col, col_off, cur_col);
  k_fill_row<<<(NE + TPB - 1) / TPB, TPB, 0, stream>>>(ei, cur_row, eid_row);
  k_fill_col<<<(NE + TPB - 1) / TPB, TPB, 0, stream>>>(ei, eid_row, cur_col, slot_col);

  float* bufs[2] = {xb0, xb1};
  const float* xin = x0;
  for (int l = 0; l < 4; l++) {
    float* xout = bufs[l & 1];
    if (l == 0) {
      run_layer<16, 32>(xin, xout, L[0], ei, ea, row_off, col_off, eid_row, slot_col,
                        xp, root, Bb, msg, Vb, U, uavail, stream);
    } else if (l == 1) {
      run_layer<32, 16>(xin, xout, L[1], ei, ea, row_off, col_off, eid_row, slot_col,
                        xp, root, Bb, msg, Vb, U, uavail, stream);
    } else if (l == 2) {
      run_layer<16, 16>(xin, xout, L[2], ei, ea, row_off, col_off, eid_row, slot_col,
                        xp, root, Bb, msg, Vb, U, uavail, stream);
    } else {
      run_layer<16, 16>(xin, xout, L[3], ei, ea, row_off, col_off, eid_row, slot_col,
                        xp, root, Bb, msg, Vb, U, uavail, stream);
    }
    xin = xout;
  }
  k_final<<<(NE + TPB - 1) / TPB, TPB, 0, stream>>>(ei, xin, mw0, mb0, mw1, mb1, out);
}

// Round 5
// 746.630 us; speedup vs baseline: 1.0247x; 1.0247x over previous
//
#include <hip/hip_runtime.h>

#define NN 10000
#define NE 160000
static constexpr int TPB = 256;

typedef unsigned int uint32;

static __device__ __forceinline__ ushort f2bf(float f) {
  uint32 u = __float_as_uint(f);
  u += 0x7fff + ((u >> 16) & 1);   // round-to-nearest-even
  return (ushort)(u >> 16);
}
static __device__ __forceinline__ uint32 pk2bf(float a, float b) {
  return (uint32)f2bf(a) | ((uint32)f2bf(b) << 16);
}
static __device__ __forceinline__ float bflo(uint32 u) {
  return __uint_as_float(u << 16);
}
static __device__ __forceinline__ float bfhi(uint32 u) {
  return __uint_as_float(u & 0xffff0000u);
}

// ---------------- sort / CSR build ----------------

__global__ void k_count(const int* __restrict__ ei, int* __restrict__ cnt_row,
                        int* __restrict__ cnt_col) {
  int e = blockIdx.x * TPB + threadIdx.x;
  if (e >= NE) return;
  atomicAdd(&cnt_row[ei[e]], 1);
  atomicAdd(&cnt_col[ei[NE + e]], 1);
}

__global__ void k_scan2(const int* __restrict__ cnt_r, int* __restrict__ off_r, int* __restrict__ cur_r,
                        const int* __restrict__ cnt_c, int* __restrict__ off_c, int* __restrict__ cur_c) {
  const int* cnt = (blockIdx.x == 0) ? cnt_r : cnt_c;
  int* off = (blockIdx.x == 0) ? off_r : off_c;
  int* cur = (blockIdx.x == 0) ? cur_r : cur_c;
  int lane = threadIdx.x;  // 64 threads (one wave)
  int carry = 0;
  for (int base = 0; base < NN; base += 64) {
    int i = base + lane;
    int v = (i < NN) ? cnt[i] : 0;
    int s = v;
    #pragma unroll
    for (int dd = 1; dd < 64; dd <<= 1) {
      int t = __shfl_up(s, dd, 64);
      if (lane >= dd) s += t;
    }
    int excl = carry + s - v;
    if (i < NN) { off[i] = excl; cur[i] = excl; }
    carry += __shfl(s, 63, 64);
  }
  if (lane == 0) off[NN] = carry;
}

__global__ void k_fill_row(const int* __restrict__ ei, int* __restrict__ cur_row,
                           int* __restrict__ eid_row) {
  int e = blockIdx.x * TPB + threadIdx.x;
  if (e >= NE) return;
  int r = ei[e];
  int p = atomicAdd(&cur_row[r], 1);
  eid_row[p] = e;
}

__global__ void k_fill_col(const int* __restrict__ ei, const int* __restrict__ eid_row,
                           int* __restrict__ cur_col, int* __restrict__ slot_col) {
  int s = blockIdx.x * TPB + threadIdx.x;
  if (s >= NE) return;
  int e = eid_row[s];
  int c = ei[NE + e];
  int p = atomicAdd(&cur_col[c], 1);
  slot_col[p] = s;
}

// ---------------- per-layer kernels ----------------

// xp = x@pw^T + pb ; root = xp@rw^T + cb ; B[n,o] = sum_i xp[i]*eb2[i*D+o]
template<int DIN, int D>
__global__ void __launch_bounds__(TPB)
k_nodeprep(const float* __restrict__ x, const float* __restrict__ pw, const float* __restrict__ pb,
           const float* __restrict__ rw, const float* __restrict__ cb, const float* __restrict__ eb2,
           float* __restrict__ xp, float* __restrict__ root, float* __restrict__ Bb) {
  __shared__ float s_pw[D * DIN], s_rw[D * D], s_eb2[D * D], s_pb[D], s_cb[D];
  for (int t = threadIdx.x; t < D * DIN; t += TPB) s_pw[t] = pw[t];
  for (int t = threadIdx.x; t < D * D; t += TPB) { s_rw[t] = rw[t]; s_eb2[t] = eb2[t]; }
  for (int t = threadIdx.x; t < D; t += TPB) { s_pb[t] = pb[t]; s_cb[t] = cb[t]; }
  __syncthreads();
  int n = blockIdx.x * TPB + threadIdx.x;
  if (n >= NN) return;
  float xv[DIN];
  const float4* x4 = (const float4*)(x + (size_t)n * DIN);
  #pragma unroll
  for (int i = 0; i < DIN / 4; i++) {
    float4 v = x4[i];
    xv[4*i+0] = v.x; xv[4*i+1] = v.y; xv[4*i+2] = v.z; xv[4*i+3] = v.w;
  }
  float xpv[D];
  #pragma unroll
  for (int o = 0; o < D; o++) {
    float a = s_pb[o];
    #pragma unroll
    for (int i = 0; i < DIN; i++) a = fmaf(s_pw[o*DIN + i], xv[i], a);
    xpv[o] = a;
    xp[(size_t)n*D + o] = a;
  }
  #pragma unroll
  for (int o = 0; o < D; o++) {
    float a = s_cb[o];
    #pragma unroll
    for (int i = 0; i < D; i++) a = fmaf(s_rw[o*D + i], xpv[i], a);
    root[(size_t)n*D + o] = a;
  }
  #pragma unroll
  for (int o = 0; o < D; o++) {
    float a = 0.f;
    #pragma unroll
    for (int i = 0; i < D; i++) a = fmaf(xpv[i], s_eb2[i*D + o], a);
    Bb[(size_t)n*D + o] = a;
  }
}

// V[i][k*D+o] = ew2[(i*D+o)*128 + k]   (one-time per layer, 512 KB max)
__global__ void k_trans(const float* __restrict__ ew2, float* __restrict__ V, int D) {
  int t = blockIdx.x * TPB + threadIdx.x;
  int COLS = D * 128;
  if (t >= D * COLS) return;
  int i = t / COLS, c = t - i * COLS;
  int k = c / D, o = c - k * D;
  V[t] = ew2[((size_t)(i * D + o)) * 128 + k];
}

// U[nloc, c] = sum_i xp[n0+nloc, i] * V[i*COLS + c], c = k*D+o.  bf16 output,
// packed pairs stored as uint4 (16B/lane -> dwordx4, fully-covered lines).
// Each thread: 8 consecutive cols x 8 nodes.
template<int D>
__global__ void __launch_bounds__(TPB)
k_ugemm4(const float* __restrict__ xp, const float* __restrict__ V,
         uint32* __restrict__ U2 /* U as packed pairs */, int n0, int nch) {
  constexpr int COLS = D * 128;
  constexpr int C8 = COLS / 8;
  int c8 = blockIdx.x * TPB + threadIdx.x;   // column-group of 8
  int nb = blockIdx.y * 8;
  __shared__ float s_xp[8][D];
  int nload = nch - nb; if (nload > 8) nload = 8;
  for (int t = threadIdx.x; t < 8 * D; t += TPB) {
    int g = t / D, i = t % D;
    s_xp[g][i] = (g < nload) ? xp[(size_t)(n0 + nb + g) * D + i] : 0.f;
  }
  __syncthreads();
  float4 accA[8], accB[8];
  #pragma unroll
  for (int g = 0; g < 8; g++) { accA[g] = {0,0,0,0}; accB[g] = {0,0,0,0}; }
  const float4* V4 = (const float4*)V;
  #pragma unroll 4
  for (int i = 0; i < D; i++) {
    float4 va = V4[(size_t)i * (COLS / 4) + c8 * 2];
    float4 vb = V4[(size_t)i * (COLS / 4) + c8 * 2 + 1];
    #pragma unroll
    for (int g = 0; g < 8; g++) {
      float xg = s_xp[g][i];
      accA[g].x = fmaf(xg, va.x, accA[g].x);
      accA[g].y = fmaf(xg, va.y, accA[g].y);
      accA[g].z = fmaf(xg, va.z, accA[g].z);
      accA[g].w = fmaf(xg, va.w, accA[g].w);
      accB[g].x = fmaf(xg, vb.x, accB[g].x);
      accB[g].y = fmaf(xg, vb.y, accB[g].y);
      accB[g].z = fmaf(xg, vb.z, accB[g].z);
      accB[g].w = fmaf(xg, vb.w, accB[g].w);
    }
  }
  for (int g = 0; g < nload; g++) {
    uint4 o;
    o.x = pk2bf(accA[g].x, accA[g].y);
    o.y = pk2bf(accA[g].z, accA[g].w);
    o.z = pk2bf(accB[g].x, accB[g].y);
    o.w = pk2bf(accB[g].z, accB[g].w);
    ((uint4*)(U2 + (size_t)(nb + g) * (COLS / 2)))[c8] = o;
  }
}

// One block per source node: stage the node's U row (packed bf16 -> f32) in LDS
// once, then run all of its (row-sorted) edges against it.  D/4 threads per edge.
template<int D>
__global__ void __launch_bounds__(TPB)
k_edgemsg3(const int* __restrict__ eid_row, const int* __restrict__ row_off,
           const float* __restrict__ ea, const float* __restrict__ ew1,
           const float* __restrict__ eb1, const uint32* __restrict__ U2,
           const float* __restrict__ Bb, float* __restrict__ msg, int n0) {
  constexpr int OQ = D / 4;       // threads per edge
  constexpr int EB = TPB / OQ;    // edges per inner iteration
  constexpr int COLS = D * 128;
  int n = n0 + blockIdx.x;
  int p0 = row_off[n], p1 = row_off[n + 1];
  if (p0 >= p1) return;
  __shared__ float s_w1t[8 * 128];    // [i][k]
  __shared__ float s_b1[128];
  __shared__ float s_U[COLS];         // this node's U row: [k][o]
  __shared__ float s_h[EB * 129];     // padded stride kills bank conflicts
  __shared__ float s_ea[EB * 8];
  int tid = threadIdx.x;
  for (int t = tid; t < 1024; t += TPB) {
    int k = t >> 3, i = t & 7;
    s_w1t[i * 128 + k] = ew1[t];
  }
  for (int t = tid; t < 128; t += TPB) s_b1[t] = eb1[t];
  {
    const uint4* Ug = (const uint4*)(U2 + (size_t)(n - n0) * (COLS / 2));
    float4* Us = (float4*)s_U;
    for (int t = tid; t < COLS / 8; t += TPB) {
      uint4 q = Ug[t];
      float4 f0 = {bflo(q.x), bfhi(q.x), bflo(q.y), bfhi(q.y)};
      float4 f1 = {bflo(q.z), bfhi(q.z), bflo(q.w), bfhi(q.w)};
      Us[2 * t] = f0;
      Us[2 * t + 1] = f1;
    }
  }
  int el = tid / OQ, oq = tid % OQ;
  float4 b = ((const float4*)(Bb + (size_t)n * D))[oq];
  for (int pc = p0; pc < p1; pc += EB) {
    int cnt = p1 - pc; if (cnt > EB) cnt = EB;
    __syncthreads();   // first iter: staging done; later: protect s_ea/s_h reuse
    for (int t = tid; t < cnt * 8; t += TPB) {
      int e2 = t >> 3, i = t & 7;
      s_ea[t] = ea[(size_t)eid_row[pc + e2] * 8 + i];
    }
    __syncthreads();
    for (int t = tid; t < cnt * 128; t += TPB) {
      int e2 = t >> 7, k = t & 127;
      float a = s_b1[k];
      #pragma unroll
      for (int i = 0; i < 8; i++) a = fmaf(s_ea[e2 * 8 + i], s_w1t[i * 128 + k], a);
      s_h[e2 * 129 + k] = fmaxf(a, 0.f);
    }
    __syncthreads();
    if (el < cnt) {
      const float* hp = s_h + el * 129;
      const float4* U4 = (const float4*)s_U;
      float4 acc = {0.f, 0.f, 0.f, 0.f};
      #pragma unroll 8
      for (int k = 0; k < 128; k++) {
        float hk = hp[k];
        float4 u = U4[k * OQ + oq];
        acc.x = fmaf(hk, u.x, acc.x);
        acc.y = fmaf(hk, u.y, acc.y);
        acc.z = fmaf(hk, u.z, acc.z);
        acc.w = fmaf(hk, u.w, acc.w);
      }
      acc.x += b.x; acc.y += b.y; acc.z += b.z; acc.w += b.w;
      ((float4*)(msg + (size_t)(pc + el) * D))[oq] = acc;
    }
  }
}

// gather aggregation by col-CSR (deterministic), then x = relu(agg/deg + root) + xp
template<int D>
__global__ void __launch_bounds__(TPB)
k_agg(const int* __restrict__ col_off, const int* __restrict__ slot_col,
      const float* __restrict__ msg, const float* __restrict__ root,
      const float* __restrict__ xp, float* __restrict__ xout) {
  constexpr int GP = TPB / D;
  int g = threadIdx.x / D, o = threadIdx.x % D;
  int n = blockIdx.x * GP + g;
  if (n >= NN) return;
  int p0 = col_off[n], p1 = col_off[n + 1];
  float acc = 0.f;
  for (int p = p0; p < p1; p++) {
    int sc = slot_col[p];
    acc += msg[(size_t)sc * D + o];
  }
  float deg = (p1 > p0) ? (float)(p1 - p0) : 1.f;
  float conv = acc / deg + root[(size_t)n * D + o];
  float rl = conv > 0.f ? conv : 0.f;
  xout[(size_t)n * D + o] = rl + xp[(size_t)n * D + o];
}

// final edge MLP: out = relu((x[row]+x[col]) @ mw0^T + mb0) @ mw1^T + mb1
__global__ void __launch_bounds__(TPB)
k_final(const int* __restrict__ ei, const float* __restrict__ x,
        const float* __restrict__ mw0, const float* __restrict__ mb0,
        const float* __restrict__ mw1, const float* __restrict__ mb1,
        float* __restrict__ out) {
  __shared__ float s_w0[256], s_b0[16], s_w1[16], s_b1;
  for (int t = threadIdx.x; t < 256; t += TPB) s_w0[t] = mw0[t];
  if (threadIdx.x < 16) { s_b0[threadIdx.x] = mb0[threadIdx.x]; s_w1[threadIdx.x] = mw1[threadIdx.x]; }
  if (threadIdx.x == 0) s_b1 = mb1[0];
  __syncthreads();
  int e = blockIdx.x * TPB + threadIdx.x;
  if (e >= NE) return;
  int r = ei[e], c = ei[NE + e];
  const float4* xr4 = (const float4*)(x + (size_t)r * 16);
  const float4* xc4 = (const float4*)(x + (size_t)c * 16);
  float er[16];
  #pragma unroll
  for (int q = 0; q < 4; q++) {
    float4 vr = xr4[q], vc = xc4[q];
    er[4*q+0] = vr.x + vc.x; er[4*q+1] = vr.y + vc.y;
    er[4*q+2] = vr.z + vc.z; er[4*q+3] = vr.w + vc.w;
  }
  float o = s_b1;
  #pragma unroll
  for (int j = 0; j < 16; j++) {
    float t = s_b0[j];
    #pragma unroll
    for (int k = 0; k < 16; k++) t = fmaf(er[k], s_w0[j * 16 + k], t);
    t = fmaxf(t, 0.f);
    o = fmaf(t, s_w1[j], o);
  }
  out[e] = o;
}

// ---------------- host side ----------------

struct LayerPtrs {
  const float *pw, *pb, *ew1, *eb1, *ew2, *eb2, *rw, *cb;
};

template<int DIN, int D>
static void run_layer(const float* xin, float* xout, const LayerPtrs& L,
                      const int* ei, const float* ea,
                      const int* row_off, const int* col_off,
                      const int* eid_row, const int* slot_col,
                      float* xp, float* root, float* Bb, float* msg, float* Vb,
                      uint32* U2, size_t uavail, hipStream_t stream) {
  k_nodeprep<DIN, D><<<(NN + TPB - 1) / TPB, TPB, 0, stream>>>(
      xin, L.pw, L.pb, L.rw, L.cb, L.eb2, xp, root, Bb);
  constexpr int COLS = D * 128;
  k_trans<<<(D * COLS + TPB - 1) / TPB, TPB, 0, stream>>>(L.ew2, Vb, D);
  size_t per_node = sizeof(ushort) * COLS;
  size_t ch = uavail / per_node;
  int CH = (ch > (size_t)NN) ? NN : (int)ch;
  if (CH < 1) CH = 1;
  for (int n0 = 0; n0 < NN; n0 += CH) {
    int n1 = n0 + CH; if (n1 > NN) n1 = NN;
    int nch = n1 - n0;
    dim3 gb((COLS / 8) / TPB, (nch + 7) / 8);
    k_ugemm4<D><<<gb, TPB, 0, stream>>>(xp, Vb, U2, n0, nch);
    k_edgemsg3<D><<<nch, TPB, 0, stream>>>(
        eid_row, row_off, ea, L.ew1, L.eb1, U2, Bb, msg, n0);
  }
  k_agg<D><<<(NN * D + TPB - 1) / TPB, TPB, 0, stream>>>(
      col_off, slot_col, msg, root, xp, xout);
}

extern "C" void kernel_launch(void* const* d_in, const int* in_sizes, int n_in,
                              void* d_out, int out_size, void* d_ws, size_t ws_size,
                              hipStream_t stream) {
  (void)in_sizes; (void)n_in; (void)out_size;
  const float* x0 = (const float*)d_in[0];
  const float* ea = (const float*)d_in[1];
  const int* ei = (const int*)d_in[2];
  LayerPtrs L[4];
  for (int l = 0; l < 4; l++) {
    L[l].pw  = (const float*)d_in[3 + 8 * l];
    L[l].pb  = (const float*)d_in[4 + 8 * l];
    L[l].ew1 = (const float*)d_in[5 + 8 * l];
    L[l].eb1 = (const float*)d_in[6 + 8 * l];
    L[l].ew2 = (const float*)d_in[7 + 8 * l];
    L[l].eb2 = (const float*)d_in[8 + 8 * l];
    L[l].rw  = (const float*)d_in[9 + 8 * l];
    L[l].cb  = (const float*)d_in[10 + 8 * l];
  }
  const float* mw0 = (const float*)d_in[35];
  const float* mb0 = (const float*)d_in[36];
  const float* mw1 = (const float*)d_in[37];
  const float* mb1 = (const float*)d_in[38];
  float* out = (float*)d_out;

  char* w = (char*)d_ws;
  size_t off = 0;
  auto alloc = [&](size_t b) -> void* {
    void* p = w + off;
    off = (off + b + 255) & ~(size_t)255;
    return p;
  };
  int* cnt_row  = (int*)alloc(sizeof(int) * NN);
  int* cnt_col  = (int*)alloc(sizeof(int) * NN);
  int* row_off  = (int*)alloc(sizeof(int) * (NN + 1));
  int* col_off  = (int*)alloc(sizeof(int) * (NN + 1));
  int* cur_row  = (int*)alloc(sizeof(int) * NN);
  int* cur_col  = (int*)alloc(sizeof(int) * NN);
  int* eid_row  = (int*)alloc(sizeof(int) * NE);
  int* slot_col = (int*)alloc(sizeof(int) * NE);
  float* xb0  = (float*)alloc(sizeof(float) * NN * 32);
  float* xb1  = (float*)alloc(sizeof(float) * NN * 32);
  float* xp   = (float*)alloc(sizeof(float) * NN * 32);
  float* root = (float*)alloc(sizeof(float) * NN * 32);
  float* Bb   = (float*)alloc(sizeof(float) * NN * 32);
  float* msg  = (float*)alloc(sizeof(float) * NE * 32);
  float* Vb   = (float*)alloc(sizeof(float) * 128 * 32 * 32);  // 512 KB max
  uint32* U2 = (uint32*)(w + off);
  size_t uavail = (ws_size > off) ? (ws_size - off) : 0;

  hipMemsetAsync(cnt_row, 0, sizeof(int) * NN, stream);
  hipMemsetAsync(cnt_col, 0, sizeof(int) * NN, stream);
  k_count<<<(NE + TPB - 1) / TPB, TPB, 0, stream>>>(ei, cnt_row, cnt_col);
  k_scan2<<<2, 64, 0, stream>>>(cnt_row, row_off, cur_row, cnt_col, col_off, cur_col);
  k_fill_row<<<(NE + TPB - 1) / TPB, TPB, 0, stream>>>(ei, cur_row, eid_row);
  k_fill_col<<<(NE + TPB - 1) / TPB, TPB, 0, stream>>>(ei, eid_row, cur_col, slot_col);

  float* bufs[2] = {xb0, xb1};
  const float* xin = x0;
  for (int l = 0; l < 4; l++) {
    float* xout = bufs[l & 1];
    if (l == 0) {
      run_layer<16, 32>(xin, xout, L[0], ei, ea, row_off, col_off, eid_row, slot_col,
                        xp, root, Bb, msg, Vb, U2, uavail, stream);
    } else if (l == 1) {
      run_layer<32, 16>(xin, xout, L[1], ei, ea, row_off, col_off, eid_row, slot_col,
                        xp, root, Bb, msg, Vb, U2, uavail, stream);
    } else if (l == 2) {
      run_layer<16, 16>(xin, xout, L[2], ei, ea, row_off, col_off, eid_row, slot_col,
                        xp, root, Bb, msg, Vb, U2, uavail, stream);
    } else {
      run_layer<16, 16>(xin, xout, L[3], ei, ea, row_off, col_off, eid_row, slot_col,
                        xp, root, Bb, msg, Vb, U2, uavail, stream);
    }
    xin = xout;
  }
  k_final<<<(NE + TPB - 1) / TPB, TPB, 0, stream>>>(ei, xin, mw0, mb0, mw1, mb1, out);
}

// Round 6
// 583.115 us; speedup vs baseline: 1.3120x; 1.2804x over previous
//
#include <hip/hip_runtime.h>

#define NN 10000
#define NE 160000
static constexpr int TPB = 256;

typedef unsigned int uint32;

static __device__ __forceinline__ ushort f2bf(float f) {
  uint32 u = __float_as_uint(f);
  u += 0x7fff + ((u >> 16) & 1);   // round-to-nearest-even
  return (ushort)(u >> 16);
}
static __device__ __forceinline__ uint32 pk2bf(float a, float b) {
  return (uint32)f2bf(a) | ((uint32)f2bf(b) << 16);
}
static __device__ __forceinline__ float bflo(uint32 u) {
  return __uint_as_float(u << 16);
}
static __device__ __forceinline__ float bfhi(uint32 u) {
  return __uint_as_float(u & 0xffff0000u);
}

// ---------------- sort / CSR build ----------------

__global__ void k_count(const int* __restrict__ ei, int* __restrict__ cnt_row,
                        int* __restrict__ cnt_col) {
  int e = blockIdx.x * TPB + threadIdx.x;
  if (e >= NE) return;
  atomicAdd(&cnt_row[ei[e]], 1);
  atomicAdd(&cnt_col[ei[NE + e]], 1);
}

__global__ void k_scan2(const int* __restrict__ cnt_r, int* __restrict__ off_r, int* __restrict__ cur_r,
                        const int* __restrict__ cnt_c, int* __restrict__ off_c, int* __restrict__ cur_c) {
  const int* cnt = (blockIdx.x == 0) ? cnt_r : cnt_c;
  int* off = (blockIdx.x == 0) ? off_r : off_c;
  int* cur = (blockIdx.x == 0) ? cur_r : cur_c;
  int lane = threadIdx.x;  // 64 threads (one wave)
  int carry = 0;
  for (int base = 0; base < NN; base += 64) {
    int i = base + lane;
    int v = (i < NN) ? cnt[i] : 0;
    int s = v;
    #pragma unroll
    for (int dd = 1; dd < 64; dd <<= 1) {
      int t = __shfl_up(s, dd, 64);
      if (lane >= dd) s += t;
    }
    int excl = carry + s - v;
    if (i < NN) { off[i] = excl; cur[i] = excl; }
    carry += __shfl(s, 63, 64);
  }
  if (lane == 0) off[NN] = carry;
}

__global__ void k_fill_row(const int* __restrict__ ei, int* __restrict__ cur_row,
                           int* __restrict__ eid_row) {
  int e = blockIdx.x * TPB + threadIdx.x;
  if (e >= NE) return;
  int r = ei[e];
  int p = atomicAdd(&cur_row[r], 1);
  eid_row[p] = e;
}

__global__ void k_fill_col(const int* __restrict__ ei, const int* __restrict__ eid_row,
                           int* __restrict__ cur_col, int* __restrict__ slot_col) {
  int s = blockIdx.x * TPB + threadIdx.x;
  if (s >= NE) return;
  int e = eid_row[s];
  int c = ei[NE + e];
  int p = atomicAdd(&cur_col[c], 1);
  slot_col[p] = s;
}

// ---------------- per-layer kernels ----------------

// xp = x@pw^T + pb ; root = xp@rw^T + cb ; B[n,o] = sum_i xp[i]*eb2[i*D+o]
template<int DIN, int D>
__global__ void __launch_bounds__(TPB)
k_nodeprep(const float* __restrict__ x, const float* __restrict__ pw, const float* __restrict__ pb,
           const float* __restrict__ rw, const float* __restrict__ cb, const float* __restrict__ eb2,
           float* __restrict__ xp, float* __restrict__ root, float* __restrict__ Bb) {
  __shared__ float s_pw[D * DIN], s_rw[D * D], s_eb2[D * D], s_pb[D], s_cb[D];
  for (int t = threadIdx.x; t < D * DIN; t += TPB) s_pw[t] = pw[t];
  for (int t = threadIdx.x; t < D * D; t += TPB) { s_rw[t] = rw[t]; s_eb2[t] = eb2[t]; }
  for (int t = threadIdx.x; t < D; t += TPB) { s_pb[t] = pb[t]; s_cb[t] = cb[t]; }
  __syncthreads();
  int n = blockIdx.x * TPB + threadIdx.x;
  if (n >= NN) return;
  float xv[DIN];
  const float4* x4 = (const float4*)(x + (size_t)n * DIN);
  #pragma unroll
  for (int i = 0; i < DIN / 4; i++) {
    float4 v = x4[i];
    xv[4*i+0] = v.x; xv[4*i+1] = v.y; xv[4*i+2] = v.z; xv[4*i+3] = v.w;
  }
  float xpv[D];
  #pragma unroll
  for (int o = 0; o < D; o++) {
    float a = s_pb[o];
    #pragma unroll
    for (int i = 0; i < DIN; i++) a = fmaf(s_pw[o*DIN + i], xv[i], a);
    xpv[o] = a;
    xp[(size_t)n*D + o] = a;
  }
  #pragma unroll
  for (int o = 0; o < D; o++) {
    float a = s_cb[o];
    #pragma unroll
    for (int i = 0; i < D; i++) a = fmaf(s_rw[o*D + i], xpv[i], a);
    root[(size_t)n*D + o] = a;
  }
  #pragma unroll
  for (int o = 0; o < D; o++) {
    float a = 0.f;
    #pragma unroll
    for (int i = 0; i < D; i++) a = fmaf(xpv[i], s_eb2[i*D + o], a);
    Bb[(size_t)n*D + o] = a;
  }
}

// V[i][k*D+o] = ew2[(i*D+o)*128 + k]   (one-time per layer, 512 KB max)
__global__ void k_trans(const float* __restrict__ ew2, float* __restrict__ V, int D) {
  int t = blockIdx.x * TPB + threadIdx.x;
  int COLS = D * 128;
  if (t >= D * COLS) return;
  int i = t / COLS, c = t - i * COLS;
  int k = c / D, o = c - k * D;
  V[t] = ew2[((size_t)(i * D + o)) * 128 + k];
}

// Fused: one block per G consecutive source nodes.
// Phase B: compute the G U-rows (U[g][c] = sum_i xp[g][i]*V[i][c], c=k*D+o)
//          directly into LDS as packed bf16 pairs (row pad +4 words staggers banks).
// Phase C: run the group's contiguous row-sorted edges against LDS U-rows:
//          h = relu(ew1@ea+eb1); msg = h . U[g] + B[g].
template<int D, int G>
__global__ void __launch_bounds__(TPB)
k_fused(const int* __restrict__ eid_row, const int* __restrict__ row_off,
        const float* __restrict__ ea, const float* __restrict__ ew1,
        const float* __restrict__ eb1, const float* __restrict__ V,
        const float* __restrict__ xp, const float* __restrict__ Bb,
        float* __restrict__ msg) {
  constexpr int OQ = D / 4;            // threads per edge
  constexpr int EB = TPB / OQ;         // edges per inner iteration
  constexpr int COLS = D * 128;
  constexpr int UP = COLS / 2 + 4;     // u32 words per LDS U-row (pad 4 -> bank stagger)
  constexpr int NC2 = COLS / 2 / TPB;  // col-pairs per thread (8 for D32, 4 for D16)
  constexpr int CT = (NC2 < 4) ? NC2 : 4;  // col-pair tile

  __shared__ float  s_w1t[8 * 128];    // [i][k]
  __shared__ float  s_b1[128];
  __shared__ uint32 s_U[G * UP];       // packed bf16 U-rows
  __shared__ float  s_h[EB * 129];
  __shared__ float  s_ea[EB * 8];
  __shared__ float  s_xp[G][D];
  __shared__ float  s_B[G * D];
  __shared__ int    s_off[G + 1];

  int tid = threadIdx.x;
  int n0 = blockIdx.x * G;
  int GA = NN - n0; if (GA > G) GA = G;

  // ---- phase A: stage weights + per-node vectors ----
  for (int t = tid; t < 1024; t += TPB) {
    int k = t >> 3, i = t & 7;
    s_w1t[i * 128 + k] = ew1[t];
  }
  for (int t = tid; t < 128; t += TPB) s_b1[t] = eb1[t];
  for (int t = tid; t < G * D; t += TPB) {
    int g = t / D, i = t % D;
    s_xp[g][i] = (g < GA) ? xp[(size_t)(n0 + g) * D + i] : 0.f;
    s_B[t]     = (g < GA) ? Bb[(size_t)(n0 + g) * D + i] : 0.f;
  }
  if (tid <= GA) s_off[tid] = row_off[n0 + tid];
  __syncthreads();

  // ---- phase B: U-rows into LDS (register-tiled: CT col-pairs x G nodes) ----
  const float2* V2 = (const float2*)V;
  for (int t0 = 0; t0 < NC2; t0 += CT) {
    float2 acc[G][CT];
    #pragma unroll
    for (int g = 0; g < G; g++)
      #pragma unroll
      for (int j = 0; j < CT; j++) acc[g][j] = {0.f, 0.f};
    for (int i = 0; i < D; i++) {
      float2 v[CT];
      #pragma unroll
      for (int j = 0; j < CT; j++)
        v[j] = V2[(size_t)i * (COLS / 2) + (t0 + j) * TPB + tid];
      #pragma unroll
      for (int g = 0; g < G; g++) {
        float xg = s_xp[g][i];
        #pragma unroll
        for (int j = 0; j < CT; j++) {
          acc[g][j].x = fmaf(xg, v[j].x, acc[g][j].x);
          acc[g][j].y = fmaf(xg, v[j].y, acc[g][j].y);
        }
      }
    }
    #pragma unroll
    for (int g = 0; g < G; g++)
      #pragma unroll
      for (int j = 0; j < CT; j++)
        s_U[g * UP + (t0 + j) * TPB + tid] = pk2bf(acc[g][j].x, acc[g][j].y);
  }

  // ---- phase C: edges of the group (contiguous sorted slots) ----
  int p0 = row_off[n0], p1 = row_off[n0 + GA];
  int el = tid / OQ, oq = tid % OQ;
  for (int pc = p0; pc < p1; pc += EB) {
    int cnt = p1 - pc; if (cnt > EB) cnt = EB;
    __syncthreads();   // first iter: phase A/B done; later: protect s_ea/s_h reuse
    for (int t = tid; t < cnt * 8; t += TPB) {
      int e2 = t >> 3, i = t & 7;
      s_ea[t] = ea[(size_t)eid_row[pc + e2] * 8 + i];
    }
    __syncthreads();
    for (int t = tid; t < cnt * 128; t += TPB) {
      int e2 = t >> 7, k = t & 127;
      float a = s_b1[k];
      #pragma unroll
      for (int i = 0; i < 8; i++) a = fmaf(s_ea[e2 * 8 + i], s_w1t[i * 128 + k], a);
      s_h[e2 * 129 + k] = fmaxf(a, 0.f);
    }
    __syncthreads();
    if (el < cnt) {
      int s = pc + el;
      int g = 0;
      #pragma unroll
      for (int q = 1; q < G; q++) g += (q < GA && s >= s_off[q]) ? 1 : 0;
      const float* hp = s_h + el * 129;
      const uint32* up = s_U + g * UP + oq * 2;
      float4 acc = {0.f, 0.f, 0.f, 0.f};
      #pragma unroll 8
      for (int k = 0; k < 128; k++) {
        float hk = hp[k];
        uint32 u0 = up[k * (D / 2)];
        uint32 u1 = up[k * (D / 2) + 1];
        acc.x = fmaf(hk, bflo(u0), acc.x);
        acc.y = fmaf(hk, bfhi(u0), acc.y);
        acc.z = fmaf(hk, bflo(u1), acc.z);
        acc.w = fmaf(hk, bfhi(u1), acc.w);
      }
      float4 b = ((const float4*)(s_B + g * D))[oq];
      acc.x += b.x; acc.y += b.y; acc.z += b.z; acc.w += b.w;
      ((float4*)(msg + (size_t)s * D))[oq] = acc;
    }
  }
}

// gather aggregation by col-CSR (deterministic), then x = relu(agg/deg + root) + xp
template<int D>
__global__ void __launch_bounds__(TPB)
k_agg(const int* __restrict__ col_off, const int* __restrict__ slot_col,
      const float* __restrict__ msg, const float* __restrict__ root,
      const float* __restrict__ xp, float* __restrict__ xout) {
  constexpr int GP = TPB / D;
  int g = threadIdx.x / D, o = threadIdx.x % D;
  int n = blockIdx.x * GP + g;
  if (n >= NN) return;
  int p0 = col_off[n], p1 = col_off[n + 1];
  float acc = 0.f;
  for (int p = p0; p < p1; p++) {
    int sc = slot_col[p];
    acc += msg[(size_t)sc * D + o];
  }
  float deg = (p1 > p0) ? (float)(p1 - p0) : 1.f;
  float conv = acc / deg + root[(size_t)n * D + o];
  float rl = conv > 0.f ? conv : 0.f;
  xout[(size_t)n * D + o] = rl + xp[(size_t)n * D + o];
}

// final edge MLP: out = relu((x[row]+x[col]) @ mw0^T + mb0) @ mw1^T + mb1
__global__ void __launch_bounds__(TPB)
k_final(const int* __restrict__ ei, const float* __restrict__ x,
        const float* __restrict__ mw0, const float* __restrict__ mb0,
        const float* __restrict__ mw1, const float* __restrict__ mb1,
        float* __restrict__ out) {
  __shared__ float s_w0[256], s_b0[16], s_w1[16], s_b1;
  for (int t = threadIdx.x; t < 256; t += TPB) s_w0[t] = mw0[t];
  if (threadIdx.x < 16) { s_b0[threadIdx.x] = mb0[threadIdx.x]; s_w1[threadIdx.x] = mw1[threadIdx.x]; }
  if (threadIdx.x == 0) s_b1 = mb1[0];
  __syncthreads();
  int e = blockIdx.x * TPB + threadIdx.x;
  if (e >= NE) return;
  int r = ei[e], c = ei[NE + e];
  const float4* xr4 = (const float4*)(x + (size_t)r * 16);
  const float4* xc4 = (const float4*)(x + (size_t)c * 16);
  float er[16];
  #pragma unroll
  for (int q = 0; q < 4; q++) {
    float4 vr = xr4[q], vc = xc4[q];
    er[4*q+0] = vr.x + vc.x; er[4*q+1] = vr.y + vc.y;
    er[4*q+2] = vr.z + vc.z; er[4*q+3] = vr.w + vc.w;
  }
  float o = s_b1;
  #pragma unroll
  for (int j = 0; j < 16; j++) {
    float t = s_b0[j];
    #pragma unroll
    for (int k = 0; k < 16; k++) t = fmaf(er[k], s_w0[j * 16 + k], t);
    t = fmaxf(t, 0.f);
    o = fmaf(t, s_w1[j], o);
  }
  out[e] = o;
}

// ---------------- host side ----------------

struct LayerPtrs {
  const float *pw, *pb, *ew1, *eb1, *ew2, *eb2, *rw, *cb;
};

template<int DIN, int D, int G>
static void run_layer(const float* xin, float* xout, const LayerPtrs& L,
                      const int* ei, const float* ea,
                      const int* row_off, const int* col_off,
                      const int* eid_row, const int* slot_col,
                      float* xp, float* root, float* Bb, float* msg, float* Vb,
                      hipStream_t stream) {
  k_nodeprep<DIN, D><<<(NN + TPB - 1) / TPB, TPB, 0, stream>>>(
      xin, L.pw, L.pb, L.rw, L.cb, L.eb2, xp, root, Bb);
  constexpr int COLS = D * 128;
  k_trans<<<(D * COLS + TPB - 1) / TPB, TPB, 0, stream>>>(L.ew2, Vb, D);
  k_fused<D, G><<<(NN + G - 1) / G, TPB, 0, stream>>>(
      eid_row, row_off, ea, L.ew1, L.eb1, Vb, xp, Bb, msg);
  k_agg<D><<<(NN * D + TPB - 1) / TPB, TPB, 0, stream>>>(
      col_off, slot_col, msg, root, xp, xout);
}

extern "C" void kernel_launch(void* const* d_in, const int* in_sizes, int n_in,
                              void* d_out, int out_size, void* d_ws, size_t ws_size,
                              hipStream_t stream) {
  (void)in_sizes; (void)n_in; (void)out_size; (void)ws_size;
  const float* x0 = (const float*)d_in[0];
  const float* ea = (const float*)d_in[1];
  const int* ei = (const int*)d_in[2];
  LayerPtrs L[4];
  for (int l = 0; l < 4; l++) {
    L[l].pw  = (const float*)d_in[3 + 8 * l];
    L[l].pb  = (const float*)d_in[4 + 8 * l];
    L[l].ew1 = (const float*)d_in[5 + 8 * l];
    L[l].eb1 = (const float*)d_in[6 + 8 * l];
    L[l].ew2 = (const float*)d_in[7 + 8 * l];
    L[l].eb2 = (const float*)d_in[8 + 8 * l];
    L[l].rw  = (const float*)d_in[9 + 8 * l];
    L[l].cb  = (const float*)d_in[10 + 8 * l];
  }
  const float* mw0 = (const float*)d_in[35];
  const float* mb0 = (const float*)d_in[36];
  const float* mw1 = (const float*)d_in[37];
  const float* mb1 = (const float*)d_in[38];
  float* out = (float*)d_out;

  char* w = (char*)d_ws;
  size_t off = 0;
  auto alloc = [&](size_t b) -> void* {
    void* p = w + off;
    off = (off + b + 255) & ~(size_t)255;
    return p;
  };
  int* cnt_row  = (int*)alloc(sizeof(int) * NN);
  int* cnt_col  = (int*)alloc(sizeof(int) * NN);
  int* row_off  = (int*)alloc(sizeof(int) * (NN + 1));
  int* col_off  = (int*)alloc(sizeof(int) * (NN + 1));
  int* cur_row  = (int*)alloc(sizeof(int) * NN);
  int* cur_col  = (int*)alloc(sizeof(int) * NN);
  int* eid_row  = (int*)alloc(sizeof(int) * NE);
  int* slot_col = (int*)alloc(sizeof(int) * NE);
  float* xb0  = (float*)alloc(sizeof(float) * NN * 32);
  float* xb1  = (float*)alloc(sizeof(float) * NN * 32);
  float* xp   = (float*)alloc(sizeof(float) * NN * 32);
  float* root = (float*)alloc(sizeof(float) * NN * 32);
  float* Bb   = (float*)alloc(sizeof(float) * NN * 32);
  float* msg  = (float*)alloc(sizeof(float) * NE * 32);
  float* Vb   = (float*)alloc(sizeof(float) * 128 * 32 * 32);  // 512 KB max

  hipMemsetAsync(cnt_row, 0, sizeof(int) * NN, stream);
  hipMemsetAsync(cnt_col, 0, sizeof(int) * NN, stream);
  k_count<<<(NE + TPB - 1) / TPB, TPB, 0, stream>>>(ei, cnt_row, cnt_col);
  k_scan2<<<2, 64, 0, stream>>>(cnt_row, row_off, cur_row, cnt_col, col_off, cur_col);
  k_fill_row<<<(NE + TPB - 1) / TPB, TPB, 0, stream>>>(ei, cur_row, eid_row);
  k_fill_col<<<(NE + TPB - 1) / TPB, TPB, 0, stream>>>(ei, eid_row, cur_col, slot_col);

  float* bufs[2] = {xb0, xb1};
  const float* xin = x0;
  for (int l = 0; l < 4; l++) {
    float* xout = bufs[l & 1];
    if (l == 0) {
      run_layer<16, 32, 6>(xin, xout, L[0], ei, ea, row_off, col_off, eid_row, slot_col,
                           xp, root, Bb, msg, Vb, stream);
    } else if (l == 1) {
      run_layer<32, 16, 8>(xin, xout, L[1], ei, ea, row_off, col_off, eid_row, slot_col,
                           xp, root, Bb, msg, Vb, stream);
    } else if (l == 2) {
      run_layer<16, 16, 8>(xin, xout, L[2], ei, ea, row_off, col_off, eid_row, slot_col,
                           xp, root, Bb, msg, Vb, stream);
    } else {
      run_layer<16, 16, 8>(xin, xout, L[3], ei, ea, row_off, col_off, eid_row, slot_col,
                           xp, root, Bb, msg, Vb, stream);
    }
    xin = xout;
  }
  k_final<<<(NE + TPB - 1) / TPB, TPB, 0, stream>>>(ei, xin, mw0, mb0, mw1, mb1, out);
}

// Round 7
// 559.206 us; speedup vs baseline: 1.3681x; 1.0428x over previous
//
#include <hip/hip_runtime.h>

#define NN 10000
#define NE 160000
static constexpr int TPB = 256;

typedef unsigned int uint32;
typedef float v2f __attribute__((ext_vector_type(2)));

static __device__ __forceinline__ ushort f2bf(float f) {
  uint32 u = __float_as_uint(f);
  u += 0x7fff + ((u >> 16) & 1);   // round-to-nearest-even
  return (ushort)(u >> 16);
}
static __device__ __forceinline__ uint32 pk2bf(float a, float b) {
  return (uint32)f2bf(a) | ((uint32)f2bf(b) << 16);
}
static __device__ __forceinline__ float bflo(uint32 u) {
  return __uint_as_float(u << 16);
}
static __device__ __forceinline__ float bfhi(uint32 u) {
  return __uint_as_float(u & 0xffff0000u);
}

// ---------------- sort / CSR build ----------------

__global__ void k_count(const int* __restrict__ ei, int* __restrict__ cnt_row,
                        int* __restrict__ cnt_col) {
  int e = blockIdx.x * TPB + threadIdx.x;
  if (e >= NE) return;
  atomicAdd(&cnt_row[ei[e]], 1);
  atomicAdd(&cnt_col[ei[NE + e]], 1);
}

__global__ void k_scan2(const int* __restrict__ cnt_r, int* __restrict__ off_r, int* __restrict__ cur_r,
                        const int* __restrict__ cnt_c, int* __restrict__ off_c, int* __restrict__ cur_c) {
  const int* cnt = (blockIdx.x == 0) ? cnt_r : cnt_c;
  int* off = (blockIdx.x == 0) ? off_r : off_c;
  int* cur = (blockIdx.x == 0) ? cur_r : cur_c;
  int lane = threadIdx.x;  // 64 threads (one wave)
  int carry = 0;
  for (int base = 0; base < NN; base += 64) {
    int i = base + lane;
    int v = (i < NN) ? cnt[i] : 0;
    int s = v;
    #pragma unroll
    for (int dd = 1; dd < 64; dd <<= 1) {
      int t = __shfl_up(s, dd, 64);
      if (lane >= dd) s += t;
    }
    int excl = carry + s - v;
    if (i < NN) { off[i] = excl; cur[i] = excl; }
    carry += __shfl(s, 63, 64);
  }
  if (lane == 0) off[NN] = carry;
}

__global__ void k_fill_row(const int* __restrict__ ei, int* __restrict__ cur_row,
                           int* __restrict__ eid_row) {
  int e = blockIdx.x * TPB + threadIdx.x;
  if (e >= NE) return;
  int r = ei[e];
  int p = atomicAdd(&cur_row[r], 1);
  eid_row[p] = e;
}

__global__ void k_fill_col(const int* __restrict__ ei, const int* __restrict__ eid_row,
                           int* __restrict__ cur_col, int* __restrict__ slot_col) {
  int s = blockIdx.x * TPB + threadIdx.x;
  if (s >= NE) return;
  int e = eid_row[s];
  int c = ei[NE + e];
  int p = atomicAdd(&cur_col[c], 1);
  slot_col[p] = s;
}

// ---------------- per-layer kernels ----------------

// xp = x@pw^T + pb ; root = xp@rw^T + cb ; B[n,o] = sum_i xp[i]*eb2[i*D+o]
template<int DIN, int D>
__global__ void __launch_bounds__(TPB)
k_nodeprep(const float* __restrict__ x, const float* __restrict__ pw, const float* __restrict__ pb,
           const float* __restrict__ rw, const float* __restrict__ cb, const float* __restrict__ eb2,
           float* __restrict__ xp, float* __restrict__ root, float* __restrict__ Bb) {
  __shared__ float s_pw[D * DIN], s_rw[D * D], s_eb2[D * D], s_pb[D], s_cb[D];
  for (int t = threadIdx.x; t < D * DIN; t += TPB) s_pw[t] = pw[t];
  for (int t = threadIdx.x; t < D * D; t += TPB) { s_rw[t] = rw[t]; s_eb2[t] = eb2[t]; }
  for (int t = threadIdx.x; t < D; t += TPB) { s_pb[t] = pb[t]; s_cb[t] = cb[t]; }
  __syncthreads();
  int n = blockIdx.x * TPB + threadIdx.x;
  if (n >= NN) return;
  float xv[DIN];
  const float4* x4 = (const float4*)(x + (size_t)n * DIN);
  #pragma unroll
  for (int i = 0; i < DIN / 4; i++) {
    float4 v = x4[i];
    xv[4*i+0] = v.x; xv[4*i+1] = v.y; xv[4*i+2] = v.z; xv[4*i+3] = v.w;
  }
  float xpv[D];
  #pragma unroll
  for (int o = 0; o < D; o++) {
    float a = s_pb[o];
    #pragma unroll
    for (int i = 0; i < DIN; i++) a = fmaf(s_pw[o*DIN + i], xv[i], a);
    xpv[o] = a;
    xp[(size_t)n*D + o] = a;
  }
  #pragma unroll
  for (int o = 0; o < D; o++) {
    float a = s_cb[o];
    #pragma unroll
    for (int i = 0; i < D; i++) a = fmaf(s_rw[o*D + i], xpv[i], a);
    root[(size_t)n*D + o] = a;
  }
  #pragma unroll
  for (int o = 0; o < D; o++) {
    float a = 0.f;
    #pragma unroll
    for (int i = 0; i < D; i++) a = fmaf(xpv[i], s_eb2[i*D + o], a);
    Bb[(size_t)n*D + o] = a;
  }
}

// V[i][k*D+o] = ew2[(i*D+o)*128 + k]   (one-time per layer, 512 KB max)
__global__ void k_trans(const float* __restrict__ ew2, float* __restrict__ V, int D) {
  int t = blockIdx.x * TPB + threadIdx.x;
  int COLS = D * 128;
  if (t >= D * COLS) return;
  int i = t / COLS, c = t - i * COLS;
  int k = c / D, o = c - k * D;
  V[t] = ew2[((size_t)(i * D + o)) * 128 + k];
}

// Fused: one block per G consecutive source nodes.
// Phase B: U-rows (bf16 o-pairs) into LDS.  Phase C: h = relu(ew1@ea+eb1)
// packed bf16 into LDS, then msg = h . U[g] + B[g] with b64 U reads.
template<int D, int G>
__global__ void __launch_bounds__(TPB)
k_fused(const int* __restrict__ eid_row, const int* __restrict__ row_off,
        const float* __restrict__ ea, const float* __restrict__ ew1,
        const float* __restrict__ eb1, const float* __restrict__ V,
        const float* __restrict__ xp, const float* __restrict__ Bb,
        float* __restrict__ msg) {
  constexpr int OQ = D / 4;            // threads per edge
  constexpr int EB = TPB / OQ;         // edges per inner iteration
  constexpr int COLS = D * 128;
  constexpr int UP = COLS / 2 + 4;     // u32 words per LDS U-row (pad -> bank stagger)
  constexpr int NC2 = COLS / 2 / TPB;  // col-pairs per thread (8 for D32, 4 for D16)
  constexpr int CT = (NC2 < 4) ? NC2 : 4;  // col-pair tile

  __shared__ float  s_w1t[8 * 128];    // [i][k]
  __shared__ float  s_b1[128];
  __shared__ __align__(16) uint32 s_U[G * UP];   // packed bf16 U-rows (o-pairs)
  __shared__ __align__(16) uint32 s_hp[EB * 65]; // packed bf16 h (k-pairs), stride 65
  __shared__ float  s_ea[EB * 8];
  __shared__ float  s_xp[G][D];
  __shared__ float  s_B[G * D];
  __shared__ int    s_off[G + 1];

  int tid = threadIdx.x;
  int n0 = blockIdx.x * G;
  int GA = NN - n0; if (GA > G) GA = G;

  // ---- phase A: stage weights + per-node vectors ----
  for (int t = tid; t < 1024; t += TPB) {
    int k = t >> 3, i = t & 7;
    s_w1t[i * 128 + k] = ew1[t];
  }
  for (int t = tid; t < 128; t += TPB) s_b1[t] = eb1[t];
  for (int t = tid; t < G * D; t += TPB) {
    int g = t / D, i = t % D;
    s_xp[g][i] = (g < GA) ? xp[(size_t)(n0 + g) * D + i] : 0.f;
    s_B[t]     = (g < GA) ? Bb[(size_t)(n0 + g) * D + i] : 0.f;
  }
  if (tid <= GA) s_off[tid] = row_off[n0 + tid];
  __syncthreads();

  // ---- phase B: U-rows into LDS (register-tiled: CT col-pairs x G nodes) ----
  const float2* V2 = (const float2*)V;
  for (int t0 = 0; t0 < NC2; t0 += CT) {
    float2 acc[G][CT];
    #pragma unroll
    for (int g = 0; g < G; g++)
      #pragma unroll
      for (int j = 0; j < CT; j++) acc[g][j] = {0.f, 0.f};
    for (int i = 0; i < D; i++) {
      float2 v[CT];
      #pragma unroll
      for (int j = 0; j < CT; j++)
        v[j] = V2[(size_t)i * (COLS / 2) + (t0 + j) * TPB + tid];
      #pragma unroll
      for (int g = 0; g < G; g++) {
        float xg = s_xp[g][i];
        #pragma unroll
        for (int j = 0; j < CT; j++) {
          acc[g][j].x = fmaf(xg, v[j].x, acc[g][j].x);
          acc[g][j].y = fmaf(xg, v[j].y, acc[g][j].y);
        }
      }
    }
    #pragma unroll
    for (int g = 0; g < G; g++)
      #pragma unroll
      for (int j = 0; j < CT; j++)
        s_U[g * UP + (t0 + j) * TPB + tid] = pk2bf(acc[g][j].x, acc[g][j].y);
  }

  // ---- phase C: edges of the group (contiguous sorted slots) ----
  int p0 = row_off[n0], p1 = row_off[n0 + GA];
  int el = tid / OQ, oq = tid % OQ;
  for (int pc = p0; pc < p1; pc += EB) {
    int cnt = p1 - pc; if (cnt > EB) cnt = EB;
    __syncthreads();   // first iter: phase A/B done; later: protect s_ea/s_hp reuse
    for (int t = tid; t < cnt * 8; t += TPB) {
      int e2 = t >> 3, i = t & 7;
      s_ea[t] = ea[(size_t)eid_row[pc + e2] * 8 + i];
    }
    __syncthreads();
    // h packed as bf16 k-pairs
    for (int t = tid; t < cnt * 64; t += TPB) {
      int e2 = t >> 6, k2 = t & 63;
      float a0 = s_b1[2 * k2], a1 = s_b1[2 * k2 + 1];
      #pragma unroll
      for (int i = 0; i < 8; i++) {
        float e = s_ea[e2 * 8 + i];
        a0 = fmaf(e, s_w1t[i * 128 + 2 * k2], a0);
        a1 = fmaf(e, s_w1t[i * 128 + 2 * k2 + 1], a1);
      }
      s_hp[e2 * 65 + k2] = pk2bf(fmaxf(a0, 0.f), fmaxf(a1, 0.f));
    }
    __syncthreads();
    if (el < cnt) {
      int s = pc + el;
      int g = 0;
      #pragma unroll
      for (int q = 1; q < G; q++) g += (q < GA && s >= s_off[q]) ? 1 : 0;
      const uint32* up = s_U + g * UP + oq * 2;
      const uint32* hp = s_hp + el * 65;
      v2f acc01 = {0.f, 0.f}, acc23 = {0.f, 0.f};
      #pragma unroll 8
      for (int k2 = 0; k2 < 64; k2++) {
        uint32 hw = hp[k2];
        float h0 = bflo(hw), h1 = bfhi(hw);
        uint2 ua = *(const uint2*)(up + (2 * k2) * (D / 2));
        uint2 ub = *(const uint2*)(up + (2 * k2 + 1) * (D / 2));
        v2f a0 = {bflo(ua.x), bfhi(ua.x)};
        v2f a1 = {bflo(ua.y), bfhi(ua.y)};
        v2f b0 = {bflo(ub.x), bfhi(ub.x)};
        v2f b1 = {bflo(ub.y), bfhi(ub.y)};
        acc01 += h0 * a0 + h1 * b0;
        acc23 += h0 * a1 + h1 * b1;
      }
      float4 b = ((const float4*)(s_B + g * D))[oq];
      float4 o4 = {acc01.x + b.x, acc01.y + b.y, acc23.x + b.z, acc23.y + b.w};
      ((float4*)(msg + (size_t)s * D))[oq] = o4;
    }
  }
}

// gather aggregation by col-CSR (deterministic), then x = relu(agg/deg + root) + xp
template<int D>
__global__ void __launch_bounds__(TPB)
k_agg(const int* __restrict__ col_off, const int* __restrict__ slot_col,
      const float* __restrict__ msg, const float* __restrict__ root,
      const float* __restrict__ xp, float* __restrict__ xout) {
  constexpr int GP = TPB / D;
  int g = threadIdx.x / D, o = threadIdx.x % D;
  int n = blockIdx.x * GP + g;
  if (n >= NN) return;
  int p0 = col_off[n], p1 = col_off[n + 1];
  float acc = 0.f;
  for (int p = p0; p < p1; p++) {
    int sc = slot_col[p];
    acc += msg[(size_t)sc * D + o];
  }
  float deg = (p1 > p0) ? (float)(p1 - p0) : 1.f;
  float conv = acc / deg + root[(size_t)n * D + o];
  float rl = conv > 0.f ? conv : 0.f;
  xout[(size_t)n * D + o] = rl + xp[(size_t)n * D + o];
}

// final edge MLP: out = relu((x[row]+x[col]) @ mw0^T + mb0) @ mw1^T + mb1
__global__ void __launch_bounds__(TPB)
k_final(const int* __restrict__ ei, const float* __restrict__ x,
        const float* __restrict__ mw0, const float* __restrict__ mb0,
        const float* __restrict__ mw1, const float* __restrict__ mb1,
        float* __restrict__ out) {
  __shared__ float s_w0[256], s_b0[16], s_w1[16], s_b1;
  for (int t = threadIdx.x; t < 256; t += TPB) s_w0[t] = mw0[t];
  if (threadIdx.x < 16) { s_b0[threadIdx.x] = mb0[threadIdx.x]; s_w1[threadIdx.x] = mw1[threadIdx.x]; }
  if (threadIdx.x == 0) s_b1 = mb1[0];
  __syncthreads();
  int e = blockIdx.x * TPB + threadIdx.x;
  if (e >= NE) return;
  int r = ei[e], c = ei[NE + e];
  const float4* xr4 = (const float4*)(x + (size_t)r * 16);
  const float4* xc4 = (const float4*)(x + (size_t)c * 16);
  float er[16];
  #pragma unroll
  for (int q = 0; q < 4; q++) {
    float4 vr = xr4[q], vc = xc4[q];
    er[4*q+0] = vr.x + vc.x; er[4*q+1] = vr.y + vc.y;
    er[4*q+2] = vr.z + vc.z; er[4*q+3] = vr.w + vc.w;
  }
  float o = s_b1;
  #pragma unroll
  for (int j = 0; j < 16; j++) {
    float t = s_b0[j];
    #pragma unroll
    for (int k = 0; k < 16; k++) t = fmaf(er[k], s_w0[j * 16 + k], t);
    t = fmaxf(t, 0.f);
    o = fmaf(t, s_w1[j], o);
  }
  out[e] = o;
}

// ---------------- host side ----------------

struct LayerPtrs {
  const float *pw, *pb, *ew1, *eb1, *ew2, *eb2, *rw, *cb;
};

template<int DIN, int D, int G>
static void run_layer(const float* xin, float* xout, const LayerPtrs& L,
                      const int* ei, const float* ea,
                      const int* row_off, const int* col_off,
                      const int* eid_row, const int* slot_col,
                      float* xp, float* root, float* Bb, float* msg, float* Vb,
                      hipStream_t stream) {
  k_nodeprep<DIN, D><<<(NN + TPB - 1) / TPB, TPB, 0, stream>>>(
      xin, L.pw, L.pb, L.rw, L.cb, L.eb2, xp, root, Bb);
  constexpr int COLS = D * 128;
  k_trans<<<(D * COLS + TPB - 1) / TPB, TPB, 0, stream>>>(L.ew2, Vb, D);
  k_fused<D, G><<<(NN + G - 1) / G, TPB, 0, stream>>>(
      eid_row, row_off, ea, L.ew1, L.eb1, Vb, xp, Bb, msg);
  k_agg<D><<<(NN * D + TPB - 1) / TPB, TPB, 0, stream>>>(
      col_off, slot_col, msg, root, xp, xout);
}

extern "C" void kernel_launch(void* const* d_in, const int* in_sizes, int n_in,
                              void* d_out, int out_size, void* d_ws, size_t ws_size,
                              hipStream_t stream) {
  (void)in_sizes; (void)n_in; (void)out_size; (void)ws_size;
  const float* x0 = (const float*)d_in[0];
  const float* ea = (const float*)d_in[1];
  const int* ei = (const int*)d_in[2];
  LayerPtrs L[4];
  for (int l = 0; l < 4; l++) {
    L[l].pw  = (const float*)d_in[3 + 8 * l];
    L[l].pb  = (const float*)d_in[4 + 8 * l];
    L[l].ew1 = (const float*)d_in[5 + 8 * l];
    L[l].eb1 = (const float*)d_in[6 + 8 * l];
    L[l].ew2 = (const float*)d_in[7 + 8 * l];
    L[l].eb2 = (const float*)d_in[8 + 8 * l];
    L[l].rw  = (const float*)d_in[9 + 8 * l];
    L[l].cb  = (const float*)d_in[10 + 8 * l];
  }
  const float* mw0 = (const float*)d_in[35];
  const float* mb0 = (const float*)d_in[36];
  const float* mw1 = (const float*)d_in[37];
  const float* mb1 = (const float*)d_in[38];
  float* out = (float*)d_out;

  char* w = (char*)d_ws;
  size_t off = 0;
  auto alloc = [&](size_t b) -> void* {
    void* p = w + off;
    off = (off + b + 255) & ~(size_t)255;
    return p;
  };
  int* cnt_row  = (int*)alloc(sizeof(int) * NN);
  int* cnt_col  = (int*)alloc(sizeof(int) * NN);
  int* row_off  = (int*)alloc(sizeof(int) * (NN + 1));
  int* col_off  = (int*)alloc(sizeof(int) * (NN + 1));
  int* cur_row  = (int*)alloc(sizeof(int) * NN);
  int* cur_col  = (int*)alloc(sizeof(int) * NN);
  int* eid_row  = (int*)alloc(sizeof(int) * NE);
  int* slot_col = (int*)alloc(sizeof(int) * NE);
  float* xb0  = (float*)alloc(sizeof(float) * NN * 32);
  float* xb1  = (float*)alloc(sizeof(float) * NN * 32);
  float* xp   = (float*)alloc(sizeof(float) * NN * 32);
  float* root = (float*)alloc(sizeof(float) * NN * 32);
  float* Bb   = (float*)alloc(sizeof(float) * NN * 32);
  float* msg  = (float*)alloc(sizeof(float) * NE * 32);
  float* Vb   = (float*)alloc(sizeof(float) * 128 * 32 * 32);  // 512 KB max

  hipMemsetAsync(cnt_row, 0, sizeof(int) * NN, stream);
  hipMemsetAsync(cnt_col, 0, sizeof(int) * NN, stream);
  k_count<<<(NE + TPB - 1) / TPB, TPB, 0, stream>>>(ei, cnt_row, cnt_col);
  k_scan2<<<2, 64, 0, stream>>>(cnt_row, row_off, cur_row, cnt_col, col_off, cur_col);
  k_fill_row<<<(NE + TPB - 1) / TPB, TPB, 0, stream>>>(ei, cur_row, eid_row);
  k_fill_col<<<(NE + TPB - 1) / TPB, TPB, 0, stream>>>(ei, eid_row, cur_col, slot_col);

  float* bufs[2] = {xb0, xb1};
  const float* xin = x0;
  for (int l = 0; l < 4; l++) {
    float* xout = bufs[l & 1];
    if (l == 0) {
      run_layer<16, 32, 4>(xin, xout, L[0], ei, ea, row_off, col_off, eid_row, slot_col,
                           xp, root, Bb, msg, Vb, stream);
    } else if (l == 1) {
      run_layer<32, 16, 6>(xin, xout, L[1], ei, ea, row_off, col_off, eid_row, slot_col,
                           xp, root, Bb, msg, Vb, stream);
    } else if (l == 2) {
      run_layer<16, 16, 6>(xin, xout, L[2], ei, ea, row_off, col_off, eid_row, slot_col,
                           xp, root, Bb, msg, Vb, stream);
    } else {
      run_layer<16, 16, 6>(xin, xout, L[3], ei, ea, row_off, col_off, eid_row, slot_col,
                           xp, root, Bb, msg, Vb, stream);
    }
    xin = xout;
  }
  k_final<<<(NE + TPB - 1) / TPB, TPB, 0, stream>>>(ei, xin, mw0, mb0, mw1, mb1, out);
}

// Round 8
// 483.244 us; speedup vs baseline: 1.5832x; 1.1572x over previous
//
#include <hip/hip_runtime.h>

#define NN 10000
#define NE 160000
static constexpr int TPB = 256;

typedef unsigned int uint32;
typedef float v2f __attribute__((ext_vector_type(2)));

static __device__ __forceinline__ ushort f2bf(float f) {
  uint32 u = __float_as_uint(f);
  u += 0x7fff + ((u >> 16) & 1);   // round-to-nearest-even
  return (ushort)(u >> 16);
}
static __device__ __forceinline__ uint32 pk2bf(float a, float b) {
  return (uint32)f2bf(a) | ((uint32)f2bf(b) << 16);
}
// acc += a.lo*b.lo + a.hi*b.hi  (packed bf16 pairs, f32 accumulate)
static __device__ __forceinline__ void dot2bf(float& acc, uint32 a, uint32 b) {
  asm("v_dot2_f32_bf16 %0, %1, %2, %0" : "+v"(acc) : "v"(a), "v"(b));
}

// ---------------- sort / CSR build ----------------

__global__ void k_count(const int* __restrict__ ei, int* __restrict__ cnt_row,
                        int* __restrict__ cnt_col) {
  int e = blockIdx.x * TPB + threadIdx.x;
  if (e >= NE) return;
  atomicAdd(&cnt_row[ei[e]], 1);
  atomicAdd(&cnt_col[ei[NE + e]], 1);
}

__global__ void k_scan2(const int* __restrict__ cnt_r, int* __restrict__ off_r, int* __restrict__ cur_r,
                        const int* __restrict__ cnt_c, int* __restrict__ off_c, int* __restrict__ cur_c) {
  const int* cnt = (blockIdx.x == 0) ? cnt_r : cnt_c;
  int* off = (blockIdx.x == 0) ? off_r : off_c;
  int* cur = (blockIdx.x == 0) ? cur_r : cur_c;
  int lane = threadIdx.x;  // 64 threads (one wave)
  int carry = 0;
  for (int base = 0; base < NN; base += 64) {
    int i = base + lane;
    int v = (i < NN) ? cnt[i] : 0;
    int s = v;
    #pragma unroll
    for (int dd = 1; dd < 64; dd <<= 1) {
      int t = __shfl_up(s, dd, 64);
      if (lane >= dd) s += t;
    }
    int excl = carry + s - v;
    if (i < NN) { off[i] = excl; cur[i] = excl; }
    carry += __shfl(s, 63, 64);
  }
  if (lane == 0) off[NN] = carry;
}

__global__ void k_fill_row(const int* __restrict__ ei, int* __restrict__ cur_row,
                           int* __restrict__ eid_row) {
  int e = blockIdx.x * TPB + threadIdx.x;
  if (e >= NE) return;
  int r = ei[e];
  int p = atomicAdd(&cur_row[r], 1);
  eid_row[p] = e;
}

__global__ void k_fill_col(const int* __restrict__ ei, const int* __restrict__ eid_row,
                           int* __restrict__ cur_col, int* __restrict__ slot_col) {
  int s = blockIdx.x * TPB + threadIdx.x;
  if (s >= NE) return;
  int e = eid_row[s];
  int c = ei[NE + e];
  int p = atomicAdd(&cur_col[c], 1);
  slot_col[p] = s;
}

// ---------------- per-layer kernels ----------------

// xp = x@pw^T + pb ; root = xp@rw^T + cb ; B[n,o] = sum_i xp[i]*eb2[i*D+o]
template<int DIN, int D>
__global__ void __launch_bounds__(TPB)
k_nodeprep(const float* __restrict__ x, const float* __restrict__ pw, const float* __restrict__ pb,
           const float* __restrict__ rw, const float* __restrict__ cb, const float* __restrict__ eb2,
           float* __restrict__ xp, float* __restrict__ root, float* __restrict__ Bb) {
  __shared__ float s_pw[D * DIN], s_rw[D * D], s_eb2[D * D], s_pb[D], s_cb[D];
  for (int t = threadIdx.x; t < D * DIN; t += TPB) s_pw[t] = pw[t];
  for (int t = threadIdx.x; t < D * D; t += TPB) { s_rw[t] = rw[t]; s_eb2[t] = eb2[t]; }
  for (int t = threadIdx.x; t < D; t += TPB) { s_pb[t] = pb[t]; s_cb[t] = cb[t]; }
  __syncthreads();
  int n = blockIdx.x * TPB + threadIdx.x;
  if (n >= NN) return;
  float xv[DIN];
  const float4* x4 = (const float4*)(x + (size_t)n * DIN);
  #pragma unroll
  for (int i = 0; i < DIN / 4; i++) {
    float4 v = x4[i];
    xv[4*i+0] = v.x; xv[4*i+1] = v.y; xv[4*i+2] = v.z; xv[4*i+3] = v.w;
  }
  float xpv[D];
  #pragma unroll
  for (int o = 0; o < D; o++) {
    float a = s_pb[o];
    #pragma unroll
    for (int i = 0; i < DIN; i++) a = fmaf(s_pw[o*DIN + i], xv[i], a);
    xpv[o] = a;
    xp[(size_t)n*D + o] = a;
  }
  #pragma unroll
  for (int o = 0; o < D; o++) {
    float a = s_cb[o];
    #pragma unroll
    for (int i = 0; i < D; i++) a = fmaf(s_rw[o*D + i], xpv[i], a);
    root[(size_t)n*D + o] = a;
  }
  #pragma unroll
  for (int o = 0; o < D; o++) {
    float a = 0.f;
    #pragma unroll
    for (int i = 0; i < D; i++) a = fmaf(xpv[i], s_eb2[i*D + o], a);
    Bb[(size_t)n*D + o] = a;
  }
}

// V permuted so consecutive column pairs are (k, k+1) for a fixed o:
// c = k2*(2D) + 2o + p  <->  ew2[(i*D+o)*128 + 2*k2 + p]
__global__ void k_trans(const float* __restrict__ ew2, float* __restrict__ V, int D) {
  int t = blockIdx.x * TPB + threadIdx.x;
  int COLS = D * 128;
  if (t >= D * COLS) return;
  int i = t / COLS, c = t - i * COLS;
  int k2 = c / (2 * D);
  int rem = c - k2 * 2 * D;
  int o = rem >> 1, p = rem & 1;
  V[t] = ew2[((size_t)(i * D + o)) * 128 + 2 * k2 + p];
}

// Fused: one block per G consecutive source nodes.
// Phase B: U-rows (packed bf16 k-pairs, layout word[k2*D+o]) into LDS.
// Phase C: h = relu(ew1@ea+eb1) packed bf16 k-pairs; msg = h.U[g]+B[g] via v_dot2_f32_bf16.
template<int D, int G>
__global__ void __launch_bounds__(TPB)
k_fused(const int* __restrict__ eid_row, const int* __restrict__ row_off,
        const float* __restrict__ ea, const float* __restrict__ ew1,
        const float* __restrict__ eb1, const float* __restrict__ V,
        const float* __restrict__ xp, const float* __restrict__ Bb,
        float* __restrict__ msg) {
  constexpr int OQ = D / 4;            // threads per edge
  constexpr int EB = TPB / OQ;         // edges per inner iteration
  constexpr int COLS = D * 128;
  constexpr int UW = COLS / 2;         // u32 words per U-row
  constexpr int CT = UW / TPB;         // col-pair words per thread (8 for D32, 4 for D16)

  __shared__ float  s_w1t[8 * 128];    // [i][k]
  __shared__ float  s_b1[128];
  __shared__ __align__(16) uint32 s_U[G * UW];   // packed bf16 k-pairs: [g][k2*D+o]
  __shared__ __align__(16) uint32 s_hp[EB * 66]; // packed bf16 h k-pairs, stride 66 (8B-aligned)
  __shared__ float  s_ea[EB * 8];
  __shared__ float  s_xp[G][D];
  __shared__ float  s_B[G * D];
  __shared__ int    s_off[G + 1];

  int tid = threadIdx.x;
  int n0 = blockIdx.x * G;
  int GA = NN - n0; if (GA > G) GA = G;

  // ---- phase A: stage weights + per-node vectors ----
  for (int t = tid; t < 1024; t += TPB) {
    int k = t >> 3, i = t & 7;
    s_w1t[i * 128 + k] = ew1[t];
  }
  for (int t = tid; t < 128; t += TPB) s_b1[t] = eb1[t];
  for (int t = tid; t < G * D; t += TPB) {
    int g = t / D, i = t % D;
    s_xp[g][i] = (g < GA) ? xp[(size_t)(n0 + g) * D + i] : 0.f;
    s_B[t]     = (g < GA) ? Bb[(size_t)(n0 + g) * D + i] : 0.f;
  }
  if (tid <= GA) s_off[tid] = row_off[n0 + tid];
  __syncthreads();

  // ---- phase B: U-rows into LDS (register tile: CT col-pair words x G nodes) ----
  const float2* V2 = (const float2*)V;
  {
    float2 acc[G][CT];
    #pragma unroll
    for (int g = 0; g < G; g++)
      #pragma unroll
      for (int j = 0; j < CT; j++) acc[g][j] = {0.f, 0.f};
    for (int i = 0; i < D; i++) {
      float2 v[CT];
      #pragma unroll
      for (int j = 0; j < CT; j++)
        v[j] = V2[(size_t)i * UW + j * TPB + tid];
      #pragma unroll
      for (int g = 0; g < G; g++) {
        float xg = s_xp[g][i];
        #pragma unroll
        for (int j = 0; j < CT; j++) {
          acc[g][j].x = fmaf(xg, v[j].x, acc[g][j].x);
          acc[g][j].y = fmaf(xg, v[j].y, acc[g][j].y);
        }
      }
    }
    #pragma unroll
    for (int g = 0; g < G; g++)
      #pragma unroll
      for (int j = 0; j < CT; j++)
        s_U[g * UW + j * TPB + tid] = pk2bf(acc[g][j].x, acc[g][j].y);
  }

  // ---- phase C: edges of the group (contiguous sorted slots) ----
  int p0 = row_off[n0], p1 = row_off[n0 + GA];
  int el = tid / OQ, oq = tid % OQ;
  for (int pc = p0; pc < p1; pc += EB) {
    int cnt = p1 - pc; if (cnt > EB) cnt = EB;
    __syncthreads();   // first iter: phase A/B done; later: protect s_ea/s_hp reuse
    for (int t = tid; t < cnt * 8; t += TPB) {
      int e2 = t >> 3, i = t & 7;
      s_ea[t] = ea[(size_t)eid_row[pc + e2] * 8 + i];
    }
    __syncthreads();
    // h packed as bf16 k-pairs
    for (int t = tid; t < cnt * 64; t += TPB) {
      int e2 = t >> 6, k2 = t & 63;
      float a0 = s_b1[2 * k2], a1 = s_b1[2 * k2 + 1];
      #pragma unroll
      for (int i = 0; i < 8; i++) {
        float e = s_ea[e2 * 8 + i];
        a0 = fmaf(e, s_w1t[i * 128 + 2 * k2], a0);
        a1 = fmaf(e, s_w1t[i * 128 + 2 * k2 + 1], a1);
      }
      s_hp[e2 * 66 + k2] = pk2bf(fmaxf(a0, 0.f), fmaxf(a1, 0.f));
    }
    __syncthreads();
    if (el < cnt) {
      int s = pc + el;
      int g = 0;
      #pragma unroll
      for (int q = 1; q < G; q++) g += (q < GA && s >= s_off[q]) ? 1 : 0;
      const uint32* up = s_U + g * UW + oq * 4;
      const uint32* hp = s_hp + el * 66;
      float a0 = 0.f, a1 = 0.f, a2 = 0.f, a3 = 0.f;
      #pragma unroll 4
      for (int k4 = 0; k4 < 32; k4++) {
        uint2 hw = *(const uint2*)(hp + 2 * k4);
        uint4 u0 = *(const uint4*)(up + (2 * k4) * D);
        uint4 u1 = *(const uint4*)(up + (2 * k4 + 1) * D);
        dot2bf(a0, hw.x, u0.x); dot2bf(a1, hw.x, u0.y);
        dot2bf(a2, hw.x, u0.z); dot2bf(a3, hw.x, u0.w);
        dot2bf(a0, hw.y, u1.x); dot2bf(a1, hw.y, u1.y);
        dot2bf(a2, hw.y, u1.z); dot2bf(a3, hw.y, u1.w);
      }
      float4 b = ((const float4*)(s_B + g * D))[oq];
      float4 o4 = {a0 + b.x, a1 + b.y, a2 + b.z, a3 + b.w};
      ((float4*)(msg + (size_t)s * D))[oq] = o4;
    }
  }
}

// gather aggregation by col-CSR (deterministic), then x = relu(agg/deg + root) + xp
template<int D>
__global__ void __launch_bounds__(TPB)
k_agg(const int* __restrict__ col_off, const int* __restrict__ slot_col,
      const float* __restrict__ msg, const float* __restrict__ root,
      const float* __restrict__ xp, float* __restrict__ xout) {
  constexpr int GP = TPB / D;
  int g = threadIdx.x / D, o = threadIdx.x % D;
  int n = blockIdx.x * GP + g;
  if (n >= NN) return;
  int p0 = col_off[n], p1 = col_off[n + 1];
  float acc = 0.f;
  for (int p = p0; p < p1; p++) {
    int sc = slot_col[p];
    acc += msg[(size_t)sc * D + o];
  }
  float deg = (p1 > p0) ? (float)(p1 - p0) : 1.f;
  float conv = acc / deg + root[(size_t)n * D + o];
  float rl = conv > 0.f ? conv : 0.f;
  xout[(size_t)n * D + o] = rl + xp[(size_t)n * D + o];
}

// final edge MLP: out = relu((x[row]+x[col]) @ mw0^T + mb0) @ mw1^T + mb1
__global__ void __launch_bounds__(TPB)
k_final(const int* __restrict__ ei, const float* __restrict__ x,
        const float* __restrict__ mw0, const float* __restrict__ mb0,
        const float* __restrict__ mw1, const float* __restrict__ mb1,
        float* __restrict__ out) {
  __shared__ float s_w0[256], s_b0[16], s_w1[16], s_b1;
  for (int t = threadIdx.x; t < 256; t += TPB) s_w0[t] = mw0[t];
  if (threadIdx.x < 16) { s_b0[threadIdx.x] = mb0[threadIdx.x]; s_w1[threadIdx.x] = mw1[threadIdx.x]; }
  if (threadIdx.x == 0) s_b1 = mb1[0];
  __syncthreads();
  int e = blockIdx.x * TPB + threadIdx.x;
  if (e >= NE) return;
  int r = ei[e], c = ei[NE + e];
  const float4* xr4 = (const float4*)(x + (size_t)r * 16);
  const float4* xc4 = (const float4*)(x + (size_t)c * 16);
  float er[16];
  #pragma unroll
  for (int q = 0; q < 4; q++) {
    float4 vr = xr4[q], vc = xc4[q];
    er[4*q+0] = vr.x + vc.x; er[4*q+1] = vr.y + vc.y;
    er[4*q+2] = vr.z + vc.z; er[4*q+3] = vr.w + vc.w;
  }
  float o = s_b1;
  #pragma unroll
  for (int j = 0; j < 16; j++) {
    float t = s_b0[j];
    #pragma unroll
    for (int k = 0; k < 16; k++) t = fmaf(er[k], s_w0[j * 16 + k], t);
    t = fmaxf(t, 0.f);
    o = fmaf(t, s_w1[j], o);
  }
  out[e] = o;
}

// ---------------- host side ----------------

struct LayerPtrs {
  const float *pw, *pb, *ew1, *eb1, *ew2, *eb2, *rw, *cb;
};

template<int DIN, int D, int G>
static void run_layer(const float* xin, float* xout, const LayerPtrs& L,
                      const int* ei, const float* ea,
                      const int* row_off, const int* col_off,
                      const int* eid_row, const int* slot_col,
                      float* xp, float* root, float* Bb, float* msg, float* Vb,
                      hipStream_t stream) {
  k_nodeprep<DIN, D><<<(NN + TPB - 1) / TPB, TPB, 0, stream>>>(
      xin, L.pw, L.pb, L.rw, L.cb, L.eb2, xp, root, Bb);
  constexpr int COLS = D * 128;
  k_trans<<<(D * COLS + TPB - 1) / TPB, TPB, 0, stream>>>(L.ew2, Vb, D);
  k_fused<D, G><<<(NN + G - 1) / G, TPB, 0, stream>>>(
      eid_row, row_off, ea, L.ew1, L.eb1, Vb, xp, Bb, msg);
  k_agg<D><<<(NN * D + TPB - 1) / TPB, TPB, 0, stream>>>(
      col_off, slot_col, msg, root, xp, xout);
}

extern "C" void kernel_launch(void* const* d_in, const int* in_sizes, int n_in,
                              void* d_out, int out_size, void* d_ws, size_t ws_size,
                              hipStream_t stream) {
  (void)in_sizes; (void)n_in; (void)out_size; (void)ws_size;
  const float* x0 = (const float*)d_in[0];
  const float* ea = (const float*)d_in[1];
  const int* ei = (const int*)d_in[2];
  LayerPtrs L[4];
  for (int l = 0; l < 4; l++) {
    L[l].pw  = (const float*)d_in[3 + 8 * l];
    L[l].pb  = (const float*)d_in[4 + 8 * l];
    L[l].ew1 = (const float*)d_in[5 + 8 * l];
    L[l].eb1 = (const float*)d_in[6 + 8 * l];
    L[l].ew2 = (const float*)d_in[7 + 8 * l];
    L[l].eb2 = (const float*)d_in[8 + 8 * l];
    L[l].rw  = (const float*)d_in[9 + 8 * l];
    L[l].cb  = (const float*)d_in[10 + 8 * l];
  }
  const float* mw0 = (const float*)d_in[35];
  const float* mb0 = (const float*)d_in[36];
  const float* mw1 = (const float*)d_in[37];
  const float* mb1 = (const float*)d_in[38];
  float* out = (float*)d_out;

  char* w = (char*)d_ws;
  size_t off = 0;
  auto alloc = [&](size_t b) -> void* {
    void* p = w + off;
    off = (off + b + 255) & ~(size_t)255;
    return p;
  };
  int* cnt_row  = (int*)alloc(sizeof(int) * NN);
  int* cnt_col  = (int*)alloc(sizeof(int) * NN);
  int* row_off  = (int*)alloc(sizeof(int) * (NN + 1));
  int* col_off  = (int*)alloc(sizeof(int) * (NN + 1));
  int* cur_row  = (int*)alloc(sizeof(int) * NN);
  int* cur_col  = (int*)alloc(sizeof(int) * NN);
  int* eid_row  = (int*)alloc(sizeof(int) * NE);
  int* slot_col = (int*)alloc(sizeof(int) * NE);
  float* xb0  = (float*)alloc(sizeof(float) * NN * 32);
  float* xb1  = (float*)alloc(sizeof(float) * NN * 32);
  float* xp   = (float*)alloc(sizeof(float) * NN * 32);
  float* root = (float*)alloc(sizeof(float) * NN * 32);
  float* Bb   = (float*)alloc(sizeof(float) * NN * 32);
  float* msg  = (float*)alloc(sizeof(float) * NE * 32);
  float* Vb   = (float*)alloc(sizeof(float) * 128 * 32 * 32);  // 512 KB max

  hipMemsetAsync(cnt_row, 0, sizeof(int) * NN, stream);
  hipMemsetAsync(cnt_col, 0, sizeof(int) * NN, stream);
  k_count<<<(NE + TPB - 1) / TPB, TPB, 0, stream>>>(ei, cnt_row, cnt_col);
  k_scan2<<<2, 64, 0, stream>>>(cnt_row, row_off, cur_row, cnt_col, col_off, cur_col);
  k_fill_row<<<(NE + TPB - 1) / TPB, TPB, 0, stream>>>(ei, cur_row, eid_row);
  k_fill_col<<<(NE + TPB - 1) / TPB, TPB, 0, stream>>>(ei, eid_row, cur_col, slot_col);

  float* bufs[2] = {xb0, xb1};
  const float* xin = x0;
  for (int l = 0; l < 4; l++) {
    float* xout = bufs[l & 1];
    if (l == 0) {
      run_layer<16, 32, 4>(xin, xout, L[0], ei, ea, row_off, col_off, eid_row, slot_col,
                           xp, root, Bb, msg, Vb, stream);
    } else if (l == 1) {
      run_layer<32, 16, 6>(xin, xout, L[1], ei, ea, row_off, col_off, eid_row, slot_col,
                           xp, root, Bb, msg, Vb, stream);
    } else if (l == 2) {
      run_layer<16, 16, 6>(xin, xout, L[2], ei, ea, row_off, col_off, eid_row, slot_col,
                           xp, root, Bb, msg, Vb, stream);
    } else {
      run_layer<16, 16, 6>(xin, xout, L[3], ei, ea, row_off, col_off, eid_row, slot_col,
                           xp, root, Bb, msg, Vb, stream);
    }
    xin = xout;
  }
  k_final<<<(NE + TPB - 1) / TPB, TPB, 0, stream>>>(ei, xin, mw0, mb0, mw1, mb1, out);
}

// Round 9
// 453.550 us; speedup vs baseline: 1.6868x; 1.0655x over previous
//
#include <hip/hip_runtime.h>

#define NN 10000
#define NE 160000
static constexpr int TPB = 256;

typedef unsigned int uint32;

static __device__ __forceinline__ ushort f2bf(float f) {
  uint32 u = __float_as_uint(f);
  u += 0x7fff + ((u >> 16) & 1);   // round-to-nearest-even
  return (ushort)(u >> 16);
}
static __device__ __forceinline__ uint32 pk2bf(float a, float b) {
  return (uint32)f2bf(a) | ((uint32)f2bf(b) << 16);
}
// acc += a.lo*b.lo + a.hi*b.hi  (packed bf16 pairs, f32 accumulate)
static __device__ __forceinline__ void dot2bf(float& acc, uint32 a, uint32 b) {
  asm("v_dot2_f32_bf16 %0, %1, %2, %0" : "+v"(acc) : "v"(a), "v"(b));
}

// ---------------- sort / CSR build ----------------

__global__ void k_count(const int* __restrict__ ei, int* __restrict__ cnt_row,
                        int* __restrict__ cnt_col) {
  int e = blockIdx.x * TPB + threadIdx.x;
  if (e >= NE) return;
  atomicAdd(&cnt_row[ei[e]], 1);
  atomicAdd(&cnt_col[ei[NE + e]], 1);
}

__global__ void k_scan2(const int* __restrict__ cnt_r, int* __restrict__ off_r, int* __restrict__ cur_r,
                        const int* __restrict__ cnt_c, int* __restrict__ off_c, int* __restrict__ cur_c) {
  const int* cnt = (blockIdx.x == 0) ? cnt_r : cnt_c;
  int* off = (blockIdx.x == 0) ? off_r : off_c;
  int* cur = (blockIdx.x == 0) ? cur_r : cur_c;
  int lane = threadIdx.x;  // 64 threads (one wave)
  int carry = 0;
  for (int base = 0; base < NN; base += 64) {
    int i = base + lane;
    int v = (i < NN) ? cnt[i] : 0;
    int s = v;
    #pragma unroll
    for (int dd = 1; dd < 64; dd <<= 1) {
      int t = __shfl_up(s, dd, 64);
      if (lane >= dd) s += t;
    }
    int excl = carry + s - v;
    if (i < NN) { off[i] = excl; cur[i] = excl; }
    carry += __shfl(s, 63, 64);
  }
  if (lane == 0) off[NN] = carry;
}

__global__ void k_fill_row(const int* __restrict__ ei, int* __restrict__ cur_row,
                           int* __restrict__ eid_row) {
  int e = blockIdx.x * TPB + threadIdx.x;
  if (e >= NE) return;
  int r = ei[e];
  int p = atomicAdd(&cur_row[r], 1);
  eid_row[p] = e;
}

__global__ void k_fill_col(const int* __restrict__ ei, const int* __restrict__ eid_row,
                           int* __restrict__ cur_col, int* __restrict__ slot_col) {
  int s = blockIdx.x * TPB + threadIdx.x;
  if (s >= NE) return;
  int e = eid_row[s];
  int c = ei[NE + e];
  int p = atomicAdd(&cur_col[c], 1);
  slot_col[p] = s;
}

// ---------------- per-layer kernels ----------------

// xp = x@pw^T + pb ; root = xp@rw^T + cb ; B[n,o] = sum_i xp[i]*eb2[i*D+o]
template<int DIN, int D>
__global__ void __launch_bounds__(TPB)
k_nodeprep(const float* __restrict__ x, const float* __restrict__ pw, const float* __restrict__ pb,
           const float* __restrict__ rw, const float* __restrict__ cb, const float* __restrict__ eb2,
           float* __restrict__ xp, float* __restrict__ root, float* __restrict__ Bb) {
  __shared__ float s_pw[D * DIN], s_rw[D * D], s_eb2[D * D], s_pb[D], s_cb[D];
  for (int t = threadIdx.x; t < D * DIN; t += TPB) s_pw[t] = pw[t];
  for (int t = threadIdx.x; t < D * D; t += TPB) { s_rw[t] = rw[t]; s_eb2[t] = eb2[t]; }
  for (int t = threadIdx.x; t < D; t += TPB) { s_pb[t] = pb[t]; s_cb[t] = cb[t]; }
  __syncthreads();
  int n = blockIdx.x * TPB + threadIdx.x;
  if (n >= NN) return;
  float xv[DIN];
  const float4* x4 = (const float4*)(x + (size_t)n * DIN);
  #pragma unroll
  for (int i = 0; i < DIN / 4; i++) {
    float4 v = x4[i];
    xv[4*i+0] = v.x; xv[4*i+1] = v.y; xv[4*i+2] = v.z; xv[4*i+3] = v.w;
  }
  float xpv[D];
  #pragma unroll
  for (int o = 0; o < D; o++) {
    float a = s_pb[o];
    #pragma unroll
    for (int i = 0; i < DIN; i++) a = fmaf(s_pw[o*DIN + i], xv[i], a);
    xpv[o] = a;
    xp[(size_t)n*D + o] = a;
  }
  #pragma unroll
  for (int o = 0; o < D; o++) {
    float a = s_cb[o];
    #pragma unroll
    for (int i = 0; i < D; i++) a = fmaf(s_rw[o*D + i], xpv[i], a);
    root[(size_t)n*D + o] = a;
  }
  #pragma unroll
  for (int o = 0; o < D; o++) {
    float a = 0.f;
    #pragma unroll
    for (int i = 0; i < D; i++) a = fmaf(xpv[i], s_eb2[i*D + o], a);
    Bb[(size_t)n*D + o] = a;
  }
}

// V packed bf16 pairs over i (K of phase B):
// word index t = i2*(2*UW) + w*2 + p, w = k2*D + o, p = k&1, k = 2*k2+p
// Vp[t] = pack(ew2[(2*i2  )*D+o][k], ew2[(2*i2+1)*D+o][k])
__global__ void k_trans(const float* __restrict__ ew2, uint32* __restrict__ Vp, int D) {
  int t = blockIdx.x * TPB + threadIdx.x;
  int COLS = D * 128;
  int T = (D / 2) * COLS;
  if (t >= T) return;
  int i2 = t / COLS;
  int r = t - i2 * COLS;
  int w = r >> 1, p = r & 1;
  int k2 = w / D, o = w - k2 * D;
  int k = 2 * k2 + p;
  float lo = ew2[((size_t)((2 * i2) * D + o)) * 128 + k];
  float hi = ew2[((size_t)((2 * i2 + 1) * D + o)) * 128 + k];
  Vp[t] = pk2bf(lo, hi);
}

// Fused: one block per G consecutive source nodes.
// Phase B: U-rows (packed bf16 k-pairs, word[k2*D+o], row stride UP=UW+4) into LDS
//          via dot2 over packed (xp,V) i-pairs.
// Phase C: h via dot2 (packed ea, ew1 i-pairs) -> packed k-pairs; msg = h.U+B via dot2.
template<int D, int G>
__global__ void __launch_bounds__(TPB)
k_fused(const int* __restrict__ eid_row, const int* __restrict__ row_off,
        const float* __restrict__ ea, const float* __restrict__ ew1,
        const float* __restrict__ eb1, const uint32* __restrict__ Vp,
        const float* __restrict__ xp, const float* __restrict__ Bb,
        float* __restrict__ msg) {
  constexpr int OQ = D / 4;            // threads per edge
  constexpr int EB = TPB / OQ;         // edges per inner iteration
  constexpr int COLS = D * 128;
  constexpr int UW = COLS / 2;         // u32 words per U-row
  constexpr int UP = UW + 4;           // padded row stride (bank stagger, 16B-aligned)
  constexpr int CT = UW / TPB;         // words per thread (8 for D32, 4 for D16)

  __shared__ __align__(16) uint32 s_w1tp[4 * 128];  // packed ew1 i-pairs: [i2][k]
  __shared__ float  s_b1[128];
  __shared__ __align__(16) uint32 s_U[G * UP];      // packed bf16 k-pairs: [g][k2*D+o]
  __shared__ __align__(16) uint32 s_hp[EB * 66];    // packed bf16 h k-pairs, stride 66
  __shared__ __align__(16) uint32 s_eap[EB * 4];    // packed ea i-pairs
  __shared__ uint32 s_xp2[G][D / 2];                // packed xp i-pairs
  __shared__ float  s_B[G * D];
  __shared__ int    s_off[G + 1];

  int tid = threadIdx.x;
  int n0 = blockIdx.x * G;
  int GA = NN - n0; if (GA > G) GA = G;

  // ---- phase A: stage weights + per-node vectors ----
  for (int t = tid; t < 512; t += TPB) {
    int i2 = t >> 7, k = t & 127;
    s_w1tp[t] = pk2bf(ew1[k * 8 + 2 * i2], ew1[k * 8 + 2 * i2 + 1]);
  }
  for (int t = tid; t < 128; t += TPB) s_b1[t] = eb1[t];
  for (int t = tid; t < G * (D / 2); t += TPB) {
    int g = t / (D / 2), i2 = t % (D / 2);
    if (g < GA) {
      float2 v = *(const float2*)(xp + (size_t)(n0 + g) * D + 2 * i2);
      s_xp2[g][i2] = pk2bf(v.x, v.y);
    } else {
      s_xp2[g][i2] = 0;
    }
  }
  for (int t = tid; t < G * D; t += TPB) {
    int g = t / D, i = t % D;
    s_B[t] = (g < GA) ? Bb[(size_t)(n0 + g) * D + i] : 0.f;
  }
  if (tid <= GA) s_off[tid] = row_off[n0 + tid];
  __syncthreads();

  // ---- phase B: U-rows into LDS via dot2 (CT words x G nodes per thread) ----
  {
    const uint2* Vp2 = (const uint2*)Vp;   // [i2][w] -> {p=0 word, p=1 word}
    float accLo[G][CT], accHi[G][CT];
    #pragma unroll
    for (int g = 0; g < G; g++)
      #pragma unroll
      for (int j = 0; j < CT; j++) { accLo[g][j] = 0.f; accHi[g][j] = 0.f; }
    for (int i2 = 0; i2 < D / 2; i2++) {
      uint2 vv[CT];
      #pragma unroll
      for (int j = 0; j < CT; j++)
        vv[j] = Vp2[(size_t)i2 * UW + j * TPB + tid];
      #pragma unroll
      for (int g = 0; g < G; g++) {
        uint32 xg = s_xp2[g][i2];
        #pragma unroll
        for (int j = 0; j < CT; j++) {
          dot2bf(accLo[g][j], xg, vv[j].x);
          dot2bf(accHi[g][j], xg, vv[j].y);
        }
      }
    }
    #pragma unroll
    for (int g = 0; g < G; g++)
      #pragma unroll
      for (int j = 0; j < CT; j++)
        s_U[g * UP + j * TPB + tid] = pk2bf(accLo[g][j], accHi[g][j]);
  }

  // ---- phase C: edges of the group (contiguous sorted slots) ----
  int p0 = row_off[n0], p1 = row_off[n0 + GA];
  int el = tid / OQ, oq = tid % OQ;
  for (int pc = p0; pc < p1; pc += EB) {
    int cnt = p1 - pc; if (cnt > EB) cnt = EB;
    __syncthreads();   // first iter: phase A/B done; later: protect s_eap/s_hp reuse
    for (int t = tid; t < cnt * 4; t += TPB) {
      int e2 = t >> 2, i2 = t & 3;
      float2 v = *(const float2*)(ea + (size_t)eid_row[pc + e2] * 8 + 2 * i2);
      s_eap[t] = pk2bf(v.x, v.y);
    }
    __syncthreads();
    // h packed as bf16 k-pairs via dot2
    for (int t = tid; t < cnt * 64; t += TPB) {
      int e2 = t >> 6, k2 = t & 63;
      float a0 = s_b1[2 * k2], a1 = s_b1[2 * k2 + 1];
      #pragma unroll
      for (int i2 = 0; i2 < 4; i2++) {
        uint32 ep = s_eap[e2 * 4 + i2];
        uint2 ww = *(const uint2*)(s_w1tp + i2 * 128 + 2 * k2);
        dot2bf(a0, ep, ww.x);
        dot2bf(a1, ep, ww.y);
      }
      s_hp[e2 * 66 + k2] = pk2bf(fmaxf(a0, 0.f), fmaxf(a1, 0.f));
    }
    __syncthreads();
    if (el < cnt) {
      int s = pc + el;
      int g = 0;
      #pragma unroll
      for (int q = 1; q < G; q++) g += (q < GA && s >= s_off[q]) ? 1 : 0;
      const uint32* up = s_U + g * UP + oq * 4;
      const uint32* hp = s_hp + el * 66;
      float a0 = 0.f, a1 = 0.f, a2 = 0.f, a3 = 0.f;
      #pragma unroll 4
      for (int k4 = 0; k4 < 32; k4++) {
        uint2 hw = *(const uint2*)(hp + 2 * k4);
        uint4 u0 = *(const uint4*)(up + (2 * k4) * D);
        uint4 u1 = *(const uint4*)(up + (2 * k4 + 1) * D);
        dot2bf(a0, hw.x, u0.x); dot2bf(a1, hw.x, u0.y);
        dot2bf(a2, hw.x, u0.z); dot2bf(a3, hw.x, u0.w);
        dot2bf(a0, hw.y, u1.x); dot2bf(a1, hw.y, u1.y);
        dot2bf(a2, hw.y, u1.z); dot2bf(a3, hw.y, u1.w);
      }
      float4 b = ((const float4*)(s_B + g * D))[oq];
      float4 o4 = {a0 + b.x, a1 + b.y, a2 + b.z, a3 + b.w};
      ((float4*)(msg + (size_t)s * D))[oq] = o4;
    }
  }
}

// gather aggregation by col-CSR (deterministic), then x = relu(agg/deg + root) + xp
template<int D>
__global__ void __launch_bounds__(TPB)
k_agg(const int* __restrict__ col_off, const int* __restrict__ slot_col,
      const float* __restrict__ msg, const float* __restrict__ root,
      const float* __restrict__ xp, float* __restrict__ xout) {
  constexpr int GP = TPB / D;
  int g = threadIdx.x / D, o = threadIdx.x % D;
  int n = blockIdx.x * GP + g;
  if (n >= NN) return;
  int p0 = col_off[n], p1 = col_off[n + 1];
  float acc = 0.f;
  for (int p = p0; p < p1; p++) {
    int sc = slot_col[p];
    acc += msg[(size_t)sc * D + o];
  }
  float deg = (p1 > p0) ? (float)(p1 - p0) : 1.f;
  float conv = acc / deg + root[(size_t)n * D + o];
  float rl = conv > 0.f ? conv : 0.f;
  xout[(size_t)n * D + o] = rl + xp[(size_t)n * D + o];
}

// final edge MLP: out = relu((x[row]+x[col]) @ mw0^T + mb0) @ mw1^T + mb1
__global__ void __launch_bounds__(TPB)
k_final(const int* __restrict__ ei, const float* __restrict__ x,
        const float* __restrict__ mw0, const float* __restrict__ mb0,
        const float* __restrict__ mw1, const float* __restrict__ mb1,
        float* __restrict__ out) {
  __shared__ float s_w0[256], s_b0[16], s_w1[16], s_b1;
  for (int t = threadIdx.x; t < 256; t += TPB) s_w0[t] = mw0[t];
  if (threadIdx.x < 16) { s_b0[threadIdx.x] = mb0[threadIdx.x]; s_w1[threadIdx.x] = mw1[threadIdx.x]; }
  if (threadIdx.x == 0) s_b1 = mb1[0];
  __syncthreads();
  int e = blockIdx.x * TPB + threadIdx.x;
  if (e >= NE) return;
  int r = ei[e], c = ei[NE + e];
  const float4* xr4 = (const float4*)(x + (size_t)r * 16);
  const float4* xc4 = (const float4*)(x + (size_t)c * 16);
  float er[16];
  #pragma unroll
  for (int q = 0; q < 4; q++) {
    float4 vr = xr4[q], vc = xc4[q];
    er[4*q+0] = vr.x + vc.x; er[4*q+1] = vr.y + vc.y;
    er[4*q+2] = vr.z + vc.z; er[4*q+3] = vr.w + vc.w;
  }
  float o = s_b1;
  #pragma unroll
  for (int j = 0; j < 16; j++) {
    float t = s_b0[j];
    #pragma unroll
    for (int k = 0; k < 16; k++) t = fmaf(er[k], s_w0[j * 16 + k], t);
    t = fmaxf(t, 0.f);
    o = fmaf(t, s_w1[j], o);
  }
  out[e] = o;
}

// ---------------- host side ----------------

struct LayerPtrs {
  const float *pw, *pb, *ew1, *eb1, *ew2, *eb2, *rw, *cb;
};

template<int DIN, int D, int G>
static void run_layer(const float* xin, float* xout, const LayerPtrs& L,
                      const int* ei, const float* ea,
                      const int* row_off, const int* col_off,
                      const int* eid_row, const int* slot_col,
                      float* xp, float* root, float* Bb, float* msg, uint32* Vp,
                      hipStream_t stream) {
  k_nodeprep<DIN, D><<<(NN + TPB - 1) / TPB, TPB, 0, stream>>>(
      xin, L.pw, L.pb, L.rw, L.cb, L.eb2, xp, root, Bb);
  constexpr int COLS = D * 128;
  constexpr int T = (D / 2) * COLS;
  k_trans<<<(T + TPB - 1) / TPB, TPB, 0, stream>>>(L.ew2, Vp, D);
  k_fused<D, G><<<(NN + G - 1) / G, TPB, 0, stream>>>(
      eid_row, row_off, ea, L.ew1, L.eb1, Vp, xp, Bb, msg);
  k_agg<D><<<(NN * D + TPB - 1) / TPB, TPB, 0, stream>>>(
      col_off, slot_col, msg, root, xp, xout);
}

extern "C" void kernel_launch(void* const* d_in, const int* in_sizes, int n_in,
                              void* d_out, int out_size, void* d_ws, size_t ws_size,
                              hipStream_t stream) {
  (void)in_sizes; (void)n_in; (void)out_size; (void)ws_size;
  const float* x0 = (const float*)d_in[0];
  const float* ea = (const float*)d_in[1];
  const int* ei = (const int*)d_in[2];
  LayerPtrs L[4];
  for (int l = 0; l < 4; l++) {
    L[l].pw  = (const float*)d_in[3 + 8 * l];
    L[l].pb  = (const float*)d_in[4 + 8 * l];
    L[l].ew1 = (const float*)d_in[5 + 8 * l];
    L[l].eb1 = (const float*)d_in[6 + 8 * l];
    L[l].ew2 = (const float*)d_in[7 + 8 * l];
    L[l].eb2 = (const float*)d_in[8 + 8 * l];
    L[l].rw  = (const float*)d_in[9 + 8 * l];
    L[l].cb  = (const float*)d_in[10 + 8 * l];
  }
  const float* mw0 = (const float*)d_in[35];
  const float* mb0 = (const float*)d_in[36];
  const float* mw1 = (const float*)d_in[37];
  const float* mb1 = (const float*)d_in[38];
  float* out = (float*)d_out;

  char* w = (char*)d_ws;
  size_t off = 0;
  auto alloc = [&](size_t b) -> void* {
    void* p = w + off;
    off = (off + b + 255) & ~(size_t)255;
    return p;
  };
  int* cnt_row  = (int*)alloc(sizeof(int) * NN);
  int* cnt_col  = (int*)alloc(sizeof(int) * NN);
  int* row_off  = (int*)alloc(sizeof(int) * (NN + 1));
  int* col_off  = (int*)alloc(sizeof(int) * (NN + 1));
  int* cur_row  = (int*)alloc(sizeof(int) * NN);
  int* cur_col  = (int*)alloc(sizeof(int) * NN);
  int* eid_row  = (int*)alloc(sizeof(int) * NE);
  int* slot_col = (int*)alloc(sizeof(int) * NE);
  float* xb0  = (float*)alloc(sizeof(float) * NN * 32);
  float* xb1  = (float*)alloc(sizeof(float) * NN * 32);
  float* xp   = (float*)alloc(sizeof(float) * NN * 32);
  float* root = (float*)alloc(sizeof(float) * NN * 32);
  float* Bb   = (float*)alloc(sizeof(float) * NN * 32);
  float* msg  = (float*)alloc(sizeof(float) * NE * 32);
  uint32* Vp  = (uint32*)alloc(sizeof(uint32) * 16 * 4096);  // 256 KB max

  hipMemsetAsync(cnt_row, 0, sizeof(int) * NN, stream);
  hipMemsetAsync(cnt_col, 0, sizeof(int) * NN, stream);
  k_count<<<(NE + TPB - 1) / TPB, TPB, 0, stream>>>(ei, cnt_row, cnt_col);
  k_scan2<<<2, 64, 0, stream>>>(cnt_row, row_off, cur_row, cnt_col, col_off, cur_col);
  k_fill_row<<<(NE + TPB - 1) / TPB, TPB, 0, stream>>>(ei, cur_row, eid_row);
  k_fill_col<<<(NE + TPB - 1) / TPB, TPB, 0, stream>>>(ei, eid_row, cur_col, slot_col);

  float* bufs[2] = {xb0, xb1};
  const float* xin = x0;
  for (int l = 0; l < 4; l++) {
    float* xout = bufs[l & 1];
    if (l == 0) {
      run_layer<16, 32, 4>(xin, xout, L[0], ei, ea, row_off, col_off, eid_row, slot_col,
                           xp, root, Bb, msg, Vp, stream);
    } else if (l == 1) {
      run_layer<32, 16, 6>(xin, xout, L[1], ei, ea, row_off, col_off, eid_row, slot_col,
                           xp, root, Bb, msg, Vp, stream);
    } else if (l == 2) {
      run_layer<16, 16, 6>(xin, xout, L[2], ei, ea, row_off, col_off, eid_row, slot_col,
                           xp, root, Bb, msg, Vp, stream);
    } else {
      run_layer<16, 16, 6>(xin, xout, L[3], ei, ea, row_off, col_off, eid_row, slot_col,
                           xp, root, Bb, msg, Vp, stream);
    }
    xin = xout;
  }
  k_final<<<(NE + TPB - 1) / TPB, TPB, 0, stream>>>(ei, xin, mw0, mb0, mw1, mb1, out);
}

// Round 10
// 422.760 us; speedup vs baseline: 1.8097x; 1.0728x over previous
//
#include <hip/hip_runtime.h>

#define NN 10000
#define NE 160000
static constexpr int TPB = 256;

typedef unsigned int uint32;

static __device__ __forceinline__ ushort f2bf(float f) {
  uint32 u = __float_as_uint(f);
  u += 0x7fff + ((u >> 16) & 1);   // round-to-nearest-even
  return (ushort)(u >> 16);
}
static __device__ __forceinline__ uint32 pk2bf(float a, float b) {
  return (uint32)f2bf(a) | ((uint32)f2bf(b) << 16);
}
// acc += a.lo*b.lo + a.hi*b.hi  (packed bf16 pairs, f32 accumulate)
static __device__ __forceinline__ void dot2bf(float& acc, uint32 a, uint32 b) {
  asm("v_dot2_f32_bf16 %0, %1, %2, %0" : "+v"(acc) : "v"(a), "v"(b));
}

// ---------------- sort / CSR build ----------------

__global__ void k_count(const int* __restrict__ ei, int* __restrict__ cnt_row,
                        int* __restrict__ cnt_col) {
  int e = blockIdx.x * TPB + threadIdx.x;
  if (e >= NE) return;
  atomicAdd(&cnt_row[ei[e]], 1);
  atomicAdd(&cnt_col[ei[NE + e]], 1);
}

__global__ void k_scan2(const int* __restrict__ cnt_r, int* __restrict__ off_r, int* __restrict__ cur_r,
                        const int* __restrict__ cnt_c, int* __restrict__ off_c, int* __restrict__ cur_c) {
  const int* cnt = (blockIdx.x == 0) ? cnt_r : cnt_c;
  int* off = (blockIdx.x == 0) ? off_r : off_c;
  int* cur = (blockIdx.x == 0) ? cur_r : cur_c;
  int lane = threadIdx.x;  // 64 threads (one wave)
  int carry = 0;
  for (int base = 0; base < NN; base += 64) {
    int i = base + lane;
    int v = (i < NN) ? cnt[i] : 0;
    int s = v;
    #pragma unroll
    for (int dd = 1; dd < 64; dd <<= 1) {
      int t = __shfl_up(s, dd, 64);
      if (lane >= dd) s += t;
    }
    int excl = carry + s - v;
    if (i < NN) { off[i] = excl; cur[i] = excl; }
    carry += __shfl(s, 63, 64);
  }
  if (lane == 0) off[NN] = carry;
}

__global__ void k_fill_row(const int* __restrict__ ei, int* __restrict__ cur_row,
                           int* __restrict__ eid_row) {
  int e = blockIdx.x * TPB + threadIdx.x;
  if (e >= NE) return;
  int r = ei[e];
  int p = atomicAdd(&cur_row[r], 1);
  eid_row[p] = e;
}

__global__ void k_fill_col(const int* __restrict__ ei, const int* __restrict__ eid_row,
                           int* __restrict__ cur_col, int* __restrict__ slot_col) {
  int s = blockIdx.x * TPB + threadIdx.x;
  if (s >= NE) return;
  int e = eid_row[s];
  int c = ei[NE + e];
  int p = atomicAdd(&cur_col[c], 1);
  slot_col[p] = s;
}

// ---------------- per-layer kernels ----------------

// xp = x@pw^T + pb ; root = xp@rw^T + cb ; B[n,o] = sum_i xp[i]*eb2[i*D+o]
template<int DIN, int D>
__global__ void __launch_bounds__(TPB)
k_nodeprep(const float* __restrict__ x, const float* __restrict__ pw, const float* __restrict__ pb,
           const float* __restrict__ rw, const float* __restrict__ cb, const float* __restrict__ eb2,
           float* __restrict__ xp, float* __restrict__ root, float* __restrict__ Bb) {
  __shared__ float s_pw[D * DIN], s_rw[D * D], s_eb2[D * D], s_pb[D], s_cb[D];
  for (int t = threadIdx.x; t < D * DIN; t += TPB) s_pw[t] = pw[t];
  for (int t = threadIdx.x; t < D * D; t += TPB) { s_rw[t] = rw[t]; s_eb2[t] = eb2[t]; }
  for (int t = threadIdx.x; t < D; t += TPB) { s_pb[t] = pb[t]; s_cb[t] = cb[t]; }
  __syncthreads();
  int n = blockIdx.x * TPB + threadIdx.x;
  if (n >= NN) return;
  float xv[DIN];
  const float4* x4 = (const float4*)(x + (size_t)n * DIN);
  #pragma unroll
  for (int i = 0; i < DIN / 4; i++) {
    float4 v = x4[i];
    xv[4*i+0] = v.x; xv[4*i+1] = v.y; xv[4*i+2] = v.z; xv[4*i+3] = v.w;
  }
  float xpv[D];
  #pragma unroll
  for (int o = 0; o < D; o++) {
    float a = s_pb[o];
    #pragma unroll
    for (int i = 0; i < DIN; i++) a = fmaf(s_pw[o*DIN + i], xv[i], a);
    xpv[o] = a;
    xp[(size_t)n*D + o] = a;
  }
  #pragma unroll
  for (int o = 0; o < D; o++) {
    float a = s_cb[o];
    #pragma unroll
    for (int i = 0; i < D; i++) a = fmaf(s_rw[o*D + i], xpv[i], a);
    root[(size_t)n*D + o] = a;
  }
  #pragma unroll
  for (int o = 0; o < D; o++) {
    float a = 0.f;
    #pragma unroll
    for (int i = 0; i < D; i++) a = fmaf(xpv[i], s_eb2[i*D + o], a);
    Bb[(size_t)n*D + o] = a;
  }
}

// V packed bf16 pairs over i (K of phase B):
// word index t = i2*(2*UW) + w*2 + p, w = k2*D + o, p = k&1, k = 2*k2+p
// Vp[t] = pack(ew2[(2*i2  )*D+o][k], ew2[(2*i2+1)*D+o][k])
__global__ void k_trans(const float* __restrict__ ew2, uint32* __restrict__ Vp, int D) {
  int t = blockIdx.x * TPB + threadIdx.x;
  int COLS = D * 128;
  int T = (D / 2) * COLS;
  if (t >= T) return;
  int i2 = t / COLS;
  int r = t - i2 * COLS;
  int w = r >> 1, p = r & 1;
  int k2 = w / D, o = w - k2 * D;
  int k = 2 * k2 + p;
  float lo = ew2[((size_t)((2 * i2) * D + o)) * 128 + k];
  float hi = ew2[((size_t)((2 * i2 + 1) * D + o)) * 128 + k];
  Vp[t] = pk2bf(lo, hi);
}

// Fused, split-k over blockIdx.y (half = 0/1, k2 in [half*KH2, half*KH2+KH2)).
// Phase B: half U-rows (packed bf16 k-pairs, word[k2loc*D+o], row stride UP) into LDS.
// Phase C: h (half k-range) via dot2 -> packed k-pairs; partial msg = h.U (+B if half 0)
//          written to msgH[half].
template<int D, int G>
__global__ void __launch_bounds__(TPB)
k_fused(const int* __restrict__ eid_row, const int* __restrict__ row_off,
        const float* __restrict__ ea, const float* __restrict__ ew1,
        const float* __restrict__ eb1, const uint32* __restrict__ Vp,
        const float* __restrict__ xp, const float* __restrict__ Bb,
        float* __restrict__ msg0, float* __restrict__ msg1) {
  constexpr int OQ = D / 4;            // threads per edge
  constexpr int EB = TPB / OQ;         // edges per inner iteration
  constexpr int COLS = D * 128;
  constexpr int UW = COLS / 2;         // u32 words per full U-row
  constexpr int UH = UW / 2;           // words per half U-row
  constexpr int UP = UH + 4;           // padded row stride (bank stagger, 16B-aligned)
  constexpr int CT = UH / TPB;         // words per thread (4 for D32, 2 for D16)

  __shared__ __align__(16) uint32 s_w1tp[4 * 64];   // packed ew1 i-pairs: [i2][kloc]
  __shared__ float  s_b1[64];
  __shared__ __align__(16) uint32 s_U[G * UP];      // packed bf16 k-pairs (half)
  __shared__ __align__(16) uint32 s_hp[EB * 34];    // packed bf16 h k-pairs (half), stride 34
  __shared__ __align__(16) uint32 s_eap[EB * 4];    // packed ea i-pairs
  __shared__ uint32 s_xp2[G][D / 2];                // packed xp i-pairs
  __shared__ float  s_B[G * D];
  __shared__ int    s_off[G + 1];

  int tid = threadIdx.x;
  int half = blockIdx.y;
  int n0 = blockIdx.x * G;
  int GA = NN - n0; if (GA > G) GA = G;
  float* msgH = half ? msg1 : msg0;

  // ---- phase A: stage weights (this k-half) + per-node vectors ----
  for (int t = tid; t < 4 * 64; t += TPB) {
    int i2 = t >> 6, kloc = t & 63;
    int k = half * 64 + kloc;
    s_w1tp[t] = pk2bf(ew1[k * 8 + 2 * i2], ew1[k * 8 + 2 * i2 + 1]);
  }
  for (int t = tid; t < 64; t += TPB) s_b1[t] = eb1[half * 64 + t];
  for (int t = tid; t < G * (D / 2); t += TPB) {
    int g = t / (D / 2), i2 = t % (D / 2);
    if (g < GA) {
      float2 v = *(const float2*)(xp + (size_t)(n0 + g) * D + 2 * i2);
      s_xp2[g][i2] = pk2bf(v.x, v.y);
    } else {
      s_xp2[g][i2] = 0;
    }
  }
  for (int t = tid; t < G * D; t += TPB) {
    int g = t / D, i = t % D;
    s_B[t] = (g < GA && half == 0) ? Bb[(size_t)(n0 + g) * D + i] : 0.f;
  }
  if (tid <= GA) s_off[tid] = row_off[n0 + tid];
  __syncthreads();

  // ---- phase B: half U-rows into LDS via dot2 (CT words x G nodes / thread) ----
  {
    const uint2* Vp2 = (const uint2*)Vp;   // [i2][w] -> {p=0 word, p=1 word}
    float accLo[G][CT], accHi[G][CT];
    #pragma unroll
    for (int g = 0; g < G; g++)
      #pragma unroll
      for (int j = 0; j < CT; j++) { accLo[g][j] = 0.f; accHi[g][j] = 0.f; }
    #pragma unroll 2
    for (int i2 = 0; i2 < D / 2; i2++) {
      uint2 vv[CT];
      #pragma unroll
      for (int j = 0; j < CT; j++)
        vv[j] = Vp2[(size_t)i2 * UW + half * UH + j * TPB + tid];
      #pragma unroll
      for (int g = 0; g < G; g++) {
        uint32 xg = s_xp2[g][i2];
        #pragma unroll
        for (int j = 0; j < CT; j++) {
          dot2bf(accLo[g][j], xg, vv[j].x);
          dot2bf(accHi[g][j], xg, vv[j].y);
        }
      }
    }
    #pragma unroll
    for (int g = 0; g < G; g++)
      #pragma unroll
      for (int j = 0; j < CT; j++)
        s_U[g * UP + j * TPB + tid] = pk2bf(accLo[g][j], accHi[g][j]);
  }

  // ---- phase C: edges of the group (contiguous sorted slots) ----
  int p0 = row_off[n0], p1 = row_off[n0 + GA];
  int el = tid / OQ, oq = tid % OQ;
  for (int pc = p0; pc < p1; pc += EB) {
    int cnt = p1 - pc; if (cnt > EB) cnt = EB;
    __syncthreads();   // first iter: phase A/B done; later: protect s_eap/s_hp reuse
    for (int t = tid; t < cnt * 4; t += TPB) {
      int e2 = t >> 2, i2 = t & 3;
      float2 v = *(const float2*)(ea + (size_t)eid_row[pc + e2] * 8 + 2 * i2);
      s_eap[t] = pk2bf(v.x, v.y);
    }
    __syncthreads();
    // h (half k-range) packed as bf16 k-pairs via dot2
    for (int t = tid; t < cnt * 32; t += TPB) {
      int e2 = t >> 5, k2 = t & 31;
      float a0 = s_b1[2 * k2], a1 = s_b1[2 * k2 + 1];
      #pragma unroll
      for (int i2 = 0; i2 < 4; i2++) {
        uint32 ep = s_eap[e2 * 4 + i2];
        uint2 ww = *(const uint2*)(s_w1tp + i2 * 64 + 2 * k2);
        dot2bf(a0, ep, ww.x);
        dot2bf(a1, ep, ww.y);
      }
      s_hp[e2 * 34 + k2] = pk2bf(fmaxf(a0, 0.f), fmaxf(a1, 0.f));
    }
    __syncthreads();
    if (el < cnt) {
      int s = pc + el;
      int g = 0;
      #pragma unroll
      for (int q = 1; q < G; q++) g += (q < GA && s >= s_off[q]) ? 1 : 0;
      const uint32* up = s_U + g * UP + oq * 4;
      const uint32* hp = s_hp + el * 34;
      float a0 = 0.f, a1 = 0.f, a2 = 0.f, a3 = 0.f;
      #pragma unroll 4
      for (int k4 = 0; k4 < 16; k4++) {
        uint2 hw = *(const uint2*)(hp + 2 * k4);
        uint4 u0 = *(const uint4*)(up + (2 * k4) * D);
        uint4 u1 = *(const uint4*)(up + (2 * k4 + 1) * D);
        dot2bf(a0, hw.x, u0.x); dot2bf(a1, hw.x, u0.y);
        dot2bf(a2, hw.x, u0.z); dot2bf(a3, hw.x, u0.w);
        dot2bf(a0, hw.y, u1.x); dot2bf(a1, hw.y, u1.y);
        dot2bf(a2, hw.y, u1.z); dot2bf(a3, hw.y, u1.w);
      }
      float4 b = ((const float4*)(s_B + g * D))[oq];
      float4 o4 = {a0 + b.x, a1 + b.y, a2 + b.z, a3 + b.w};
      ((float4*)(msgH + (size_t)s * D))[oq] = o4;
    }
  }
}

// gather aggregation by col-CSR (deterministic), sums both k-halves,
// then x = relu(agg/deg + root) + xp
template<int D>
__global__ void __launch_bounds__(TPB)
k_agg(const int* __restrict__ col_off, const int* __restrict__ slot_col,
      const float* __restrict__ msg0, const float* __restrict__ msg1,
      const float* __restrict__ root, const float* __restrict__ xp,
      float* __restrict__ xout) {
  constexpr int GP = TPB / D;
  int g = threadIdx.x / D, o = threadIdx.x % D;
  int n = blockIdx.x * GP + g;
  if (n >= NN) return;
  int p0 = col_off[n], p1 = col_off[n + 1];
  float acc = 0.f;
  for (int p = p0; p < p1; p++) {
    int sc = slot_col[p];
    acc += msg0[(size_t)sc * D + o] + msg1[(size_t)sc * D + o];
  }
  float deg = (p1 > p0) ? (float)(p1 - p0) : 1.f;
  float conv = acc / deg + root[(size_t)n * D + o];
  float rl = conv > 0.f ? conv : 0.f;
  xout[(size_t)n * D + o] = rl + xp[(size_t)n * D + o];
}

// final edge MLP: out = relu((x[row]+x[col]) @ mw0^T + mb0) @ mw1^T + mb1
__global__ void __launch_bounds__(TPB)
k_final(const int* __restrict__ ei, const float* __restrict__ x,
        const float* __restrict__ mw0, const float* __restrict__ mb0,
        const float* __restrict__ mw1, const float* __restrict__ mb1,
        float* __restrict__ out) {
  __shared__ float s_w0[256], s_b0[16], s_w1[16], s_b1;
  for (int t = threadIdx.x; t < 256; t += TPB) s_w0[t] = mw0[t];
  if (threadIdx.x < 16) { s_b0[threadIdx.x] = mb0[threadIdx.x]; s_w1[threadIdx.x] = mw1[threadIdx.x]; }
  if (threadIdx.x == 0) s_b1 = mb1[0];
  __syncthreads();
  int e = blockIdx.x * TPB + threadIdx.x;
  if (e >= NE) return;
  int r = ei[e], c = ei[NE + e];
  const float4* xr4 = (const float4*)(x + (size_t)r * 16);
  const float4* xc4 = (const float4*)(x + (size_t)c * 16);
  float er[16];
  #pragma unroll
  for (int q = 0; q < 4; q++) {
    float4 vr = xr4[q], vc = xc4[q];
    er[4*q+0] = vr.x + vc.x; er[4*q+1] = vr.y + vc.y;
    er[4*q+2] = vr.z + vc.z; er[4*q+3] = vr.w + vc.w;
  }
  float o = s_b1;
  #pragma unroll
  for (int j = 0; j < 16; j++) {
    float t = s_b0[j];
    #pragma unroll
    for (int k = 0; k < 16; k++) t = fmaf(er[k], s_w0[j * 16 + k], t);
    t = fmaxf(t, 0.f);
    o = fmaf(t, s_w1[j], o);
  }
  out[e] = o;
}

// ---------------- host side ----------------

struct LayerPtrs {
  const float *pw, *pb, *ew1, *eb1, *ew2, *eb2, *rw, *cb;
};

template<int DIN, int D, int G>
static void run_layer(const float* xin, float* xout, const LayerPtrs& L,
                      const int* ei, const float* ea,
                      const int* row_off, const int* col_off,
                      const int* eid_row, const int* slot_col,
                      float* xp, float* root, float* Bb,
                      float* msg0, float* msg1, uint32* Vp,
                      hipStream_t stream) {
  k_nodeprep<DIN, D><<<(NN + TPB - 1) / TPB, TPB, 0, stream>>>(
      xin, L.pw, L.pb, L.rw, L.cb, L.eb2, xp, root, Bb);
  constexpr int COLS = D * 128;
  constexpr int T = (D / 2) * COLS;
  k_trans<<<(T + TPB - 1) / TPB, TPB, 0, stream>>>(L.ew2, Vp, D);
  dim3 gf((NN + G - 1) / G, 2);
  k_fused<D, G><<<gf, TPB, 0, stream>>>(
      eid_row, row_off, ea, L.ew1, L.eb1, Vp, xp, Bb, msg0, msg1);
  k_agg<D><<<(NN * D + TPB - 1) / TPB, TPB, 0, stream>>>(
      col_off, slot_col, msg0, msg1, root, xp, xout);
}

extern "C" void kernel_launch(void* const* d_in, const int* in_sizes, int n_in,
                              void* d_out, int out_size, void* d_ws, size_t ws_size,
                              hipStream_t stream) {
  (void)in_sizes; (void)n_in; (void)out_size; (void)ws_size;
  const float* x0 = (const float*)d_in[0];
  const float* ea = (const float*)d_in[1];
  const int* ei = (const int*)d_in[2];
  LayerPtrs L[4];
  for (int l = 0; l < 4; l++) {
    L[l].pw  = (const float*)d_in[3 + 8 * l];
    L[l].pb  = (const float*)d_in[4 + 8 * l];
    L[l].ew1 = (const float*)d_in[5 + 8 * l];
    L[l].eb1 = (const float*)d_in[6 + 8 * l];
    L[l].ew2 = (const float*)d_in[7 + 8 * l];
    L[l].eb2 = (const float*)d_in[8 + 8 * l];
    L[l].rw  = (const float*)d_in[9 + 8 * l];
    L[l].cb  = (const float*)d_in[10 + 8 * l];
  }
  const float* mw0 = (const float*)d_in[35];
  const float* mb0 = (const float*)d_in[36];
  const float* mw1 = (const float*)d_in[37];
  const float* mb1 = (const float*)d_in[38];
  float* out = (float*)d_out;

  char* w = (char*)d_ws;
  size_t off = 0;
  auto alloc = [&](size_t b) -> void* {
    void* p = w + off;
    off = (off + b + 255) & ~(size_t)255;
    return p;
  };
  int* cnt_row  = (int*)alloc(sizeof(int) * NN);
  int* cnt_col  = (int*)alloc(sizeof(int) * NN);
  int* row_off  = (int*)alloc(sizeof(int) * (NN + 1));
  int* col_off  = (int*)alloc(sizeof(int) * (NN + 1));
  int* cur_row  = (int*)alloc(sizeof(int) * NN);
  int* cur_col  = (int*)alloc(sizeof(int) * NN);
  int* eid_row  = (int*)alloc(sizeof(int) * NE);
  int* slot_col = (int*)alloc(sizeof(int) * NE);
  float* xb0  = (float*)alloc(sizeof(float) * NN * 32);
  float* xb1  = (float*)alloc(sizeof(float) * NN * 32);
  float* xp   = (float*)alloc(sizeof(float) * NN * 32);
  float* root = (float*)alloc(sizeof(float) * NN * 32);
  float* Bb   = (float*)alloc(sizeof(float) * NN * 32);
  float* msg0 = (float*)alloc(sizeof(float) * NE * 32);
  float* msg1 = (float*)alloc(sizeof(float) * NE * 32);
  uint32* Vp  = (uint32*)alloc(sizeof(uint32) * 16 * 4096);  // 256 KB max

  hipMemsetAsync(cnt_row, 0, sizeof(int) * NN, stream);
  hipMemsetAsync(cnt_col, 0, sizeof(int) * NN, stream);
  k_count<<<(NE + TPB - 1) / TPB, TPB, 0, stream>>>(ei, cnt_row, cnt_col);
  k_scan2<<<2, 64, 0, stream>>>(cnt_row, row_off, cur_row, cnt_col, col_off, cur_col);
  k_fill_row<<<(NE + TPB - 1) / TPB, TPB, 0, stream>>>(ei, cur_row, eid_row);
  k_fill_col<<<(NE + TPB - 1) / TPB, TPB, 0, stream>>>(ei, eid_row, cur_col, slot_col);

  float* bufs[2] = {xb0, xb1};
  const float* xin = x0;
  for (int l = 0; l < 4; l++) {
    float* xout = bufs[l & 1];
    if (l == 0) {
      run_layer<16, 32, 4>(xin, xout, L[0], ei, ea, row_off, col_off, eid_row, slot_col,
                           xp, root, Bb, msg0, msg1, Vp, stream);
    } else if (l == 1) {
      run_layer<32, 16, 6>(xin, xout, L[1], ei, ea, row_off, col_off, eid_row, slot_col,
                           xp, root, Bb, msg0, msg1, Vp, stream);
    } else if (l == 2) {
      run_layer<16, 16, 6>(xin, xout, L[2], ei, ea, row_off, col_off, eid_row, slot_col,
                           xp, root, Bb, msg0, msg1, Vp, stream);
    } else {
      run_layer<16, 16, 6>(xin, xout, L[3], ei, ea, row_off, col_off, eid_row, slot_col,
                           xp, root, Bb, msg0, msg1, Vp, stream);
    }
    xin = xout;
  }
  k_final<<<(NE + TPB - 1) / TPB, TPB, 0, stream>>>(ei, xin, mw0, mb0, mw1, mb1, out);
}

// Round 11
// 354.513 us; speedup vs baseline: 2.1581x; 1.1925x over previous
//
#include <hip/hip_runtime.h>

#define NN 10000
#define NE 160000
static constexpr int TPB = 256;
static constexpr int SCAN_T = 1024;

typedef unsigned int uint32;

static __device__ __forceinline__ ushort f2bf(float f) {
  uint32 u = __float_as_uint(f);
  u += 0x7fff + ((u >> 16) & 1);   // round-to-nearest-even
  return (ushort)(u >> 16);
}
static __device__ __forceinline__ uint32 pk2bf(float a, float b) {
  return (uint32)f2bf(a) | ((uint32)f2bf(b) << 16);
}
// acc += a.lo*b.lo + a.hi*b.hi  (packed bf16 pairs, f32 accumulate)
static __device__ __forceinline__ void dot2bf(float& acc, uint32 a, uint32 b) {
  asm("v_dot2_f32_bf16 %0, %1, %2, %0" : "+v"(acc) : "v"(a), "v"(b));
}

// ---------------- sort / CSR build ----------------

__global__ void k_count(const int* __restrict__ ei, int* __restrict__ cnt_row,
                        int* __restrict__ cnt_col) {
  int e = blockIdx.x * TPB + threadIdx.x;
  if (e >= NE) return;
  atomicAdd(&cnt_row[ei[e]], 1);
  atomicAdd(&cnt_col[ei[NE + e]], 1);
}

// 16-wave block scan: block 0 -> row CSR, block 1 -> col CSR.
__global__ void __launch_bounds__(SCAN_T)
k_scan2(const int* __restrict__ cnt_r, int* __restrict__ off_r, int* __restrict__ cur_r,
        const int* __restrict__ cnt_c, int* __restrict__ off_c, int* __restrict__ cur_c) {
  const int* cnt = (blockIdx.x == 0) ? cnt_r : cnt_c;
  int* off = (blockIdx.x == 0) ? off_r : off_c;
  int* cur = (blockIdx.x == 0) ? cur_r : cur_c;
  __shared__ int s_wave[16];
  __shared__ int s_carry;
  int tid = threadIdx.x;
  int lane = tid & 63, wid = tid >> 6;
  if (tid == 0) s_carry = 0;
  __syncthreads();
  for (int base = 0; base < NN; base += SCAN_T) {
    int i = base + tid;
    int v = (i < NN) ? cnt[i] : 0;
    int s = v;
    #pragma unroll
    for (int d = 1; d < 64; d <<= 1) {
      int t = __shfl_up(s, d, 64);
      if (lane >= d) s += t;
    }
    if (lane == 63) s_wave[wid] = s;
    __syncthreads();
    if (wid == 0 && lane < 16) {
      int ws = s_wave[lane];
      #pragma unroll
      for (int d = 1; d < 16; d <<= 1) {
        int t = __shfl_up(ws, d, 64);
        if (lane >= d) ws += t;
      }
      s_wave[lane] = ws;   // inclusive wave-sum scan
    }
    __syncthreads();
    int waveoff = (wid > 0) ? s_wave[wid - 1] : 0;
    int excl = s_carry + waveoff + s - v;
    if (i < NN) { off[i] = excl; cur[i] = excl; }
    __syncthreads();   // all reads of s_carry/s_wave done
    if (tid == 0) s_carry += s_wave[15];
    __syncthreads();
  }
  if (tid == 0) off[NN] = s_carry;
}

__global__ void k_fill_row(const int* __restrict__ ei, int* __restrict__ cur_row,
                           int* __restrict__ eid_row) {
  int e = blockIdx.x * TPB + threadIdx.x;
  if (e >= NE) return;
  int r = ei[e];
  int p = atomicAdd(&cur_row[r], 1);
  eid_row[p] = e;
}

__global__ void k_fill_col(const int* __restrict__ ei, const int* __restrict__ eid_row,
                           int* __restrict__ cur_col, int* __restrict__ slot_col) {
  int s = blockIdx.x * TPB + threadIdx.x;
  if (s >= NE) return;
  int e = eid_row[s];
  int c = ei[NE + e];
  int p = atomicAdd(&cur_col[c], 1);
  slot_col[p] = s;
}

// ---------------- per-layer kernels ----------------

// xp = x@pw^T + pb ; root = xp@rw^T + cb ; B[n,o] = sum_i xp[i]*eb2[i*D+o]
template<int DIN, int D>
__global__ void __launch_bounds__(TPB)
k_nodeprep(const float* __restrict__ x, const float* __restrict__ pw, const float* __restrict__ pb,
           const float* __restrict__ rw, const float* __restrict__ cb, const float* __restrict__ eb2,
           float* __restrict__ xp, float* __restrict__ root, float* __restrict__ Bb) {
  __shared__ float s_pw[D * DIN], s_rw[D * D], s_eb2[D * D], s_pb[D], s_cb[D];
  for (int t = threadIdx.x; t < D * DIN; t += TPB) s_pw[t] = pw[t];
  for (int t = threadIdx.x; t < D * D; t += TPB) { s_rw[t] = rw[t]; s_eb2[t] = eb2[t]; }
  for (int t = threadIdx.x; t < D; t += TPB) { s_pb[t] = pb[t]; s_cb[t] = cb[t]; }
  __syncthreads();
  int n = blockIdx.x * TPB + threadIdx.x;
  if (n >= NN) return;
  float xv[DIN];
  const float4* x4 = (const float4*)(x + (size_t)n * DIN);
  #pragma unroll
  for (int i = 0; i < DIN / 4; i++) {
    float4 v = x4[i];
    xv[4*i+0] = v.x; xv[4*i+1] = v.y; xv[4*i+2] = v.z; xv[4*i+3] = v.w;
  }
  float xpv[D];
  #pragma unroll
  for (int o = 0; o < D; o++) {
    float a = s_pb[o];
    #pragma unroll
    for (int i = 0; i < DIN; i++) a = fmaf(s_pw[o*DIN + i], xv[i], a);
    xpv[o] = a;
    xp[(size_t)n*D + o] = a;
  }
  #pragma unroll
  for (int o = 0; o < D; o++) {
    float a = s_cb[o];
    #pragma unroll
    for (int i = 0; i < D; i++) a = fmaf(s_rw[o*D + i], xpv[i], a);
    root[(size_t)n*D + o] = a;
  }
  #pragma unroll
  for (int o = 0; o < D; o++) {
    float a = 0.f;
    #pragma unroll
    for (int i = 0; i < D; i++) a = fmaf(xpv[i], s_eb2[i*D + o], a);
    Bb[(size_t)n*D + o] = a;
  }
}

// V packed bf16 pairs over i (K of phase B):
// word index t = i2*(2*UW) + w*2 + p, w = k2*D + o, p = k&1, k = 2*k2+p
// Vp[t] = pack(ew2[(2*i2  )*D+o][k], ew2[(2*i2+1)*D+o][k])
__global__ void k_trans(const float* __restrict__ ew2, uint32* __restrict__ Vp, int D) {
  int t = blockIdx.x * TPB + threadIdx.x;
  int COLS = D * 128;
  int T = (D / 2) * COLS;
  if (t >= T) return;
  int i2 = t / COLS;
  int r = t - i2 * COLS;
  int w = r >> 1, p = r & 1;
  int k2 = w / D, o = w - k2 * D;
  int k = 2 * k2 + p;
  float lo = ew2[((size_t)((2 * i2) * D + o)) * 128 + k];
  float hi = ew2[((size_t)((2 * i2 + 1) * D + o)) * 128 + k];
  Vp[t] = pk2bf(lo, hi);
}

// Fused, split-k over blockIdx.y (half = 0/1).
// Phase B: half U-rows (packed bf16 k-pairs, word[k2loc*D+o], row stride UP) into LDS.
// Phase C: h (half k-range) via dot2 -> packed k-pairs; partial msg = h.U (+B if half 0)
//          written to msgH[half].
template<int D, int G>
__global__ void __launch_bounds__(TPB)
k_fused(const int* __restrict__ eid_row, const int* __restrict__ row_off,
        const float* __restrict__ ea, const float* __restrict__ ew1,
        const float* __restrict__ eb1, const uint32* __restrict__ Vp,
        const float* __restrict__ xp, const float* __restrict__ Bb,
        float* __restrict__ msg0, float* __restrict__ msg1) {
  constexpr int OQ = D / 4;            // threads per edge
  constexpr int EB = TPB / OQ;         // edges per inner iteration
  constexpr int COLS = D * 128;
  constexpr int UW = COLS / 2;         // u32 words per full U-row
  constexpr int UH = UW / 2;           // words per half U-row
  constexpr int UP = UH + 4;           // padded row stride (bank stagger, 16B-aligned)
  constexpr int CT = UH / TPB;         // words per thread (4 for D32, 2 for D16)

  __shared__ __align__(16) uint32 s_w1tp[4 * 64];   // packed ew1 i-pairs: [i2][kloc]
  __shared__ float  s_b1[64];
  __shared__ __align__(16) uint32 s_U[G * UP];      // packed bf16 k-pairs (half)
  __shared__ __align__(16) uint32 s_hp[EB * 34];    // packed bf16 h k-pairs (half), stride 34
  __shared__ __align__(16) uint32 s_eap[EB * 4];    // packed ea i-pairs
  __shared__ uint32 s_xp2[G][D / 2];                // packed xp i-pairs
  __shared__ float  s_B[G * D];
  __shared__ int    s_off[G + 1];

  int tid = threadIdx.x;
  int half = blockIdx.y;
  int n0 = blockIdx.x * G;
  int GA = NN - n0; if (GA > G) GA = G;
  float* msgH = half ? msg1 : msg0;

  // ---- phase A: stage weights (this k-half) + per-node vectors ----
  for (int t = tid; t < 4 * 64; t += TPB) {
    int i2 = t >> 6, kloc = t & 63;
    int k = half * 64 + kloc;
    s_w1tp[t] = pk2bf(ew1[k * 8 + 2 * i2], ew1[k * 8 + 2 * i2 + 1]);
  }
  for (int t = tid; t < 64; t += TPB) s_b1[t] = eb1[half * 64 + t];
  for (int t = tid; t < G * (D / 2); t += TPB) {
    int g = t / (D / 2), i2 = t % (D / 2);
    if (g < GA) {
      float2 v = *(const float2*)(xp + (size_t)(n0 + g) * D + 2 * i2);
      s_xp2[g][i2] = pk2bf(v.x, v.y);
    } else {
      s_xp2[g][i2] = 0;
    }
  }
  for (int t = tid; t < G * D; t += TPB) {
    int g = t / D, i = t % D;
    s_B[t] = (g < GA && half == 0) ? Bb[(size_t)(n0 + g) * D + i] : 0.f;
  }
  if (tid <= GA) s_off[tid] = row_off[n0 + tid];
  __syncthreads();

  // ---- phase B: half U-rows into LDS via dot2 (CT words x G nodes / thread) ----
  {
    const uint2* Vp2 = (const uint2*)Vp;   // [i2][w] -> {p=0 word, p=1 word}
    float accLo[G][CT], accHi[G][CT];
    #pragma unroll
    for (int g = 0; g < G; g++)
      #pragma unroll
      for (int j = 0; j < CT; j++) { accLo[g][j] = 0.f; accHi[g][j] = 0.f; }
    #pragma unroll 2
    for (int i2 = 0; i2 < D / 2; i2++) {
      uint2 vv[CT];
      #pragma unroll
      for (int j = 0; j < CT; j++)
        vv[j] = Vp2[(size_t)i2 * UW + half * UH + j * TPB + tid];
      #pragma unroll
      for (int g = 0; g < G; g++) {
        uint32 xg = s_xp2[g][i2];
        #pragma unroll
        for (int j = 0; j < CT; j++) {
          dot2bf(accLo[g][j], xg, vv[j].x);
          dot2bf(accHi[g][j], xg, vv[j].y);
        }
      }
    }
    #pragma unroll
    for (int g = 0; g < G; g++)
      #pragma unroll
      for (int j = 0; j < CT; j++)
        s_U[g * UP + j * TPB + tid] = pk2bf(accLo[g][j], accHi[g][j]);
  }

  // ---- phase C: edges of the group (contiguous sorted slots) ----
  int p0 = row_off[n0], p1 = row_off[n0 + GA];
  int el = tid / OQ, oq = tid % OQ;
  for (int pc = p0; pc < p1; pc += EB) {
    int cnt = p1 - pc; if (cnt > EB) cnt = EB;
    __syncthreads();   // first iter: phase A/B done; later: protect s_eap/s_hp reuse
    for (int t = tid; t < cnt * 4; t += TPB) {
      int e2 = t >> 2, i2 = t & 3;
      float2 v = *(const float2*)(ea + (size_t)eid_row[pc + e2] * 8 + 2 * i2);
      s_eap[t] = pk2bf(v.x, v.y);
    }
    __syncthreads();
    // h (half k-range) packed as bf16 k-pairs via dot2
    for (int t = tid; t < cnt * 32; t += TPB) {
      int e2 = t >> 5, k2 = t & 31;
      float a0 = s_b1[2 * k2], a1 = s_b1[2 * k2 + 1];
      #pragma unroll
      for (int i2 = 0; i2 < 4; i2++) {
        uint32 ep = s_eap[e2 * 4 + i2];
        uint2 ww = *(const uint2*)(s_w1tp + i2 * 64 + 2 * k2);
        dot2bf(a0, ep, ww.x);
        dot2bf(a1, ep, ww.y);
      }
      s_hp[e2 * 34 + k2] = pk2bf(fmaxf(a0, 0.f), fmaxf(a1, 0.f));
    }
    __syncthreads();
    if (el < cnt) {
      int s = pc + el;
      int g = 0;
      #pragma unroll
      for (int q = 1; q < G; q++) g += (q < GA && s >= s_off[q]) ? 1 : 0;
      const uint32* up = s_U + g * UP + oq * 4;
      const uint32* hp = s_hp + el * 34;
      float a0 = 0.f, a1 = 0.f, a2 = 0.f, a3 = 0.f;
      #pragma unroll 4
      for (int k4 = 0; k4 < 16; k4++) {
        uint2 hw = *(const uint2*)(hp + 2 * k4);
        uint4 u0 = *(const uint4*)(up + (2 * k4) * D);
        uint4 u1 = *(const uint4*)(up + (2 * k4 + 1) * D);
        dot2bf(a0, hw.x, u0.x); dot2bf(a1, hw.x, u0.y);
        dot2bf(a2, hw.x, u0.z); dot2bf(a3, hw.x, u0.w);
        dot2bf(a0, hw.y, u1.x); dot2bf(a1, hw.y, u1.y);
        dot2bf(a2, hw.y, u1.z); dot2bf(a3, hw.y, u1.w);
      }
      float4 b = ((const float4*)(s_B + g * D))[oq];
      float4 o4 = {a0 + b.x, a1 + b.y, a2 + b.z, a3 + b.w};
      ((float4*)(msgH + (size_t)s * D))[oq] = o4;
    }
  }
}

// gather aggregation by col-CSR (deterministic), sums both k-halves,
// then x = relu(agg/deg + root) + xp
template<int D>
__global__ void __launch_bounds__(TPB)
k_agg(const int* __restrict__ col_off, const int* __restrict__ slot_col,
      const float* __restrict__ msg0, const float* __restrict__ msg1,
      const float* __restrict__ root, const float* __restrict__ xp,
      float* __restrict__ xout) {
  constexpr int GP = TPB / D;
  int g = threadIdx.x / D, o = threadIdx.x % D;
  int n = blockIdx.x * GP + g;
  if (n >= NN) return;
  int p0 = col_off[n], p1 = col_off[n + 1];
  float acc = 0.f;
  for (int p = p0; p < p1; p++) {
    int sc = slot_col[p];
    acc += msg0[(size_t)sc * D + o] + msg1[(size_t)sc * D + o];
  }
  float deg = (p1 > p0) ? (float)(p1 - p0) : 1.f;
  float conv = acc / deg + root[(size_t)n * D + o];
  float rl = conv > 0.f ? conv : 0.f;
  xout[(size_t)n * D + o] = rl + xp[(size_t)n * D + o];
}

// final edge MLP: out = relu((x[row]+x[col]) @ mw0^T + mb0) @ mw1^T + mb1
__global__ void __launch_bounds__(TPB)
k_final(const int* __restrict__ ei, const float* __restrict__ x,
        const float* __restrict__ mw0, const float* __restrict__ mb0,
        const float* __restrict__ mw1, const float* __restrict__ mb1,
        float* __restrict__ out) {
  __shared__ float s_w0[256], s_b0[16], s_w1[16], s_b1;
  for (int t = threadIdx.x; t < 256; t += TPB) s_w0[t] = mw0[t];
  if (threadIdx.x < 16) { s_b0[threadIdx.x] = mb0[threadIdx.x]; s_w1[threadIdx.x] = mw1[threadIdx.x]; }
  if (threadIdx.x == 0) s_b1 = mb1[0];
  __syncthreads();
  int e = blockIdx.x * TPB + threadIdx.x;
  if (e >= NE) return;
  int r = ei[e], c = ei[NE + e];
  const float4* xr4 = (const float4*)(x + (size_t)r * 16);
  const float4* xc4 = (const float4*)(x + (size_t)c * 16);
  float er[16];
  #pragma unroll
  for (int q = 0; q < 4; q++) {
    float4 vr = xr4[q], vc = xc4[q];
    er[4*q+0] = vr.x + vc.x; er[4*q+1] = vr.y + vc.y;
    er[4*q+2] = vr.z + vc.z; er[4*q+3] = vr.w + vc.w;
  }
  float o = s_b1;
  #pragma unroll
  for (int j = 0; j < 16; j++) {
    float t = s_b0[j];
    #pragma unroll
    for (int k = 0; k < 16; k++) t = fmaf(er[k], s_w0[j * 16 + k], t);
    t = fmaxf(t, 0.f);
    o = fmaf(t, s_w1[j], o);
  }
  out[e] = o;
}

// ---------------- host side ----------------

struct LayerPtrs {
  const float *pw, *pb, *ew1, *eb1, *ew2, *eb2, *rw, *cb;
};

template<int DIN, int D, int G>
static void run_layer(const float* xin, float* xout, const LayerPtrs& L,
                      const int* ei, const float* ea,
                      const int* row_off, const int* col_off,
                      const int* eid_row, const int* slot_col,
                      float* xp, float* root, float* Bb,
                      float* msg0, float* msg1, uint32* Vp,
                      hipStream_t stream) {
  k_nodeprep<DIN, D><<<(NN + TPB - 1) / TPB, TPB, 0, stream>>>(
      xin, L.pw, L.pb, L.rw, L.cb, L.eb2, xp, root, Bb);
  constexpr int COLS = D * 128;
  constexpr int T = (D / 2) * COLS;
  k_trans<<<(T + TPB - 1) / TPB, TPB, 0, stream>>>(L.ew2, Vp, D);
  dim3 gf((NN + G - 1) / G, 2);
  k_fused<D, G><<<gf, TPB, 0, stream>>>(
      eid_row, row_off, ea, L.ew1, L.eb1, Vp, xp, Bb, msg0, msg1);
  k_agg<D><<<(NN * D + TPB - 1) / TPB, TPB, 0, stream>>>(
      col_off, slot_col, msg0, msg1, root, xp, xout);
}

extern "C" void kernel_launch(void* const* d_in, const int* in_sizes, int n_in,
                              void* d_out, int out_size, void* d_ws, size_t ws_size,
                              hipStream_t stream) {
  (void)in_sizes; (void)n_in; (void)out_size; (void)ws_size;
  const float* x0 = (const float*)d_in[0];
  const float* ea = (const float*)d_in[1];
  const int* ei = (const int*)d_in[2];
  LayerPtrs L[4];
  for (int l = 0; l < 4; l++) {
    L[l].pw  = (const float*)d_in[3 + 8 * l];
    L[l].pb  = (const float*)d_in[4 + 8 * l];
    L[l].ew1 = (const float*)d_in[5 + 8 * l];
    L[l].eb1 = (const float*)d_in[6 + 8 * l];
    L[l].ew2 = (const float*)d_in[7 + 8 * l];
    L[l].eb2 = (const float*)d_in[8 + 8 * l];
    L[l].rw  = (const float*)d_in[9 + 8 * l];
    L[l].cb  = (const float*)d_in[10 + 8 * l];
  }
  const float* mw0 = (const float*)d_in[35];
  const float* mb0 = (const float*)d_in[36];
  const float* mw1 = (const float*)d_in[37];
  const float* mb1 = (const float*)d_in[38];
  float* out = (float*)d_out;

  char* w = (char*)d_ws;
  size_t off = 0;
  auto alloc = [&](size_t b) -> void* {
    void* p = w + off;
    off = (off + b + 255) & ~(size_t)255;
    return p;
  };
  int* cnt_row  = (int*)alloc(sizeof(int) * NN);
  int* cnt_col  = (int*)alloc(sizeof(int) * NN);
  int* row_off  = (int*)alloc(sizeof(int) * (NN + 1));
  int* col_off  = (int*)alloc(sizeof(int) * (NN + 1));
  int* cur_row  = (int*)alloc(sizeof(int) * NN);
  int* cur_col  = (int*)alloc(sizeof(int) * NN);
  int* eid_row  = (int*)alloc(sizeof(int) * NE);
  int* slot_col = (int*)alloc(sizeof(int) * NE);
  float* xb0  = (float*)alloc(sizeof(float) * NN * 32);
  float* xb1  = (float*)alloc(sizeof(float) * NN * 32);
  float* xp   = (float*)alloc(sizeof(float) * NN * 32);
  float* root = (float*)alloc(sizeof(float) * NN * 32);
  float* Bb   = (float*)alloc(sizeof(float) * NN * 32);
  float* msg0 = (float*)alloc(sizeof(float) * NE * 32);
  float* msg1 = (float*)alloc(sizeof(float) * NE * 32);
  uint32* Vp  = (uint32*)alloc(sizeof(uint32) * 16 * 4096);  // 256 KB max

  hipMemsetAsync(cnt_row, 0, sizeof(int) * NN, stream);
  hipMemsetAsync(cnt_col, 0, sizeof(int) * NN, stream);
  k_count<<<(NE + TPB - 1) / TPB, TPB, 0, stream>>>(ei, cnt_row, cnt_col);
  k_scan2<<<2, SCAN_T, 0, stream>>>(cnt_row, row_off, cur_row, cnt_col, col_off, cur_col);
  k_fill_row<<<(NE + TPB - 1) / TPB, TPB, 0, stream>>>(ei, cur_row, eid_row);
  k_fill_col<<<(NE + TPB - 1) / TPB, TPB, 0, stream>>>(ei, eid_row, cur_col, slot_col);

  float* bufs[2] = {xb0, xb1};
  const float* xin = x0;
  for (int l = 0; l < 4; l++) {
    float* xout = bufs[l & 1];
    if (l == 0) {
      run_layer<16, 32, 4>(xin, xout, L[0], ei, ea, row_off, col_off, eid_row, slot_col,
                           xp, root, Bb, msg0, msg1, Vp, stream);
    } else if (l == 1) {
      run_layer<32, 16, 6>(xin, xout, L[1], ei, ea, row_off, col_off, eid_row, slot_col,
                           xp, root, Bb, msg0, msg1, Vp, stream);
    } else if (l == 2) {
      run_layer<16, 16, 6>(xin, xout, L[2], ei, ea, row_off, col_off, eid_row, slot_col,
                           xp, root, Bb, msg0, msg1, Vp, stream);
    } else {
      run_layer<16, 16, 6>(xin, xout, L[3], ei, ea, row_off, col_off, eid_row, slot_col,
                           xp, root, Bb, msg0, msg1, Vp, stream);
    }
    xin = xout;
  }
  k_final<<<(NE + TPB - 1) / TPB, TPB, 0, stream>>>(ei, xin, mw0, mb0, mw1, mb1, out);
}

// Round 12
// 334.796 us; speedup vs baseline: 2.2852x; 1.0589x over previous
//
#include <hip/hip_runtime.h>

#define NN 10000
#define NE 160000
static constexpr int TPB = 256;
static constexpr int SCAN_T = 1024;

typedef unsigned int uint32;

static __device__ __forceinline__ ushort f2bf(float f) {
  uint32 u = __float_as_uint(f);
  u += 0x7fff + ((u >> 16) & 1);   // round-to-nearest-even
  return (ushort)(u >> 16);
}
static __device__ __forceinline__ uint32 pk2bf(float a, float b) {
  return (uint32)f2bf(a) | ((uint32)f2bf(b) << 16);
}
// acc += a.lo*b.lo + a.hi*b.hi  (packed bf16 pairs, f32 accumulate)
static __device__ __forceinline__ void dot2bf(float& acc, uint32 a, uint32 b) {
  asm("v_dot2_f32_bf16 %0, %1, %2, %0" : "+v"(acc) : "v"(a), "v"(b));
}

// ---------------- sort / CSR build ----------------

__global__ void k_count(const int* __restrict__ ei, int* __restrict__ cnt_row,
                        int* __restrict__ cnt_col) {
  int e = blockIdx.x * TPB + threadIdx.x;
  if (e >= NE) return;
  atomicAdd(&cnt_row[ei[e]], 1);
  atomicAdd(&cnt_col[ei[NE + e]], 1);
}

// 16-wave block scan: block 0 -> row CSR, block 1 -> col CSR.
__global__ void __launch_bounds__(SCAN_T)
k_scan2(const int* __restrict__ cnt_r, int* __restrict__ off_r, int* __restrict__ cur_r,
        const int* __restrict__ cnt_c, int* __restrict__ off_c, int* __restrict__ cur_c) {
  const int* cnt = (blockIdx.x == 0) ? cnt_r : cnt_c;
  int* off = (blockIdx.x == 0) ? off_r : off_c;
  int* cur = (blockIdx.x == 0) ? cur_r : cur_c;
  __shared__ int s_wave[16];
  __shared__ int s_carry;
  int tid = threadIdx.x;
  int lane = tid & 63, wid = tid >> 6;
  if (tid == 0) s_carry = 0;
  __syncthreads();
  for (int base = 0; base < NN; base += SCAN_T) {
    int i = base + tid;
    int v = (i < NN) ? cnt[i] : 0;
    int s = v;
    #pragma unroll
    for (int d = 1; d < 64; d <<= 1) {
      int t = __shfl_up(s, d, 64);
      if (lane >= d) s += t;
    }
    if (lane == 63) s_wave[wid] = s;
    __syncthreads();
    if (wid == 0 && lane < 16) {
      int ws = s_wave[lane];
      #pragma unroll
      for (int d = 1; d < 16; d <<= 1) {
        int t = __shfl_up(ws, d, 64);
        if (lane >= d) ws += t;
      }
      s_wave[lane] = ws;   // inclusive wave-sum scan
    }
    __syncthreads();
    int waveoff = (wid > 0) ? s_wave[wid - 1] : 0;
    int excl = s_carry + waveoff + s - v;
    if (i < NN) { off[i] = excl; cur[i] = excl; }
    __syncthreads();   // all reads of s_carry/s_wave done
    if (tid == 0) s_carry += s_wave[15];
    __syncthreads();
  }
  if (tid == 0) off[NN] = s_carry;
}

__global__ void k_fill_row(const int* __restrict__ ei, int* __restrict__ cur_row,
                           int* __restrict__ eid_row) {
  int e = blockIdx.x * TPB + threadIdx.x;
  if (e >= NE) return;
  int r = ei[e];
  int p = atomicAdd(&cur_row[r], 1);
  eid_row[p] = e;
}

__global__ void k_fill_col(const int* __restrict__ ei, const int* __restrict__ eid_row,
                           int* __restrict__ cur_col, int* __restrict__ slot_col) {
  int s = blockIdx.x * TPB + threadIdx.x;
  if (s >= NE) return;
  int e = eid_row[s];
  int c = ei[NE + e];
  int p = atomicAdd(&cur_col[c], 1);
  slot_col[p] = s;
}

// inverse permutation: colpos[slot] = col-sorted position
__global__ void k_invperm(const int* __restrict__ slot_col, int* __restrict__ colpos) {
  int p = blockIdx.x * TPB + threadIdx.x;
  if (p >= NE) return;
  colpos[slot_col[p]] = p;
}

// ---------------- per-layer kernels ----------------

// xp = x@pw^T + pb ; root = xp@rw^T + cb ; B[n,o] = sum_i xp[i]*eb2[i*D+o]
template<int DIN, int D>
__global__ void __launch_bounds__(TPB)
k_nodeprep(const float* __restrict__ x, const float* __restrict__ pw, const float* __restrict__ pb,
           const float* __restrict__ rw, const float* __restrict__ cb, const float* __restrict__ eb2,
           float* __restrict__ xp, float* __restrict__ root, float* __restrict__ Bb) {
  __shared__ float s_pw[D * DIN], s_rw[D * D], s_eb2[D * D], s_pb[D], s_cb[D];
  for (int t = threadIdx.x; t < D * DIN; t += TPB) s_pw[t] = pw[t];
  for (int t = threadIdx.x; t < D * D; t += TPB) { s_rw[t] = rw[t]; s_eb2[t] = eb2[t]; }
  for (int t = threadIdx.x; t < D; t += TPB) { s_pb[t] = pb[t]; s_cb[t] = cb[t]; }
  __syncthreads();
  int n = blockIdx.x * TPB + threadIdx.x;
  if (n >= NN) return;
  float xv[DIN];
  const float4* x4 = (const float4*)(x + (size_t)n * DIN);
  #pragma unroll
  for (int i = 0; i < DIN / 4; i++) {
    float4 v = x4[i];
    xv[4*i+0] = v.x; xv[4*i+1] = v.y; xv[4*i+2] = v.z; xv[4*i+3] = v.w;
  }
  float xpv[D];
  #pragma unroll
  for (int o = 0; o < D; o++) {
    float a = s_pb[o];
    #pragma unroll
    for (int i = 0; i < DIN; i++) a = fmaf(s_pw[o*DIN + i], xv[i], a);
    xpv[o] = a;
    xp[(size_t)n*D + o] = a;
  }
  #pragma unroll
  for (int o = 0; o < D; o++) {
    float a = s_cb[o];
    #pragma unroll
    for (int i = 0; i < D; i++) a = fmaf(s_rw[o*D + i], xpv[i], a);
    root[(size_t)n*D + o] = a;
  }
  #pragma unroll
  for (int o = 0; o < D; o++) {
    float a = 0.f;
    #pragma unroll
    for (int i = 0; i < D; i++) a = fmaf(xpv[i], s_eb2[i*D + o], a);
    Bb[(size_t)n*D + o] = a;
  }
}

// V packed bf16 pairs over i (K of phase B):
// word index t = i2*(2*UW) + w*2 + p, w = k2*D + o, p = k&1, k = 2*k2+p
// Vp[t] = pack(ew2[(2*i2  )*D+o][k], ew2[(2*i2+1)*D+o][k])
__global__ void k_trans(const float* __restrict__ ew2, uint32* __restrict__ Vp, int D) {
  int t = blockIdx.x * TPB + threadIdx.x;
  int COLS = D * 128;
  int T = (D / 2) * COLS;
  if (t >= T) return;
  int i2 = t / COLS;
  int r = t - i2 * COLS;
  int w = r >> 1, p = r & 1;
  int k2 = w / D, o = w - k2 * D;
  int k = 2 * k2 + p;
  float lo = ew2[((size_t)((2 * i2) * D + o)) * 128 + k];
  float hi = ew2[((size_t)((2 * i2 + 1) * D + o)) * 128 + k];
  Vp[t] = pk2bf(lo, hi);
}

// Fused, split-k over blockIdx.y (half = 0/1).
// Phase B: half U-rows (packed bf16 k-pairs, word[k2loc*D+o], row stride UP) into LDS.
// Phase C: h (half k-range) via dot2 -> packed k-pairs; partial msg = h.U (+B if half 0)
//          scattered to msgH[colpos[s]] (col-sorted order for sequential k_agg).
template<int D, int G>
__global__ void __launch_bounds__(TPB)
k_fused(const int* __restrict__ eid_row, const int* __restrict__ row_off,
        const int* __restrict__ colpos,
        const float* __restrict__ ea, const float* __restrict__ ew1,
        const float* __restrict__ eb1, const uint32* __restrict__ Vp,
        const float* __restrict__ xp, const float* __restrict__ Bb,
        float* __restrict__ msg0, float* __restrict__ msg1) {
  constexpr int OQ = D / 4;            // threads per edge
  constexpr int EB = TPB / OQ;         // edges per inner iteration
  constexpr int COLS = D * 128;
  constexpr int UW = COLS / 2;         // u32 words per full U-row
  constexpr int UH = UW / 2;           // words per half U-row
  constexpr int UP = UH + 4;           // padded row stride (bank stagger, 16B-aligned)
  constexpr int CT = UH / TPB;         // words per thread (4 for D32, 2 for D16)

  __shared__ __align__(16) uint32 s_w1tp[4 * 64];   // packed ew1 i-pairs: [i2][kloc]
  __shared__ float  s_b1[64];
  __shared__ __align__(16) uint32 s_U[G * UP];      // packed bf16 k-pairs (half)
  __shared__ __align__(16) uint32 s_hp[EB * 34];    // packed bf16 h k-pairs (half), stride 34
  __shared__ __align__(16) uint32 s_eap[EB * 4];    // packed ea i-pairs
  __shared__ int    s_cp[EB];                       // col-sorted dest of each edge
  __shared__ uint32 s_xp2[G][D / 2];                // packed xp i-pairs
  __shared__ float  s_B[G * D];
  __shared__ int    s_off[G + 1];

  int tid = threadIdx.x;
  int half = blockIdx.y;
  int n0 = blockIdx.x * G;
  int GA = NN - n0; if (GA > G) GA = G;
  float* msgH = half ? msg1 : msg0;

  // ---- phase A: stage weights (this k-half) + per-node vectors ----
  for (int t = tid; t < 4 * 64; t += TPB) {
    int i2 = t >> 6, kloc = t & 63;
    int k = half * 64 + kloc;
    s_w1tp[t] = pk2bf(ew1[k * 8 + 2 * i2], ew1[k * 8 + 2 * i2 + 1]);
  }
  for (int t = tid; t < 64; t += TPB) s_b1[t] = eb1[half * 64 + t];
  for (int t = tid; t < G * (D / 2); t += TPB) {
    int g = t / (D / 2), i2 = t % (D / 2);
    if (g < GA) {
      float2 v = *(const float2*)(xp + (size_t)(n0 + g) * D + 2 * i2);
      s_xp2[g][i2] = pk2bf(v.x, v.y);
    } else {
      s_xp2[g][i2] = 0;
    }
  }
  for (int t = tid; t < G * D; t += TPB) {
    int g = t / D, i = t % D;
    s_B[t] = (g < GA && half == 0) ? Bb[(size_t)(n0 + g) * D + i] : 0.f;
  }
  if (tid <= GA) s_off[tid] = row_off[n0 + tid];
  __syncthreads();

  // ---- phase B: half U-rows into LDS via dot2 (CT words x G nodes / thread) ----
  {
    const uint2* Vp2 = (const uint2*)Vp;   // [i2][w] -> {p=0 word, p=1 word}
    float accLo[G][CT], accHi[G][CT];
    #pragma unroll
    for (int g = 0; g < G; g++)
      #pragma unroll
      for (int j = 0; j < CT; j++) { accLo[g][j] = 0.f; accHi[g][j] = 0.f; }
    #pragma unroll 2
    for (int i2 = 0; i2 < D / 2; i2++) {
      uint2 vv[CT];
      #pragma unroll
      for (int j = 0; j < CT; j++)
        vv[j] = Vp2[(size_t)i2 * UW + half * UH + j * TPB + tid];
      #pragma unroll
      for (int g = 0; g < G; g++) {
        uint32 xg = s_xp2[g][i2];
        #pragma unroll
        for (int j = 0; j < CT; j++) {
          dot2bf(accLo[g][j], xg, vv[j].x);
          dot2bf(accHi[g][j], xg, vv[j].y);
        }
      }
    }
    #pragma unroll
    for (int g = 0; g < G; g++)
      #pragma unroll
      for (int j = 0; j < CT; j++)
        s_U[g * UP + j * TPB + tid] = pk2bf(accLo[g][j], accHi[g][j]);
  }

  // ---- phase C: edges of the group (contiguous sorted slots) ----
  int p0 = row_off[n0], p1 = row_off[n0 + GA];
  int el = tid / OQ, oq = tid % OQ;
  for (int pc = p0; pc < p1; pc += EB) {
    int cnt = p1 - pc; if (cnt > EB) cnt = EB;
    __syncthreads();   // first iter: phase A/B done; later: protect s_eap/s_hp reuse
    for (int t = tid; t < cnt * 4; t += TPB) {
      int e2 = t >> 2, i2 = t & 3;
      float2 v = *(const float2*)(ea + (size_t)eid_row[pc + e2] * 8 + 2 * i2);
      s_eap[t] = pk2bf(v.x, v.y);
    }
    for (int t = tid; t < cnt; t += TPB) s_cp[t] = colpos[pc + t];
    __syncthreads();
    // h (half k-range) packed as bf16 k-pairs via dot2
    for (int t = tid; t < cnt * 32; t += TPB) {
      int e2 = t >> 5, k2 = t & 31;
      float a0 = s_b1[2 * k2], a1 = s_b1[2 * k2 + 1];
      #pragma unroll
      for (int i2 = 0; i2 < 4; i2++) {
        uint32 ep = s_eap[e2 * 4 + i2];
        uint2 ww = *(const uint2*)(s_w1tp + i2 * 64 + 2 * k2);
        dot2bf(a0, ep, ww.x);
        dot2bf(a1, ep, ww.y);
      }
      s_hp[e2 * 34 + k2] = pk2bf(fmaxf(a0, 0.f), fmaxf(a1, 0.f));
    }
    __syncthreads();
    if (el < cnt) {
      int s = pc + el;
      int g = 0;
      #pragma unroll
      for (int q = 1; q < G; q++) g += (q < GA && s >= s_off[q]) ? 1 : 0;
      const uint32* up = s_U + g * UP + oq * 4;
      const uint32* hp = s_hp + el * 34;
      float a0 = 0.f, a1 = 0.f, a2 = 0.f, a3 = 0.f;
      #pragma unroll 4
      for (int k4 = 0; k4 < 16; k4++) {
        uint2 hw = *(const uint2*)(hp + 2 * k4);
        uint4 u0 = *(const uint4*)(up + (2 * k4) * D);
        uint4 u1 = *(const uint4*)(up + (2 * k4 + 1) * D);
        dot2bf(a0, hw.x, u0.x); dot2bf(a1, hw.x, u0.y);
        dot2bf(a2, hw.x, u0.z); dot2bf(a3, hw.x, u0.w);
        dot2bf(a0, hw.y, u1.x); dot2bf(a1, hw.y, u1.y);
        dot2bf(a2, hw.y, u1.z); dot2bf(a3, hw.y, u1.w);
      }
      float4 b = ((const float4*)(s_B + g * D))[oq];
      float4 o4 = {a0 + b.x, a1 + b.y, a2 + b.z, a3 + b.w};
      ((float4*)(msgH + (size_t)s_cp[el] * D))[oq] = o4;
    }
  }
}

// gather aggregation: msg already in col-sorted order -> sequential reads.
// x = relu(agg/deg + root) + xp
template<int D>
__global__ void __launch_bounds__(TPB)
k_agg(const int* __restrict__ col_off,
      const float* __restrict__ msg0, const float* __restrict__ msg1,
      const float* __restrict__ root, const float* __restrict__ xp,
      float* __restrict__ xout) {
  constexpr int GP = TPB / D;
  int g = threadIdx.x / D, o = threadIdx.x % D;
  int n = blockIdx.x * GP + g;
  if (n >= NN) return;
  int p0 = col_off[n], p1 = col_off[n + 1];
  float acc = 0.f;
  for (int p = p0; p < p1; p++) {
    acc += msg0[(size_t)p * D + o] + msg1[(size_t)p * D + o];
  }
  float deg = (p1 > p0) ? (float)(p1 - p0) : 1.f;
  float conv = acc / deg + root[(size_t)n * D + o];
  float rl = conv > 0.f ? conv : 0.f;
  xout[(size_t)n * D + o] = rl + xp[(size_t)n * D + o];
}

// final edge MLP: out = relu((x[row]+x[col]) @ mw0^T + mb0) @ mw1^T + mb1
__global__ void __launch_bounds__(TPB)
k_final(const int* __restrict__ ei, const float* __restrict__ x,
        const float* __restrict__ mw0, const float* __restrict__ mb0,
        const float* __restrict__ mw1, const float* __restrict__ mb1,
        float* __restrict__ out) {
  __shared__ float s_w0[256], s_b0[16], s_w1[16], s_b1;
  for (int t = threadIdx.x; t < 256; t += TPB) s_w0[t] = mw0[t];
  if (threadIdx.x < 16) { s_b0[threadIdx.x] = mb0[threadIdx.x]; s_w1[threadIdx.x] = mw1[threadIdx.x]; }
  if (threadIdx.x == 0) s_b1 = mb1[0];
  __syncthreads();
  int e = blockIdx.x * TPB + threadIdx.x;
  if (e >= NE) return;
  int r = ei[e], c = ei[NE + e];
  const float4* xr4 = (const float4*)(x + (size_t)r * 16);
  const float4* xc4 = (const float4*)(x + (size_t)c * 16);
  float er[16];
  #pragma unroll
  for (int q = 0; q < 4; q++) {
    float4 vr = xr4[q], vc = xc4[q];
    er[4*q+0] = vr.x + vc.x; er[4*q+1] = vr.y + vc.y;
    er[4*q+2] = vr.z + vc.z; er[4*q+3] = vr.w + vc.w;
  }
  float o = s_b1;
  #pragma unroll
  for (int j = 0; j < 16; j++) {
    float t = s_b0[j];
    #pragma unroll
    for (int k = 0; k < 16; k++) t = fmaf(er[k], s_w0[j * 16 + k], t);
    t = fmaxf(t, 0.f);
    o = fmaf(t, s_w1[j], o);
  }
  out[e] = o;
}

// ---------------- host side ----------------

struct LayerPtrs {
  const float *pw, *pb, *ew1, *eb1, *ew2, *eb2, *rw, *cb;
};

template<int DIN, int D, int G>
static void run_layer(const float* xin, float* xout, const LayerPtrs& L,
                      const int* ei, const float* ea,
                      const int* row_off, const int* col_off,
                      const int* eid_row, const int* colpos,
                      float* xp, float* root, float* Bb,
                      float* msg0, float* msg1, uint32* Vp,
                      hipStream_t stream) {
  k_nodeprep<DIN, D><<<(NN + TPB - 1) / TPB, TPB, 0, stream>>>(
      xin, L.pw, L.pb, L.rw, L.cb, L.eb2, xp, root, Bb);
  constexpr int COLS = D * 128;
  constexpr int T = (D / 2) * COLS;
  k_trans<<<(T + TPB - 1) / TPB, TPB, 0, stream>>>(L.ew2, Vp, D);
  dim3 gf((NN + G - 1) / G, 2);
  k_fused<D, G><<<gf, TPB, 0, stream>>>(
      eid_row, row_off, colpos, ea, L.ew1, L.eb1, Vp, xp, Bb, msg0, msg1);
  k_agg<D><<<(NN * D + TPB - 1) / TPB, TPB, 0, stream>>>(
      col_off, msg0, msg1, root, xp, xout);
}

extern "C" void kernel_launch(void* const* d_in, const int* in_sizes, int n_in,
                              void* d_out, int out_size, void* d_ws, size_t ws_size,
                              hipStream_t stream) {
  (void)in_sizes; (void)n_in; (void)out_size; (void)ws_size;
  const float* x0 = (const float*)d_in[0];
  const float* ea = (const float*)d_in[1];
  const int* ei = (const int*)d_in[2];
  LayerPtrs L[4];
  for (int l = 0; l < 4; l++) {
    L[l].pw  = (const float*)d_in[3 + 8 * l];
    L[l].pb  = (const float*)d_in[4 + 8 * l];
    L[l].ew1 = (const float*)d_in[5 + 8 * l];
    L[l].eb1 = (const float*)d_in[6 + 8 * l];
    L[l].ew2 = (const float*)d_in[7 + 8 * l];
    L[l].eb2 = (const float*)d_in[8 + 8 * l];
    L[l].rw  = (const float*)d_in[9 + 8 * l];
    L[l].cb  = (const float*)d_in[10 + 8 * l];
  }
  const float* mw0 = (const float*)d_in[35];
  const float* mb0 = (const float*)d_in[36];
  const float* mw1 = (const float*)d_in[37];
  const float* mb1 = (const float*)d_in[38];
  float* out = (float*)d_out;

  char* w = (char*)d_ws;
  size_t off = 0;
  auto alloc = [&](size_t b) -> void* {
    void* p = w + off;
    off = (off + b + 255) & ~(size_t)255;
    return p;
  };
  int* cnt_row  = (int*)alloc(sizeof(int) * NN);
  int* cnt_col  = (int*)alloc(sizeof(int) * NN);
  int* row_off  = (int*)alloc(sizeof(int) * (NN + 1));
  int* col_off  = (int*)alloc(sizeof(int) * (NN + 1));
  int* cur_row  = (int*)alloc(sizeof(int) * NN);
  int* cur_col  = (int*)alloc(sizeof(int) * NN);
  int* eid_row  = (int*)alloc(sizeof(int) * NE);
  int* slot_col = (int*)alloc(sizeof(int) * NE);
  int* colpos   = (int*)alloc(sizeof(int) * NE);
  float* xb0  = (float*)alloc(sizeof(float) * NN * 32);
  float* xb1  = (float*)alloc(sizeof(float) * NN * 32);
  float* xp   = (float*)alloc(sizeof(float) * NN * 32);
  float* root = (float*)alloc(sizeof(float) * NN * 32);
  float* Bb   = (float*)alloc(sizeof(float) * NN * 32);
  float* msg0 = (float*)alloc(sizeof(float) * NE * 32);
  float* msg1 = (float*)alloc(sizeof(float) * NE * 32);
  uint32* Vp  = (uint32*)alloc(sizeof(uint32) * 16 * 4096);  // 256 KB max

  hipMemsetAsync(cnt_row, 0, sizeof(int) * NN, stream);
  hipMemsetAsync(cnt_col, 0, sizeof(int) * NN, stream);
  k_count<<<(NE + TPB - 1) / TPB, TPB, 0, stream>>>(ei, cnt_row, cnt_col);
  k_scan2<<<2, SCAN_T, 0, stream>>>(cnt_row, row_off, cur_row, cnt_col, col_off, cur_col);
  k_fill_row<<<(NE + TPB - 1) / TPB, TPB, 0, stream>>>(ei, cur_row, eid_row);
  k_fill_col<<<(NE + TPB - 1) / TPB, TPB, 0, stream>>>(ei, eid_row, cur_col, slot_col);
  k_invperm<<<(NE + TPB - 1) / TPB, TPB, 0, stream>>>(slot_col, colpos);

  float* bufs[2] = {xb0, xb1};
  const float* xin = x0;
  for (int l = 0; l < 4; l++) {
    float* xout = bufs[l & 1];
    if (l == 0) {
      run_layer<16, 32, 4>(xin, xout, L[0], ei, ea, row_off, col_off, eid_row, colpos,
                           xp, root, Bb, msg0, msg1, Vp, stream);
    } else if (l == 1) {
      run_layer<32, 16, 6>(xin, xout, L[1], ei, ea, row_off, col_off, eid_row, colpos,
                           xp, root, Bb, msg0, msg1, Vp, stream);
    } else if (l == 2) {
      run_layer<16, 16, 6>(xin, xout, L[2], ei, ea, row_off, col_off, eid_row, colpos,
                           xp, root, Bb, msg0, msg1, Vp, stream);
    } else {
      run_layer<16, 16, 6>(xin, xout, L[3], ei, ea, row_off, col_off, eid_row, colpos,
                           xp, root, Bb, msg0, msg1, Vp, stream);
    }
    xin = xout;
  }
  k_final<<<(NE + TPB - 1) / TPB, TPB, 0, stream>>>(ei, xin, mw0, mb0, mw1, mb1, out);
}

// Round 13
// 302.633 us; speedup vs baseline: 2.5280x; 1.1063x over previous
//
#include <hip/hip_runtime.h>

#define NN 10000
#define NE 160000
static constexpr int TPB = 256;
static constexpr int SCAN_T = 1024;

typedef unsigned int uint32;

static __device__ __forceinline__ ushort f2bf(float f) {
  uint32 u = __float_as_uint(f);
  u += 0x7fff + ((u >> 16) & 1);   // round-to-nearest-even
  return (ushort)(u >> 16);
}
static __device__ __forceinline__ uint32 pk2bf(float a, float b) {
  return (uint32)f2bf(a) | ((uint32)f2bf(b) << 16);
}
// acc += a.lo*b.lo + a.hi*b.hi  (packed bf16 pairs, f32 accumulate)
static __device__ __forceinline__ void dot2bf(float& acc, uint32 a, uint32 b) {
  asm("v_dot2_f32_bf16 %0, %1, %2, %0" : "+v"(acc) : "v"(a), "v"(b));
}

// ---------------- sort / CSR build ----------------

// cnt = [row counts (NN) | col counts (NN)] contiguous
__global__ void k_count(const int* __restrict__ ei, int* __restrict__ cnt) {
  int e = blockIdx.x * TPB + threadIdx.x;
  if (e >= NE) return;
  atomicAdd(&cnt[ei[e]], 1);
  atomicAdd(&cnt[NN + ei[NE + e]], 1);
}

// 16-wave block scan: block 0 -> row CSR, block 1 -> col CSR.
__global__ void __launch_bounds__(SCAN_T)
k_scan2(const int* __restrict__ cnt_all, int* __restrict__ off_r, int* __restrict__ cur_r,
        int* __restrict__ off_c, int* __restrict__ cur_c) {
  const int* cnt = (blockIdx.x == 0) ? cnt_all : cnt_all + NN;
  int* off = (blockIdx.x == 0) ? off_r : off_c;
  int* cur = (blockIdx.x == 0) ? cur_r : cur_c;
  __shared__ int s_wave[16];
  __shared__ int s_carry;
  int tid = threadIdx.x;
  int lane = tid & 63, wid = tid >> 6;
  if (tid == 0) s_carry = 0;
  __syncthreads();
  for (int base = 0; base < NN; base += SCAN_T) {
    int i = base + tid;
    int v = (i < NN) ? cnt[i] : 0;
    int s = v;
    #pragma unroll
    for (int d = 1; d < 64; d <<= 1) {
      int t = __shfl_up(s, d, 64);
      if (lane >= d) s += t;
    }
    if (lane == 63) s_wave[wid] = s;
    __syncthreads();
    if (wid == 0 && lane < 16) {
      int ws = s_wave[lane];
      #pragma unroll
      for (int d = 1; d < 16; d <<= 1) {
        int t = __shfl_up(ws, d, 64);
        if (lane >= d) ws += t;
      }
      s_wave[lane] = ws;   // inclusive wave-sum scan
    }
    __syncthreads();
    int waveoff = (wid > 0) ? s_wave[wid - 1] : 0;
    int excl = s_carry + waveoff + s - v;
    if (i < NN) { off[i] = excl; cur[i] = excl; }
    __syncthreads();   // all reads of s_carry/s_wave done
    if (tid == 0) s_carry += s_wave[15];
    __syncthreads();
  }
  if (tid == 0) off[NN] = s_carry;
}

__global__ void k_fill_row(const int* __restrict__ ei, int* __restrict__ cur_row,
                           int* __restrict__ eid_row) {
  int e = blockIdx.x * TPB + threadIdx.x;
  if (e >= NE) return;
  int r = ei[e];
  int p = atomicAdd(&cur_row[r], 1);
  eid_row[p] = e;
}

// colpos[s] = position of sorted-slot s in col-sorted order (direct, no inverse pass)
__global__ void k_fill_colpos(const int* __restrict__ ei, const int* __restrict__ eid_row,
                              int* __restrict__ cur_col, int* __restrict__ colpos) {
  int s = blockIdx.x * TPB + threadIdx.x;
  if (s >= NE) return;
  int e = eid_row[s];
  int c = ei[NE + e];
  int p = atomicAdd(&cur_col[c], 1);
  colpos[s] = p;
}

// ---------------- per-layer kernels ----------------

// xp = x@pw^T + pb ; root = xp@rw^T + cb ; B[n,o] = sum_i xp[i]*eb2[i*D+o]
template<int DIN, int D>
__global__ void __launch_bounds__(TPB)
k_nodeprep(const float* __restrict__ x, const float* __restrict__ pw, const float* __restrict__ pb,
           const float* __restrict__ rw, const float* __restrict__ cb, const float* __restrict__ eb2,
           float* __restrict__ xp, float* __restrict__ root, float* __restrict__ Bb) {
  __shared__ float s_pw[D * DIN], s_rw[D * D], s_eb2[D * D], s_pb[D], s_cb[D];
  for (int t = threadIdx.x; t < D * DIN; t += TPB) s_pw[t] = pw[t];
  for (int t = threadIdx.x; t < D * D; t += TPB) { s_rw[t] = rw[t]; s_eb2[t] = eb2[t]; }
  for (int t = threadIdx.x; t < D; t += TPB) { s_pb[t] = pb[t]; s_cb[t] = cb[t]; }
  __syncthreads();
  int n = blockIdx.x * TPB + threadIdx.x;
  if (n >= NN) return;
  float xv[DIN];
  const float4* x4 = (const float4*)(x + (size_t)n * DIN);
  #pragma unroll
  for (int i = 0; i < DIN / 4; i++) {
    float4 v = x4[i];
    xv[4*i+0] = v.x; xv[4*i+1] = v.y; xv[4*i+2] = v.z; xv[4*i+3] = v.w;
  }
  float xpv[D];
  #pragma unroll
  for (int o = 0; o < D; o++) {
    float a = s_pb[o];
    #pragma unroll
    for (int i = 0; i < DIN; i++) a = fmaf(s_pw[o*DIN + i], xv[i], a);
    xpv[o] = a;
    xp[(size_t)n*D + o] = a;
  }
  #pragma unroll
  for (int o = 0; o < D; o++) {
    float a = s_cb[o];
    #pragma unroll
    for (int i = 0; i < D; i++) a = fmaf(s_rw[o*D + i], xpv[i], a);
    root[(size_t)n*D + o] = a;
  }
  #pragma unroll
  for (int o = 0; o < D; o++) {
    float a = 0.f;
    #pragma unroll
    for (int i = 0; i < D; i++) a = fmaf(xpv[i], s_eb2[i*D + o], a);
    Bb[(size_t)n*D + o] = a;
  }
}

// Fused agg + next-layer nodeprep (layers 1..3).
// Part 1: x[n] = relu(agg(msg)/deg + root_prev) + xp_prev  -> LDS
// Part 2: xp = x@pw^T+pb ; root = xp@rw^T+cb ; B = xp@eb2
template<int DP, int D>
__global__ void __launch_bounds__(TPB)
k_aggprep(const int* __restrict__ col_off,
          const float* __restrict__ msg0, const float* __restrict__ msg1,
          const float* __restrict__ root_prev, const float* __restrict__ xp_prev,
          const float* __restrict__ pw, const float* __restrict__ pb,
          const float* __restrict__ rw, const float* __restrict__ cb,
          const float* __restrict__ eb2,
          float* __restrict__ xp, float* __restrict__ root, float* __restrict__ Bb) {
  constexpr int NB = TPB / DP;   // nodes per block
  __shared__ float s_x[NB][DP];
  __shared__ float s_xpv[NB][D];
  __shared__ float s_pw[D * DP], s_rw[D * D], s_eb2[D * D], s_pb[D], s_cb[D];
  int tid = threadIdx.x;
  for (int t = tid; t < D * DP; t += TPB) s_pw[t] = pw[t];
  for (int t = tid; t < D * D; t += TPB) { s_rw[t] = rw[t]; s_eb2[t] = eb2[t]; }
  for (int t = tid; t < D; t += TPB) { s_pb[t] = pb[t]; s_cb[t] = cb[t]; }
  int g = tid / DP, o = tid % DP;
  int n = blockIdx.x * NB + g;
  if (n < NN) {
    int p0 = col_off[n], p1 = col_off[n + 1];
    float acc = 0.f;
    for (int p = p0; p < p1; p++)
      acc += msg0[(size_t)p * DP + o] + msg1[(size_t)p * DP + o];
    float deg = (p1 > p0) ? (float)(p1 - p0) : 1.f;
    float conv = acc / deg + root_prev[(size_t)n * DP + o];
    s_x[g][o] = (conv > 0.f ? conv : 0.f) + xp_prev[(size_t)n * DP + o];
  }
  __syncthreads();
  int g2 = tid / D, o2 = tid % D;
  int n2 = blockIdx.x * NB + g2;
  if (g2 < NB && n2 < NN) {
    float a = s_pb[o2];
    #pragma unroll
    for (int i = 0; i < DP; i++) a = fmaf(s_pw[o2 * DP + i], s_x[g2][i], a);
    s_xpv[g2][o2] = a;
    xp[(size_t)n2 * D + o2] = a;
  }
  __syncthreads();
  if (g2 < NB && n2 < NN) {
    float r2 = s_cb[o2], b2 = 0.f;
    #pragma unroll
    for (int i = 0; i < D; i++) {
      r2 = fmaf(s_rw[o2 * D + i], s_xpv[g2][i], r2);
      b2 = fmaf(s_xpv[g2][i], s_eb2[i * D + o2], b2);
    }
    root[(size_t)n2 * D + o2] = r2;
    Bb[(size_t)n2 * D + o2] = b2;
  }
}

// All four layers' V transposes in one dispatch.
// Layout (words): l0 @0 (65536, D=32), l1 @65536, l2 @81920, l3 @98304 (16384 each, D=16)
__global__ void k_trans_all(const float* __restrict__ e0, const float* __restrict__ e1,
                            const float* __restrict__ e2, const float* __restrict__ e3,
                            uint32* __restrict__ Vp) {
  int t = blockIdx.x * TPB + threadIdx.x;
  const float* ew2; uint32* dst; int D, loc;
  if (t < 65536)       { ew2 = e0; dst = Vp;         D = 32; loc = t; }
  else if (t < 81920)  { ew2 = e1; dst = Vp + 65536; D = 16; loc = t - 65536; }
  else if (t < 98304)  { ew2 = e2; dst = Vp + 81920; D = 16; loc = t - 81920; }
  else if (t < 114688) { ew2 = e3; dst = Vp + 98304; D = 16; loc = t - 98304; }
  else return;
  int COLS = D * 128;
  int i2 = loc / COLS;
  int r = loc - i2 * COLS;
  int w = r >> 1, p = r & 1;
  int k2 = w / D, o = w - k2 * D;
  int k = 2 * k2 + p;
  float lo = ew2[((size_t)((2 * i2) * D + o)) * 128 + k];
  float hi = ew2[((size_t)((2 * i2 + 1) * D + o)) * 128 + k];
  dst[loc] = pk2bf(lo, hi);
}

// Fused, split-k over blockIdx.y (half = 0/1).
// Phase B: half U-rows (packed bf16 k-pairs, word[k2loc*D+o], row stride UP) into LDS.
// Phase C: h (half k-range) via dot2 -> packed k-pairs; partial msg = h.U (+B if half 0)
//          scattered to msgH[colpos[s]] (col-sorted order for sequential agg).
template<int D, int G>
__global__ void __launch_bounds__(TPB)
k_fused(const int* __restrict__ eid_row, const int* __restrict__ row_off,
        const int* __restrict__ colpos,
        const float* __restrict__ ea, const float* __restrict__ ew1,
        const float* __restrict__ eb1, const uint32* __restrict__ Vp,
        const float* __restrict__ xp, const float* __restrict__ Bb,
        float* __restrict__ msg0, float* __restrict__ msg1) {
  constexpr int OQ = D / 4;            // threads per edge
  constexpr int EB = TPB / OQ;         // edges per inner iteration
  constexpr int COLS = D * 128;
  constexpr int UW = COLS / 2;         // u32 words per full U-row
  constexpr int UH = UW / 2;           // words per half U-row
  constexpr int UP = UH + 4;           // padded row stride (bank stagger, 16B-aligned)
  constexpr int CT = UH / TPB;         // words per thread (4 for D32, 2 for D16)

  __shared__ __align__(16) uint32 s_w1tp[4 * 64];   // packed ew1 i-pairs: [i2][kloc]
  __shared__ float  s_b1[64];
  __shared__ __align__(16) uint32 s_U[G * UP];      // packed bf16 k-pairs (half)
  __shared__ __align__(16) uint32 s_hp[EB * 34];    // packed bf16 h k-pairs (half), stride 34
  __shared__ __align__(16) uint32 s_eap[EB * 4];    // packed ea i-pairs
  __shared__ int    s_cp[EB];                       // col-sorted dest of each edge
  __shared__ uint32 s_xp2[G][D / 2];                // packed xp i-pairs
  __shared__ float  s_B[G * D];
  __shared__ int    s_off[G + 1];

  int tid = threadIdx.x;
  int half = blockIdx.y;
  int n0 = blockIdx.x * G;
  int GA = NN - n0; if (GA > G) GA = G;
  float* msgH = half ? msg1 : msg0;

  // ---- phase A: stage weights (this k-half) + per-node vectors ----
  for (int t = tid; t < 4 * 64; t += TPB) {
    int i2 = t >> 6, kloc = t & 63;
    int k = half * 64 + kloc;
    s_w1tp[t] = pk2bf(ew1[k * 8 + 2 * i2], ew1[k * 8 + 2 * i2 + 1]);
  }
  for (int t = tid; t < 64; t += TPB) s_b1[t] = eb1[half * 64 + t];
  for (int t = tid; t < G * (D / 2); t += TPB) {
    int g = t / (D / 2), i2 = t % (D / 2);
    if (g < GA) {
      float2 v = *(const float2*)(xp + (size_t)(n0 + g) * D + 2 * i2);
      s_xp2[g][i2] = pk2bf(v.x, v.y);
    } else {
      s_xp2[g][i2] = 0;
    }
  }
  for (int t = tid; t < G * D; t += TPB) {
    int g = t / D, i = t % D;
    s_B[t] = (g < GA && half == 0) ? Bb[(size_t)(n0 + g) * D + i] : 0.f;
  }
  if (tid <= GA) s_off[tid] = row_off[n0 + tid];
  __syncthreads();

  // ---- phase B: half U-rows into LDS via dot2 (CT words x G nodes / thread) ----
  {
    const uint2* Vp2 = (const uint2*)Vp;   // [i2][w] -> {p=0 word, p=1 word}
    float accLo[G][CT], accHi[G][CT];
    #pragma unroll
    for (int g = 0; g < G; g++)
      #pragma unroll
      for (int j = 0; j < CT; j++) { accLo[g][j] = 0.f; accHi[g][j] = 0.f; }
    #pragma unroll 2
    for (int i2 = 0; i2 < D / 2; i2++) {
      uint2 vv[CT];
      #pragma unroll
      for (int j = 0; j < CT; j++)
        vv[j] = Vp2[(size_t)i2 * UW + half * UH + j * TPB + tid];
      #pragma unroll
      for (int g = 0; g < G; g++) {
        uint32 xg = s_xp2[g][i2];
        #pragma unroll
        for (int j = 0; j < CT; j++) {
          dot2bf(accLo[g][j], xg, vv[j].x);
          dot2bf(accHi[g][j], xg, vv[j].y);
        }
      }
    }
    #pragma unroll
    for (int g = 0; g < G; g++)
      #pragma unroll
      for (int j = 0; j < CT; j++)
        s_U[g * UP + j * TPB + tid] = pk2bf(accLo[g][j], accHi[g][j]);
  }

  // ---- phase C: edges of the group (contiguous sorted slots) ----
  int p0 = row_off[n0], p1 = row_off[n0 + GA];
  int el = tid / OQ, oq = tid % OQ;
  for (int pc = p0; pc < p1; pc += EB) {
    int cnt = p1 - pc; if (cnt > EB) cnt = EB;
    __syncthreads();   // first iter: phase A/B done; later: protect s_eap/s_hp reuse
    for (int t = tid; t < cnt * 4; t += TPB) {
      int e2 = t >> 2, i2 = t & 3;
      float2 v = *(const float2*)(ea + (size_t)eid_row[pc + e2] * 8 + 2 * i2);
      s_eap[t] = pk2bf(v.x, v.y);
    }
    for (int t = tid; t < cnt; t += TPB) s_cp[t] = colpos[pc + t];
    __syncthreads();
    // h (half k-range) packed as bf16 k-pairs via dot2
    for (int t = tid; t < cnt * 32; t += TPB) {
      int e2 = t >> 5, k2 = t & 31;
      float a0 = s_b1[2 * k2], a1 = s_b1[2 * k2 + 1];
      #pragma unroll
      for (int i2 = 0; i2 < 4; i2++) {
        uint32 ep = s_eap[e2 * 4 + i2];
        uint2 ww = *(const uint2*)(s_w1tp + i2 * 64 + 2 * k2);
        dot2bf(a0, ep, ww.x);
        dot2bf(a1, ep, ww.y);
      }
      s_hp[e2 * 34 + k2] = pk2bf(fmaxf(a0, 0.f), fmaxf(a1, 0.f));
    }
    __syncthreads();
    if (el < cnt) {
      int s = pc + el;
      int g = 0;
      #pragma unroll
      for (int q = 1; q < G; q++) g += (q < GA && s >= s_off[q]) ? 1 : 0;
      const uint32* up = s_U + g * UP + oq * 4;
      const uint32* hp = s_hp + el * 34;
      float a0 = 0.f, a1 = 0.f, a2 = 0.f, a3 = 0.f;
      #pragma unroll 4
      for (int k4 = 0; k4 < 16; k4++) {
        uint2 hw = *(const uint2*)(hp + 2 * k4);
        uint4 u0 = *(const uint4*)(up + (2 * k4) * D);
        uint4 u1 = *(const uint4*)(up + (2 * k4 + 1) * D);
        dot2bf(a0, hw.x, u0.x); dot2bf(a1, hw.x, u0.y);
        dot2bf(a2, hw.x, u0.z); dot2bf(a3, hw.x, u0.w);
        dot2bf(a0, hw.y, u1.x); dot2bf(a1, hw.y, u1.y);
        dot2bf(a2, hw.y, u1.z); dot2bf(a3, hw.y, u1.w);
      }
      float4 b = ((const float4*)(s_B + g * D))[oq];
      float4 o4 = {a0 + b.x, a1 + b.y, a2 + b.z, a3 + b.w};
      ((float4*)(msgH + (size_t)s_cp[el] * D))[oq] = o4;
    }
  }
}

// last-layer aggregation (writes x for the final edge MLP)
template<int D>
__global__ void __launch_bounds__(TPB)
k_agg(const int* __restrict__ col_off,
      const float* __restrict__ msg0, const float* __restrict__ msg1,
      const float* __restrict__ root, const float* __restrict__ xp,
      float* __restrict__ xout) {
  constexpr int GP = TPB / D;
  int g = threadIdx.x / D, o = threadIdx.x % D;
  int n = blockIdx.x * GP + g;
  if (n >= NN) return;
  int p0 = col_off[n], p1 = col_off[n + 1];
  float acc = 0.f;
  for (int p = p0; p < p1; p++) {
    acc += msg0[(size_t)p * D + o] + msg1[(size_t)p * D + o];
  }
  float deg = (p1 > p0) ? (float)(p1 - p0) : 1.f;
  float conv = acc / deg + root[(size_t)n * D + o];
  float rl = conv > 0.f ? conv : 0.f;
  xout[(size_t)n * D + o] = rl + xp[(size_t)n * D + o];
}

// final edge MLP: out = relu((x[row]+x[col]) @ mw0^T + mb0) @ mw1^T + mb1
__global__ void __launch_bounds__(TPB)
k_final(const int* __restrict__ ei, const float* __restrict__ x,
        const float* __restrict__ mw0, const float* __restrict__ mb0,
        const float* __restrict__ mw1, const float* __restrict__ mb1,
        float* __restrict__ out) {
  __shared__ float s_w0[256], s_b0[16], s_w1[16], s_b1;
  for (int t = threadIdx.x; t < 256; t += TPB) s_w0[t] = mw0[t];
  if (threadIdx.x < 16) { s_b0[threadIdx.x] = mb0[threadIdx.x]; s_w1[threadIdx.x] = mw1[threadIdx.x]; }
  if (threadIdx.x == 0) s_b1 = mb1[0];
  __syncthreads();
  int e = blockIdx.x * TPB + threadIdx.x;
  if (e >= NE) return;
  int r = ei[e], c = ei[NE + e];
  const float4* xr4 = (const float4*)(x + (size_t)r * 16);
  const float4* xc4 = (const float4*)(x + (size_t)c * 16);
  float er[16];
  #pragma unroll
  for (int q = 0; q < 4; q++) {
    float4 vr = xr4[q], vc = xc4[q];
    er[4*q+0] = vr.x + vc.x; er[4*q+1] = vr.y + vc.y;
    er[4*q+2] = vr.z + vc.z; er[4*q+3] = vr.w + vc.w;
  }
  float o = s_b1;
  #pragma unroll
  for (int j = 0; j < 16; j++) {
    float t = s_b0[j];
    #pragma unroll
    for (int k = 0; k < 16; k++) t = fmaf(er[k], s_w0[j * 16 + k], t);
    t = fmaxf(t, 0.f);
    o = fmaf(t, s_w1[j], o);
  }
  out[e] = o;
}

// ---------------- host side ----------------

struct LayerPtrs {
  const float *pw, *pb, *ew1, *eb1, *ew2, *eb2, *rw, *cb;
};

extern "C" void kernel_launch(void* const* d_in, const int* in_sizes, int n_in,
                              void* d_out, int out_size, void* d_ws, size_t ws_size,
                              hipStream_t stream) {
  (void)in_sizes; (void)n_in; (void)out_size; (void)ws_size;
  const float* x0 = (const float*)d_in[0];
  const float* ea = (const float*)d_in[1];
  const int* ei = (const int*)d_in[2];
  LayerPtrs L[4];
  for (int l = 0; l < 4; l++) {
    L[l].pw  = (const float*)d_in[3 + 8 * l];
    L[l].pb  = (const float*)d_in[4 + 8 * l];
    L[l].ew1 = (const float*)d_in[5 + 8 * l];
    L[l].eb1 = (const float*)d_in[6 + 8 * l];
    L[l].ew2 = (const float*)d_in[7 + 8 * l];
    L[l].eb2 = (const float*)d_in[8 + 8 * l];
    L[l].rw  = (const float*)d_in[9 + 8 * l];
    L[l].cb  = (const float*)d_in[10 + 8 * l];
  }
  const float* mw0 = (const float*)d_in[35];
  const float* mb0 = (const float*)d_in[36];
  const float* mw1 = (const float*)d_in[37];
  const float* mb1 = (const float*)d_in[38];
  float* out = (float*)d_out;

  char* w = (char*)d_ws;
  size_t off = 0;
  auto alloc = [&](size_t b) -> void* {
    void* p = w + off;
    off = (off + b + 255) & ~(size_t)255;
    return p;
  };
  int* cnt      = (int*)alloc(sizeof(int) * 2 * NN);   // [row | col]
  int* row_off  = (int*)alloc(sizeof(int) * (NN + 1));
  int* col_off  = (int*)alloc(sizeof(int) * (NN + 1));
  int* cur_row  = (int*)alloc(sizeof(int) * NN);
  int* cur_col  = (int*)alloc(sizeof(int) * NN);
  int* eid_row  = (int*)alloc(sizeof(int) * NE);
  int* colpos   = (int*)alloc(sizeof(int) * NE);
  float* xpA   = (float*)alloc(sizeof(float) * NN * 32);
  float* xpB   = (float*)alloc(sizeof(float) * NN * 32);
  float* rootA = (float*)alloc(sizeof(float) * NN * 32);
  float* rootB = (float*)alloc(sizeof(float) * NN * 32);
  float* Bb    = (float*)alloc(sizeof(float) * NN * 32);
  float* msg0  = (float*)alloc(sizeof(float) * NE * 32);
  float* msg1  = (float*)alloc(sizeof(float) * NE * 32);
  float* xfin  = (float*)alloc(sizeof(float) * NN * 16);
  uint32* Vp   = (uint32*)alloc(sizeof(uint32) * 114688);  // 448 KB, all layers

  hipMemsetAsync(cnt, 0, sizeof(int) * 2 * NN, stream);
  k_count<<<(NE + TPB - 1) / TPB, TPB, 0, stream>>>(ei, cnt);
  k_scan2<<<2, SCAN_T, 0, stream>>>(cnt, row_off, cur_row, col_off, cur_col);
  k_fill_row<<<(NE + TPB - 1) / TPB, TPB, 0, stream>>>(ei, cur_row, eid_row);
  k_fill_colpos<<<(NE + TPB - 1) / TPB, TPB, 0, stream>>>(ei, eid_row, cur_col, colpos);
  k_trans_all<<<(114688 + TPB - 1) / TPB, TPB, 0, stream>>>(
      L[0].ew2, L[1].ew2, L[2].ew2, L[3].ew2, Vp);

  // layer 0 (DIN=16, D=32)
  k_nodeprep<16, 32><<<(NN + TPB - 1) / TPB, TPB, 0, stream>>>(
      x0, L[0].pw, L[0].pb, L[0].rw, L[0].cb, L[0].eb2, xpA, rootA, Bb);
  {
    dim3 gf((NN + 3) / 4, 2);
    k_fused<32, 4><<<gf, TPB, 0, stream>>>(
        eid_row, row_off, colpos, ea, L[0].ew1, L[0].eb1, Vp, xpA, Bb, msg0, msg1);
  }
  // layer 1 (DP=32 -> D=16)
  k_aggprep<32, 16><<<NN / 8, TPB, 0, stream>>>(
      col_off, msg0, msg1, rootA, xpA,
      L[1].pw, L[1].pb, L[1].rw, L[1].cb, L[1].eb2, xpB, rootB, Bb);
  {
    dim3 gf((NN + 5) / 6, 2);
    k_fused<16, 6><<<gf, TPB, 0, stream>>>(
        eid_row, row_off, colpos, ea, L[1].ew1, L[1].eb1, Vp + 65536, xpB, Bb, msg0, msg1);
  }
  // layer 2 (DP=16 -> D=16)
  k_aggprep<16, 16><<<NN / 16, TPB, 0, stream>>>(
      col_off, msg0, msg1, rootB, xpB,
      L[2].pw, L[2].pb, L[2].rw, L[2].cb, L[2].eb2, xpA, rootA, Bb);
  {
    dim3 gf((NN + 5) / 6, 2);
    k_fused<16, 6><<<gf, TPB, 0, stream>>>(
        eid_row, row_off, colpos, ea, L[2].ew1, L[2].eb1, Vp + 81920, xpA, Bb, msg0, msg1);
  }
  // layer 3 (DP=16 -> D=16)
  k_aggprep<16, 16><<<NN / 16, TPB, 0, stream>>>(
      col_off, msg0, msg1, rootA, xpA,
      L[3].pw, L[3].pb, L[3].rw, L[3].cb, L[3].eb2, xpB, rootB, Bb);
  {
    dim3 gf((NN + 5) / 6, 2);
    k_fused<16, 6><<<gf, TPB, 0, stream>>>(
        eid_row, row_off, colpos, ea, L[3].ew1, L[3].eb1, Vp + 98304, xpB, Bb, msg0, msg1);
  }
  // final aggregation + edge MLP
  k_agg<16><<<(NN * 16 + TPB - 1) / TPB, TPB, 0, stream>>>(
      col_off, msg0, msg1, rootB, xpB, xfin);
  k_final<<<(NE + TPB - 1) / TPB, TPB, 0, stream>>>(ei, xfin, mw0, mb0, mw1, mb1, out);
}

// Round 14
// 297.486 us; speedup vs baseline: 2.5717x; 1.0173x over previous
//
#include <hip/hip_runtime.h>

#define NN 10000
#define NE 160000
static constexpr int TPB = 256;
static constexpr int SCAN_T = 1024;

typedef unsigned int uint32;

static __device__ __forceinline__ ushort f2bf(float f) {
  uint32 u = __float_as_uint(f);
  u += 0x7fff + ((u >> 16) & 1);   // round-to-nearest-even
  return (ushort)(u >> 16);
}
static __device__ __forceinline__ uint32 pk2bf(float a, float b) {
  return (uint32)f2bf(a) | ((uint32)f2bf(b) << 16);
}
static __device__ __forceinline__ float bflo(uint32 u) {
  return __uint_as_float(u << 16);
}
static __device__ __forceinline__ float bfhi(uint32 u) {
  return __uint_as_float(u & 0xffff0000u);
}
// acc += a.lo*b.lo + a.hi*b.hi  (packed bf16 pairs, f32 accumulate)
static __device__ __forceinline__ void dot2bf(float& acc, uint32 a, uint32 b) {
  asm("v_dot2_f32_bf16 %0, %1, %2, %0" : "+v"(acc) : "v"(a), "v"(b));
}

// ---------------- sort / CSR build ----------------

// cnt = [row counts (NN) | col counts (NN)] contiguous
__global__ void k_count(const int* __restrict__ ei, int* __restrict__ cnt) {
  int e = blockIdx.x * TPB + threadIdx.x;
  if (e >= NE) return;
  atomicAdd(&cnt[ei[e]], 1);
  atomicAdd(&cnt[NN + ei[NE + e]], 1);
}

// 16-wave block scan: block 0 -> row CSR, block 1 -> col CSR.
__global__ void __launch_bounds__(SCAN_T)
k_scan2(const int* __restrict__ cnt_all, int* __restrict__ off_r, int* __restrict__ cur_r,
        int* __restrict__ off_c, int* __restrict__ cur_c) {
  const int* cnt = (blockIdx.x == 0) ? cnt_all : cnt_all + NN;
  int* off = (blockIdx.x == 0) ? off_r : off_c;
  int* cur = (blockIdx.x == 0) ? cur_r : cur_c;
  __shared__ int s_wave[16];
  __shared__ int s_carry;
  int tid = threadIdx.x;
  int lane = tid & 63, wid = tid >> 6;
  if (tid == 0) s_carry = 0;
  __syncthreads();
  for (int base = 0; base < NN; base += SCAN_T) {
    int i = base + tid;
    int v = (i < NN) ? cnt[i] : 0;
    int s = v;
    #pragma unroll
    for (int d = 1; d < 64; d <<= 1) {
      int t = __shfl_up(s, d, 64);
      if (lane >= d) s += t;
    }
    if (lane == 63) s_wave[wid] = s;
    __syncthreads();
    if (wid == 0 && lane < 16) {
      int ws = s_wave[lane];
      #pragma unroll
      for (int d = 1; d < 16; d <<= 1) {
        int t = __shfl_up(ws, d, 64);
        if (lane >= d) ws += t;
      }
      s_wave[lane] = ws;   // inclusive wave-sum scan
    }
    __syncthreads();
    int waveoff = (wid > 0) ? s_wave[wid - 1] : 0;
    int excl = s_carry + waveoff + s - v;
    if (i < NN) { off[i] = excl; cur[i] = excl; }
    __syncthreads();   // all reads of s_carry/s_wave done
    if (tid == 0) s_carry += s_wave[15];
    __syncthreads();
  }
  if (tid == 0) off[NN] = s_carry;
}

__global__ void k_fill_row(const int* __restrict__ ei, int* __restrict__ cur_row,
                           int* __restrict__ eid_row) {
  int e = blockIdx.x * TPB + threadIdx.x;
  if (e >= NE) return;
  int r = ei[e];
  int p = atomicAdd(&cur_row[r], 1);
  eid_row[p] = e;
}

// colpos[s] = position of sorted-slot s in col-sorted order (direct, no inverse pass)
__global__ void k_fill_colpos(const int* __restrict__ ei, const int* __restrict__ eid_row,
                              int* __restrict__ cur_col, int* __restrict__ colpos) {
  int s = blockIdx.x * TPB + threadIdx.x;
  if (s >= NE) return;
  int e = eid_row[s];
  int c = ei[NE + e];
  int p = atomicAdd(&cur_col[c], 1);
  colpos[s] = p;
}

// ---------------- per-layer kernels ----------------

// xp = x@pw^T + pb ; root = xp@rw^T + cb ; B[n,o] = sum_i xp[i]*eb2[i*D+o]
template<int DIN, int D>
__global__ void __launch_bounds__(TPB)
k_nodeprep(const float* __restrict__ x, const float* __restrict__ pw, const float* __restrict__ pb,
           const float* __restrict__ rw, const float* __restrict__ cb, const float* __restrict__ eb2,
           float* __restrict__ xp, float* __restrict__ root, float* __restrict__ Bb) {
  __shared__ float s_pw[D * DIN], s_rw[D * D], s_eb2[D * D], s_pb[D], s_cb[D];
  for (int t = threadIdx.x; t < D * DIN; t += TPB) s_pw[t] = pw[t];
  for (int t = threadIdx.x; t < D * D; t += TPB) { s_rw[t] = rw[t]; s_eb2[t] = eb2[t]; }
  for (int t = threadIdx.x; t < D; t += TPB) { s_pb[t] = pb[t]; s_cb[t] = cb[t]; }
  __syncthreads();
  int n = blockIdx.x * TPB + threadIdx.x;
  if (n >= NN) return;
  float xv[DIN];
  const float4* x4 = (const float4*)(x + (size_t)n * DIN);
  #pragma unroll
  for (int i = 0; i < DIN / 4; i++) {
    float4 v = x4[i];
    xv[4*i+0] = v.x; xv[4*i+1] = v.y; xv[4*i+2] = v.z; xv[4*i+3] = v.w;
  }
  float xpv[D];
  #pragma unroll
  for (int o = 0; o < D; o++) {
    float a = s_pb[o];
    #pragma unroll
    for (int i = 0; i < DIN; i++) a = fmaf(s_pw[o*DIN + i], xv[i], a);
    xpv[o] = a;
    xp[(size_t)n*D + o] = a;
  }
  #pragma unroll
  for (int o = 0; o < D; o++) {
    float a = s_cb[o];
    #pragma unroll
    for (int i = 0; i < D; i++) a = fmaf(s_rw[o*D + i], xpv[i], a);
    root[(size_t)n*D + o] = a;
  }
  #pragma unroll
  for (int o = 0; o < D; o++) {
    float a = 0.f;
    #pragma unroll
    for (int i = 0; i < D; i++) a = fmaf(xpv[i], s_eb2[i*D + o], a);
    Bb[(size_t)n*D + o] = a;
  }
}

// Fused agg + next-layer nodeprep (layers 1..3), packed-bf16 msg input.
template<int DP, int D>
__global__ void __launch_bounds__(TPB)
k_aggprep(const int* __restrict__ col_off,
          const uint32* __restrict__ msg0p, const uint32* __restrict__ msg1p,
          const float* __restrict__ root_prev, const float* __restrict__ xp_prev,
          const float* __restrict__ pw, const float* __restrict__ pb,
          const float* __restrict__ rw, const float* __restrict__ cb,
          const float* __restrict__ eb2,
          float* __restrict__ xp, float* __restrict__ root, float* __restrict__ Bb) {
  constexpr int W = DP / 2;      // packed words per edge
  constexpr int NB = TPB / W;    // nodes per block (16 for DP=32, 32 for DP=16)
  __shared__ float s_x[NB][DP];
  __shared__ float s_xpv[NB][D];
  __shared__ float s_pw[D * DP], s_rw[D * D], s_eb2[D * D], s_pb[D], s_cb[D];
  int tid = threadIdx.x;
  for (int t = tid; t < D * DP; t += TPB) s_pw[t] = pw[t];
  for (int t = tid; t < D * D; t += TPB) { s_rw[t] = rw[t]; s_eb2[t] = eb2[t]; }
  for (int t = tid; t < D; t += TPB) { s_pb[t] = pb[t]; s_cb[t] = cb[t]; }
  int g = tid / W, o2 = tid % W;
  int n = blockIdx.x * NB + g;
  if (n < NN) {
    int p0 = col_off[n], p1 = col_off[n + 1];
    float ax = 0.f, ay = 0.f;
    for (int p = p0; p < p1; p++) {
      uint32 w0 = msg0p[(size_t)p * W + o2];
      uint32 w1 = msg1p[(size_t)p * W + o2];
      ax += bflo(w0) + bflo(w1);
      ay += bfhi(w0) + bfhi(w1);
    }
    float deg = (p1 > p0) ? (float)(p1 - p0) : 1.f;
    float2 rp = *(const float2*)(root_prev + (size_t)n * DP + 2 * o2);
    float2 xq = *(const float2*)(xp_prev + (size_t)n * DP + 2 * o2);
    float c0 = ax / deg + rp.x, c1 = ay / deg + rp.y;
    s_x[g][2 * o2]     = (c0 > 0.f ? c0 : 0.f) + xq.x;
    s_x[g][2 * o2 + 1] = (c1 > 0.f ? c1 : 0.f) + xq.y;
  }
  __syncthreads();
  for (int t = tid; t < NB * D; t += TPB) {
    int g2 = t / D, o = t % D;
    int n2 = blockIdx.x * NB + g2;
    if (n2 < NN) {
      float a = s_pb[o];
      #pragma unroll
      for (int i = 0; i < DP; i++) a = fmaf(s_pw[o * DP + i], s_x[g2][i], a);
      s_xpv[g2][o] = a;
      xp[(size_t)n2 * D + o] = a;
    }
  }
  __syncthreads();
  for (int t = tid; t < NB * D; t += TPB) {
    int g2 = t / D, o = t % D;
    int n2 = blockIdx.x * NB + g2;
    if (n2 < NN) {
      float r2 = s_cb[o], b2 = 0.f;
      #pragma unroll
      for (int i = 0; i < D; i++) {
        r2 = fmaf(s_rw[o * D + i], s_xpv[g2][i], r2);
        b2 = fmaf(s_xpv[g2][i], s_eb2[i * D + o], b2);
      }
      root[(size_t)n2 * D + o] = r2;
      Bb[(size_t)n2 * D + o] = b2;
    }
  }
}

// All four layers' V transposes in one dispatch.
// Layout (words): l0 @0 (65536, D=32), l1 @65536, l2 @81920, l3 @98304 (16384 each, D=16)
__global__ void k_trans_all(const float* __restrict__ e0, const float* __restrict__ e1,
                            const float* __restrict__ e2, const float* __restrict__ e3,
                            uint32* __restrict__ Vp) {
  int t = blockIdx.x * TPB + threadIdx.x;
  const float* ew2; uint32* dst; int D, loc;
  if (t < 65536)       { ew2 = e0; dst = Vp;         D = 32; loc = t; }
  else if (t < 81920)  { ew2 = e1; dst = Vp + 65536; D = 16; loc = t - 65536; }
  else if (t < 98304)  { ew2 = e2; dst = Vp + 81920; D = 16; loc = t - 81920; }
  else if (t < 114688) { ew2 = e3; dst = Vp + 98304; D = 16; loc = t - 98304; }
  else return;
  int COLS = D * 128;
  int i2 = loc / COLS;
  int r = loc - i2 * COLS;
  int w = r >> 1, p = r & 1;
  int k2 = w / D, o = w - k2 * D;
  int k = 2 * k2 + p;
  float lo = ew2[((size_t)((2 * i2) * D + o)) * 128 + k];
  float hi = ew2[((size_t)((2 * i2 + 1) * D + o)) * 128 + k];
  dst[loc] = pk2bf(lo, hi);
}

// Fused, split-k over blockIdx.y (half = 0/1).
// Phase B: half U-rows (packed bf16 k-pairs, word[k2loc*D+o], row stride UP) into LDS.
// Phase C: h (half k-range) via dot2 -> packed k-pairs; partial msg = h.U (+B if half 0)
//          scattered bf16-packed to msgHp[colpos[s]] (col-sorted for sequential agg).
template<int D, int G>
__global__ void __launch_bounds__(TPB)
k_fused(const int* __restrict__ eid_row, const int* __restrict__ row_off,
        const int* __restrict__ colpos,
        const float* __restrict__ ea, const float* __restrict__ ew1,
        const float* __restrict__ eb1, const uint32* __restrict__ Vp,
        const float* __restrict__ xp, const float* __restrict__ Bb,
        uint32* __restrict__ msg0p, uint32* __restrict__ msg1p) {
  constexpr int OQ = D / 4;            // threads per edge
  constexpr int EB = TPB / OQ;         // edges per inner iteration
  constexpr int COLS = D * 128;
  constexpr int UW = COLS / 2;         // u32 words per full U-row
  constexpr int UH = UW / 2;           // words per half U-row
  constexpr int UP = UH + 4;           // padded row stride (bank stagger, 16B-aligned)
  constexpr int CT = UH / TPB;         // words per thread (4 for D32, 2 for D16)

  __shared__ __align__(16) uint32 s_w1tp[4 * 64];   // packed ew1 i-pairs: [i2][kloc]
  __shared__ float  s_b1[64];
  __shared__ __align__(16) uint32 s_U[G * UP];      // packed bf16 k-pairs (half)
  __shared__ __align__(16) uint32 s_hp[EB * 36];    // packed bf16 h k-pairs, stride 36 (16B-aligned)
  __shared__ __align__(16) uint32 s_eap[EB * 4];    // packed ea i-pairs
  __shared__ int    s_cp[EB];                       // col-sorted dest of each edge
  __shared__ uint32 s_xp2[G][D / 2];                // packed xp i-pairs
  __shared__ float  s_B[G * D];
  __shared__ int    s_off[G + 1];

  int tid = threadIdx.x;
  int half = blockIdx.y;
  int n0 = blockIdx.x * G;
  int GA = NN - n0; if (GA > G) GA = G;
  uint32* msgHp = half ? msg1p : msg0p;

  // ---- phase A: stage weights (this k-half) + per-node vectors ----
  for (int t = tid; t < 4 * 64; t += TPB) {
    int i2 = t >> 6, kloc = t & 63;
    int k = half * 64 + kloc;
    s_w1tp[t] = pk2bf(ew1[k * 8 + 2 * i2], ew1[k * 8 + 2 * i2 + 1]);
  }
  for (int t = tid; t < 64; t += TPB) s_b1[t] = eb1[half * 64 + t];
  for (int t = tid; t < G * (D / 2); t += TPB) {
    int g = t / (D / 2), i2 = t % (D / 2);
    if (g < GA) {
      float2 v = *(const float2*)(xp + (size_t)(n0 + g) * D + 2 * i2);
      s_xp2[g][i2] = pk2bf(v.x, v.y);
    } else {
      s_xp2[g][i2] = 0;
    }
  }
  for (int t = tid; t < G * D; t += TPB) {
    int g = t / D, i = t % D;
    s_B[t] = (g < GA && half == 0) ? Bb[(size_t)(n0 + g) * D + i] : 0.f;
  }
  if (tid <= GA) s_off[tid] = row_off[n0 + tid];
  __syncthreads();

  // ---- phase B: half U-rows into LDS via dot2 (CT words x G nodes / thread) ----
  {
    const uint2* Vp2 = (const uint2*)Vp;   // [i2][w] -> {p=0 word, p=1 word}
    float accLo[G][CT], accHi[G][CT];
    #pragma unroll
    for (int g = 0; g < G; g++)
      #pragma unroll
      for (int j = 0; j < CT; j++) { accLo[g][j] = 0.f; accHi[g][j] = 0.f; }
    #pragma unroll 2
    for (int i2 = 0; i2 < D / 2; i2++) {
      uint2 vv[CT];
      #pragma unroll
      for (int j = 0; j < CT; j++)
        vv[j] = Vp2[(size_t)i2 * UW + half * UH + j * TPB + tid];
      #pragma unroll
      for (int g = 0; g < G; g++) {
        uint32 xg = s_xp2[g][i2];
        #pragma unroll
        for (int j = 0; j < CT; j++) {
          dot2bf(accLo[g][j], xg, vv[j].x);
          dot2bf(accHi[g][j], xg, vv[j].y);
        }
      }
    }
    #pragma unroll
    for (int g = 0; g < G; g++)
      #pragma unroll
      for (int j = 0; j < CT; j++)
        s_U[g * UP + j * TPB + tid] = pk2bf(accLo[g][j], accHi[g][j]);
  }

  // ---- phase C: edges of the group (contiguous sorted slots) ----
  int p0 = row_off[n0], p1 = row_off[n0 + GA];
  int el = tid / OQ, oq = tid % OQ;
  for (int pc = p0; pc < p1; pc += EB) {
    int cnt = p1 - pc; if (cnt > EB) cnt = EB;
    __syncthreads();   // first iter: phase A/B done; later: protect s_eap/s_hp reuse
    for (int t = tid; t < cnt * 4; t += TPB) {
      int e2 = t >> 2, i2 = t & 3;
      float2 v = *(const float2*)(ea + (size_t)eid_row[pc + e2] * 8 + 2 * i2);
      s_eap[t] = pk2bf(v.x, v.y);
    }
    for (int t = tid; t < cnt; t += TPB) s_cp[t] = colpos[pc + t];
    __syncthreads();
    // h (half k-range) packed as bf16 k-pairs via dot2
    for (int t = tid; t < cnt * 32; t += TPB) {
      int e2 = t >> 5, k2 = t & 31;
      float a0 = s_b1[2 * k2], a1 = s_b1[2 * k2 + 1];
      #pragma unroll
      for (int i2 = 0; i2 < 4; i2++) {
        uint32 ep = s_eap[e2 * 4 + i2];
        uint2 ww = *(const uint2*)(s_w1tp + i2 * 64 + 2 * k2);
        dot2bf(a0, ep, ww.x);
        dot2bf(a1, ep, ww.y);
      }
      s_hp[e2 * 36 + k2] = pk2bf(fmaxf(a0, 0.f), fmaxf(a1, 0.f));
    }
    __syncthreads();
    if (el < cnt) {
      int g = 0;
      {
        int s = pc + el;
        #pragma unroll
        for (int q = 1; q < G; q++) g += (q < GA && s >= s_off[q]) ? 1 : 0;
      }
      const uint32* up = s_U + g * UP + oq * 4;
      const uint32* hp = s_hp + el * 36;
      float a0 = 0.f, a1 = 0.f, a2 = 0.f, a3 = 0.f;
      #pragma unroll
      for (int k8 = 0; k8 < 8; k8++) {
        uint4 hw = *(const uint4*)(hp + 4 * k8);
        uint4 u0 = *(const uint4*)(up + (4 * k8 + 0) * D);
        uint4 u1 = *(const uint4*)(up + (4 * k8 + 1) * D);
        uint4 u2 = *(const uint4*)(up + (4 * k8 + 2) * D);
        uint4 u3 = *(const uint4*)(up + (4 * k8 + 3) * D);
        dot2bf(a0, hw.x, u0.x); dot2bf(a1, hw.x, u0.y); dot2bf(a2, hw.x, u0.z); dot2bf(a3, hw.x, u0.w);
        dot2bf(a0, hw.y, u1.x); dot2bf(a1, hw.y, u1.y); dot2bf(a2, hw.y, u1.z); dot2bf(a3, hw.y, u1.w);
        dot2bf(a0, hw.z, u2.x); dot2bf(a1, hw.z, u2.y); dot2bf(a2, hw.z, u2.z); dot2bf(a3, hw.z, u2.w);
        dot2bf(a0, hw.w, u3.x); dot2bf(a1, hw.w, u3.y); dot2bf(a2, hw.w, u3.z); dot2bf(a3, hw.w, u3.w);
      }
      float4 b = ((const float4*)(s_B + g * D))[oq];
      uint2 om;
      om.x = pk2bf(a0 + b.x, a1 + b.y);
      om.y = pk2bf(a2 + b.z, a3 + b.w);
      ((uint2*)(msgHp + (size_t)s_cp[el] * (D / 2)))[oq] = om;
    }
  }
}

// last-layer aggregation (packed msg in, f32 x out for the final edge MLP)
template<int D>
__global__ void __launch_bounds__(TPB)
k_agg(const int* __restrict__ col_off,
      const uint32* __restrict__ msg0p, const uint32* __restrict__ msg1p,
      const float* __restrict__ root, const float* __restrict__ xp,
      float* __restrict__ xout) {
  constexpr int W = D / 2;
  constexpr int GP = TPB / W;
  int g = threadIdx.x / W, o2 = threadIdx.x % W;
  int n = blockIdx.x * GP + g;
  if (n >= NN) return;
  int p0 = col_off[n], p1 = col_off[n + 1];
  float ax = 0.f, ay = 0.f;
  for (int p = p0; p < p1; p++) {
    uint32 w0 = msg0p[(size_t)p * W + o2];
    uint32 w1 = msg1p[(size_t)p * W + o2];
    ax += bflo(w0) + bflo(w1);
    ay += bfhi(w0) + bfhi(w1);
  }
  float deg = (p1 > p0) ? (float)(p1 - p0) : 1.f;
  float2 rp = *(const float2*)(root + (size_t)n * D + 2 * o2);
  float2 xq = *(const float2*)(xp + (size_t)n * D + 2 * o2);
  float c0 = ax / deg + rp.x, c1 = ay / deg + rp.y;
  xout[(size_t)n * D + 2 * o2]     = (c0 > 0.f ? c0 : 0.f) + xq.x;
  xout[(size_t)n * D + 2 * o2 + 1] = (c1 > 0.f ? c1 : 0.f) + xq.y;
}

// final edge MLP: out = relu((x[row]+x[col]) @ mw0^T + mb0) @ mw1^T + mb1
__global__ void __launch_bounds__(TPB)
k_final(const int* __restrict__ ei, const float* __restrict__ x,
        const float* __restrict__ mw0, const float* __restrict__ mb0,
        const float* __restrict__ mw1, const float* __restrict__ mb1,
        float* __restrict__ out) {
  __shared__ float s_w0[256], s_b0[16], s_w1[16], s_b1;
  for (int t = threadIdx.x; t < 256; t += TPB) s_w0[t] = mw0[t];
  if (threadIdx.x < 16) { s_b0[threadIdx.x] = mb0[threadIdx.x]; s_w1[threadIdx.x] = mw1[threadIdx.x]; }
  if (threadIdx.x == 0) s_b1 = mb1[0];
  __syncthreads();
  int e = blockIdx.x * TPB + threadIdx.x;
  if (e >= NE) return;
  int r = ei[e], c = ei[NE + e];
  const float4* xr4 = (const float4*)(x + (size_t)r * 16);
  const float4* xc4 = (const float4*)(x + (size_t)c * 16);
  float er[16];
  #pragma unroll
  for (int q = 0; q < 4; q++) {
    float4 vr = xr4[q], vc = xc4[q];
    er[4*q+0] = vr.x + vc.x; er[4*q+1] = vr.y + vc.y;
    er[4*q+2] = vr.z + vc.z; er[4*q+3] = vr.w + vc.w;
  }
  float o = s_b1;
  #pragma unroll
  for (int j = 0; j < 16; j++) {
    float t = s_b0[j];
    #pragma unroll
    for (int k = 0; k < 16; k++) t = fmaf(er[k], s_w0[j * 16 + k], t);
    t = fmaxf(t, 0.f);
    o = fmaf(t, s_w1[j], o);
  }
  out[e] = o;
}

// ---------------- host side ----------------

struct LayerPtrs {
  const float *pw, *pb, *ew1, *eb1, *ew2, *eb2, *rw, *cb;
};

extern "C" void kernel_launch(void* const* d_in, const int* in_sizes, int n_in,
                              void* d_out, int out_size, void* d_ws, size_t ws_size,
                              hipStream_t stream) {
  (void)in_sizes; (void)n_in; (void)out_size; (void)ws_size;
  const float* x0 = (const float*)d_in[0];
  const float* ea = (const float*)d_in[1];
  const int* ei = (const int*)d_in[2];
  LayerPtrs L[4];
  for (int l = 0; l < 4; l++) {
    L[l].pw  = (const float*)d_in[3 + 8 * l];
    L[l].pb  = (const float*)d_in[4 + 8 * l];
    L[l].ew1 = (const float*)d_in[5 + 8 * l];
    L[l].eb1 = (const float*)d_in[6 + 8 * l];
    L[l].ew2 = (const float*)d_in[7 + 8 * l];
    L[l].eb2 = (const float*)d_in[8 + 8 * l];
    L[l].rw  = (const float*)d_in[9 + 8 * l];
    L[l].cb  = (const float*)d_in[10 + 8 * l];
  }
  const float* mw0 = (const float*)d_in[35];
  const float* mb0 = (const float*)d_in[36];
  const float* mw1 = (const float*)d_in[37];
  const float* mb1 = (const float*)d_in[38];
  float* out = (float*)d_out;

  char* w = (char*)d_ws;
  size_t off = 0;
  auto alloc = [&](size_t b) -> void* {
    void* p = w + off;
    off = (off + b + 255) & ~(size_t)255;
    return p;
  };
  int* cnt      = (int*)alloc(sizeof(int) * 2 * NN);   // [row | col]
  int* row_off  = (int*)alloc(sizeof(int) * (NN + 1));
  int* col_off  = (int*)alloc(sizeof(int) * (NN + 1));
  int* cur_row  = (int*)alloc(sizeof(int) * NN);
  int* cur_col  = (int*)alloc(sizeof(int) * NN);
  int* eid_row  = (int*)alloc(sizeof(int) * NE);
  int* colpos   = (int*)alloc(sizeof(int) * NE);
  float* xpA   = (float*)alloc(sizeof(float) * NN * 32);
  float* xpB   = (float*)alloc(sizeof(float) * NN * 32);
  float* rootA = (float*)alloc(sizeof(float) * NN * 32);
  float* rootB = (float*)alloc(sizeof(float) * NN * 32);
  float* Bb    = (float*)alloc(sizeof(float) * NN * 32);
  uint32* msg0p = (uint32*)alloc(sizeof(uint32) * NE * 16);
  uint32* msg1p = (uint32*)alloc(sizeof(uint32) * NE * 16);
  float* xfin  = (float*)alloc(sizeof(float) * NN * 16);
  uint32* Vp   = (uint32*)alloc(sizeof(uint32) * 114688);  // 448 KB, all layers

  hipMemsetAsync(cnt, 0, sizeof(int) * 2 * NN, stream);
  k_count<<<(NE + TPB - 1) / TPB, TPB, 0, stream>>>(ei, cnt);
  k_scan2<<<2, SCAN_T, 0, stream>>>(cnt, row_off, cur_row, col_off, cur_col);
  k_fill_row<<<(NE + TPB - 1) / TPB, TPB, 0, stream>>>(ei, cur_row, eid_row);
  k_fill_colpos<<<(NE + TPB - 1) / TPB, TPB, 0, stream>>>(ei, eid_row, cur_col, colpos);
  k_trans_all<<<(114688 + TPB - 1) / TPB, TPB, 0, stream>>>(
      L[0].ew2, L[1].ew2, L[2].ew2, L[3].ew2, Vp);

  // layer 0 (DIN=16, D=32)
  k_nodeprep<16, 32><<<(NN + TPB - 1) / TPB, TPB, 0, stream>>>(
      x0, L[0].pw, L[0].pb, L[0].rw, L[0].cb, L[0].eb2, xpA, rootA, Bb);
  {
    dim3 gf((NN + 5) / 6, 2);
    k_fused<32, 6><<<gf, TPB, 0, stream>>>(
        eid_row, row_off, colpos, ea, L[0].ew1, L[0].eb1, Vp, xpA, Bb, msg0p, msg1p);
  }
  // layer 1 (DP=32 -> D=16)
  k_aggprep<32, 16><<<(NN + 15) / 16, TPB, 0, stream>>>(
      col_off, msg0p, msg1p, rootA, xpA,
      L[1].pw, L[1].pb, L[1].rw, L[1].cb, L[1].eb2, xpB, rootB, Bb);
  {
    dim3 gf((NN + 5) / 6, 2);
    k_fused<16, 6><<<gf, TPB, 0, stream>>>(
        eid_row, row_off, colpos, ea, L[1].ew1, L[1].eb1, Vp + 65536, xpB, Bb, msg0p, msg1p);
  }
  // layer 2 (DP=16 -> D=16)
  k_aggprep<16, 16><<<(NN + 31) / 32, TPB, 0, stream>>>(
      col_off, msg0p, msg1p, rootB, xpB,
      L[2].pw, L[2].pb, L[2].rw, L[2].cb, L[2].eb2, xpA, rootA, Bb);
  {
    dim3 gf((NN + 5) / 6, 2);
    k_fused<16, 6><<<gf, TPB, 0, stream>>>(
        eid_row, row_off, colpos, ea, L[2].ew1, L[2].eb1, Vp + 81920, xpA, Bb, msg0p, msg1p);
  }
  // layer 3 (DP=16 -> D=16)
  k_aggprep<16, 16><<<(NN + 31) / 32, TPB, 0, stream>>>(
      col_off, msg0p, msg1p, rootA, xpA,
      L[3].pw, L[3].pb, L[3].rw, L[3].cb, L[3].eb2, xpB, rootB, Bb);
  {
    dim3 gf((NN + 5) / 6, 2);
    k_fused<16, 6><<<gf, TPB, 0, stream>>>(
        eid_row, row_off, colpos, ea, L[3].ew1, L[3].eb1, Vp + 98304, xpB, Bb, msg0p, msg1p);
  }
  // final aggregation + edge MLP
  k_agg<16><<<(NN + 31) / 32, TPB, 0, stream>>>(
      col_off, msg0p, msg1p, rootB, xpB, xfin);
  k_final<<<(NE + TPB - 1) / TPB, TPB, 0, stream>>>(ei, xfin, mw0, mb0, mw1, mb1, out);
}